// Round 18
// baseline (358.502 us; speedup 1.0000x reference)
//
#include <hip/hip_runtime.h>
#include <hip/hip_fp16.h>
#include <math.h>

// GAT node classification: 2 GATConv layers + ELU + log_softmax.
// N=100000, E=1600000 (+N self loops), IN=128, HEADS=4, HID=32, OUT=40.
//
// Rules learned:
//  - R4: every __shfl executes with ALL 64 lanes active; wave-uniform bounds;
//    predicate VALUES not control flow.
//  - R8: __shfl returns the SOURCE lane's evaluation of its operand.
//  - R9/R15: same-address atomics serialize at every level; many-writer
//    reductions must be shfl/tree form.
//  - R10: diff-check unrolled blocks line-by-line after mechanical edits.
//  - R12: 2-deep gather unroll is the sweet spot.
//  - R14: feature accumulation in packed fp16 (__hfma2); logits/dens f32.
//  - R17: independent kernels grid-fused; k_init -> hipMemsetAsync.
//  - R18: fused-kernel LDS is the SUM of branch statics -> union via one
//    smem buffer; GEMM inner loop widened to b64 LDS reads (k-quad W layout).

#define SLOPE 0.2f
#define NB 512
#define NBSHIFT 9

#if defined(__has_builtin)
#if __has_builtin(__builtin_amdgcn_fdot2)
#define HAS_FDOT2 1
#endif
#endif

typedef _Float16 h2v __attribute__((ext_vector_type(2)));

__device__ __forceinline__ float dot2f(__half2 a, __half2 b, float c) {
#ifdef HAS_FDOT2
    return __builtin_amdgcn_fdot2(*reinterpret_cast<h2v*>(&a),
                                  *reinterpret_cast<h2v*>(&b), c, false);
#else
    float2 af = __half22float2(a), bf = __half22float2(b);
    return fmaf(af.y, bf.y, fmaf(af.x, bf.x, c));
#endif
}

__device__ __forceinline__ unsigned fenc(float f) {
    unsigned b = __float_as_uint(f);
    return (b & 0x80000000u) ? ~b : (b | 0x80000000u);
}
__device__ __forceinline__ float fdec(unsigned u) {
    return __uint_as_float((u & 0x80000000u) ? (u ^ 0x80000000u) : ~u);
}
__device__ __forceinline__ __half2 i2h2(int i) { return *reinterpret_cast<__half2*>(&i); }
__device__ __forceinline__ int h22i(__half2 h) { return *reinterpret_cast<int*>(&h); }
__device__ __forceinline__ __half2 h2shflxor(__half2 v, int off) {
    int j = __shfl_xor(h22i(v), off);
    return i2h2(j);
}

// ---------------- CSR bin (device body, smem-carved) ----------------

__device__ void bin_body(const int* __restrict__ src, const int* __restrict__ dst,
                         unsigned* __restrict__ gcnt, unsigned* __restrict__ binbuf,
                         int E, int nbuck, int cap, int epb, int bid, char* smem) {
    unsigned* hist = (unsigned*)smem;          // 1KB
    unsigned* base = hist + 256;               // 1KB
    unsigned* cur  = base + 256;               // 1KB
    int t = threadIdx.x;
    if (t < nbuck) { hist[t] = 0u; cur[t] = 0u; }
    __syncthreads();
    int e0 = bid * epb;
    int e1 = min(E, e0 + epb);
    for (int e = e0 + t; e < e1; e += 256) {
        int bk = dst[e] >> NBSHIFT;
        atomicAdd(&hist[bk], 1u);
    }
    __syncthreads();
    if (t < nbuck) base[t] = hist[t] ? atomicAdd(&gcnt[t], hist[t]) : 0u;
    __syncthreads();
    for (int e = e0 + t; e < e1; e += 256) {
        int d = dst[e];
        int bk = d >> NBSHIFT;
        unsigned p = atomicAdd(&cur[bk], 1u);
        binbuf[(size_t)bk * cap + base[bk] + p] =
            ((unsigned)src[e] << NBSHIFT) | (unsigned)(d & (NB - 1));
    }
}

// ---------------- Layer1 GEMM + fused al1 (device body, smem-carved) ----------------
// W LDS layout (R18): wq[kp][c] (uint2) = 4 halves of W[kc*32+4kp .. +3][c].
// wv reads: element-stride-1 ds_read_b64, conflict-free.

__device__ void gemm1_body(const float* __restrict__ x, const float* __restrict__ W,
                           const float* __restrict__ asrc, const float* __restrict__ adst,
                           __half* __restrict__ hh, float* __restrict__ als,
                           float* __restrict__ ald, int n, int bid, char* smem) {
    __half2 (*xs2)[64] = (__half2(*)[64])smem;            // 8KB: [row][k2]
    uint2   (*wq)[128] = (uint2(*)[128])(smem + 8192);    // 8KB: [kp][c]
    int t = threadIdx.x;
    int row0 = bid * 32;
#pragma unroll
    for (int i = 0; i < 4; i++) {
        int flat = t + 256 * i;
        int r = flat >> 5, c4 = flat & 31;
        int gr = row0 + r;
        float4 v = make_float4(0.f, 0.f, 0.f, 0.f);
        if (gr < n) v = ((const float4*)(x + (size_t)gr * 128))[c4];
        xs2[r][c4 * 2]     = __floats2half2_rn(v.x, v.y);
        xs2[r][c4 * 2 + 1] = __floats2half2_rn(v.z, v.w);
    }
    int ty = t >> 5;
    int tx = t & 31;
    float acc[4][4] = {};
    for (int kc = 0; kc < 4; ++kc) {
        __syncthreads();
        // stage W chunk into k-quad layout: thread (kk, c4) scatters 4 halves
#pragma unroll
        for (int i = 0; i < 4; i++) {
            int flat = t + 256 * i;
            int kk = flat >> 5, c4 = flat & 31;          // kk in [0,32)
            float4 v = ((const float4*)(W + (size_t)(kc * 32 + kk) * 128))[c4];
            int kp = kk >> 2, slot = kk & 3;
            ((__half*)&wq[kp][c4 * 4 + 0])[slot] = __float2half_rn(v.x);
            ((__half*)&wq[kp][c4 * 4 + 1])[slot] = __float2half_rn(v.y);
            ((__half*)&wq[kp][c4 * 4 + 2])[slot] = __float2half_rn(v.z);
            ((__half*)&wq[kp][c4 * 4 + 3])[slot] = __float2half_rn(v.w);
        }
        __syncthreads();
#pragma unroll
        for (int kp = 0; kp < 8; ++kp) {
            uint2 wv4[4];
#pragma unroll
            for (int j = 0; j < 4; j++)
                wv4[j] = wq[kp][tx + 32 * j];
#pragma unroll
            for (int r = 0; r < 4; r++) {
                uint2 xv4 = *(const uint2*)&xs2[ty + 8 * r][kc * 16 + kp * 2];
                __half2 xv0 = i2h2((int)xv4.x);
                __half2 xv1 = i2h2((int)xv4.y);
#pragma unroll
                for (int j = 0; j < 4; j++) {
                    acc[r][j] = dot2f(xv0, i2h2((int)wv4[j].x), acc[r][j]);
                    acc[r][j] = dot2f(xv1, i2h2((int)wv4[j].y), acc[r][j]);
                }
            }
        }
    }
    float vs0 = asrc[tx], vs1 = asrc[32 + tx], vs2 = asrc[64 + tx], vs3 = asrc[96 + tx];
    float vd0 = adst[tx], vd1 = adst[32 + tx], vd2 = adst[64 + tx], vd3 = adst[96 + tx];
#pragma unroll
    for (int r = 0; r < 4; r++) {
        int gr = row0 + ty + 8 * r;
        if (gr < n) {
#pragma unroll
            for (int j = 0; j < 4; j++)
                hh[(size_t)gr * 128 + tx + 32 * j] = __float2half_rn(acc[r][j]);
        }
        // fused al1: 32-lane shfl reduce (no atomics -- R15); all lanes run.
        float ps0 = acc[r][0] * vs0, ps1 = acc[r][1] * vs1;
        float ps2 = acc[r][2] * vs2, ps3 = acc[r][3] * vs3;
        float pd0 = acc[r][0] * vd0, pd1 = acc[r][1] * vd1;
        float pd2 = acc[r][2] * vd2, pd3 = acc[r][3] * vd3;
#pragma unroll
        for (int off = 1; off <= 16; off <<= 1) {
            ps0 += __shfl_xor(ps0, off); ps1 += __shfl_xor(ps1, off);
            ps2 += __shfl_xor(ps2, off); ps3 += __shfl_xor(ps3, off);
            pd0 += __shfl_xor(pd0, off); pd1 += __shfl_xor(pd1, off);
            pd2 += __shfl_xor(pd2, off); pd3 += __shfl_xor(pd3, off);
        }
        if (tx == 0 && gr < n) {
            float4 s4 = make_float4(ps0, ps1, ps2, ps3);
            float4 d4 = make_float4(pd0, pd1, pd2, pd3);
            *(float4*)(als + (size_t)gr * 4) = s4;
            *(float4*)(ald + (size_t)gr * 4) = d4;
        }
    }
}

// fused: blocks [0,binBlocks) bin; [binBlocks, ...) gemm1. Shared smem union.
__global__ __launch_bounds__(256) void k_binGemm1(const int* src, const int* dst,
                                                  unsigned* gcnt, unsigned* binbuf,
                                                  int E, int nbuck, int cap, int epb, int binBlocks,
                                                  const float* x, const float* W,
                                                  const float* asrc, const float* adst,
                                                  __half* hh, float* als, float* ald, int n) {
    __shared__ __align__(16) char smem[16384];
    if ((int)blockIdx.x < binBlocks)
        bin_body(src, dst, gcnt, binbuf, E, nbuck, cap, epb, blockIdx.x, smem);
    else
        gemm1_body(x, W, asrc, adst, hh, als, ald, n, blockIdx.x - binBlocks, smem);
}

// ---------------- bscan + gmax4 (fused) ----------------

__device__ void bscan_body(const unsigned* __restrict__ gcnt, unsigned* __restrict__ gbase,
                           int* __restrict__ row, int n, int nbuck, int etot) {
    __shared__ unsigned s[256];
    int t = threadIdx.x;
    unsigned v = 0u;
    if (t < nbuck) {
        int nodes = min(NB, n - t * NB);
        v = gcnt[t] + (unsigned)nodes;
    }
    s[t] = v;
    __syncthreads();
    for (int off = 1; off < 256; off <<= 1) {
        unsigned x = (t >= off) ? s[t - off] : 0u;
        __syncthreads();
        s[t] += x;
        __syncthreads();
    }
    if (t < nbuck) gbase[t] = s[t] - v;  // exclusive
    if (t == 0) row[n] = etot;
}

__device__ void gmax4_body(const float4* __restrict__ als4, unsigned* gm, int n, int bid) {
    float m0 = -INFINITY, m1 = -INFINITY, m2 = -INFINITY, m3 = -INFINITY;
    for (int i = bid * 256 + threadIdx.x; i < n; i += 256 * 256) {
        float4 v = als4[i];
        m0 = fmaxf(m0, v.x); m1 = fmaxf(m1, v.y);
        m2 = fmaxf(m2, v.z); m3 = fmaxf(m3, v.w);
    }
#pragma unroll
    for (int off = 32; off; off >>= 1) {
        m0 = fmaxf(m0, __shfl_xor(m0, off));
        m1 = fmaxf(m1, __shfl_xor(m1, off));
        m2 = fmaxf(m2, __shfl_xor(m2, off));
        m3 = fmaxf(m3, __shfl_xor(m3, off));
    }
    __shared__ float sm[4][4];
    int wid = threadIdx.x >> 6;
    if ((threadIdx.x & 63) == 0) { sm[wid][0] = m0; sm[wid][1] = m1; sm[wid][2] = m2; sm[wid][3] = m3; }
    __syncthreads();
    if (threadIdx.x == 0) {
        float r0 = sm[0][0], r1 = sm[0][1], r2 = sm[0][2], r3 = sm[0][3];
        for (int w = 1; w < 4; w++) {
            r0 = fmaxf(r0, sm[w][0]); r1 = fmaxf(r1, sm[w][1]);
            r2 = fmaxf(r2, sm[w][2]); r3 = fmaxf(r3, sm[w][3]);
        }
        atomicMax(gm + 0, fenc(r0)); atomicMax(gm + 1, fenc(r1));
        atomicMax(gm + 2, fenc(r2)); atomicMax(gm + 3, fenc(r3));
    }
}

__global__ __launch_bounds__(256) void k_bscanGmax4(const unsigned* gcnt, unsigned* gbase,
                                                    int* row, int n, int nbuck, int etot,
                                                    const float4* als4, unsigned* gm) {
    if (blockIdx.x == 0)
        bscan_body(gcnt, gbase, row, n, nbuck, etot);
    else
        gmax4_body(als4, gm, n, blockIdx.x - 1);
}

__global__ __launch_bounds__(256) void k_build(const unsigned* __restrict__ gcnt, const unsigned* __restrict__ gbase,
                                               const unsigned* __restrict__ binbuf, int* __restrict__ row,
                                               int* __restrict__ csr, int n, int cap) {
    __shared__ int s_cnt[NB];
    __shared__ int s_off[NB];
    __shared__ int sums[256];
    int b = blockIdx.x;
    int t = threadIdx.x;
    int nn = min(NB, n - b * NB);
    int total = (int)gcnt[b];
    int base = (int)gbase[b];
    s_cnt[t] = 0; s_cnt[t + 256] = 0;
    __syncthreads();
    const unsigned* rec = binbuf + (size_t)b * cap;
    for (int r = t; r < total; r += 256) atomicAdd(&s_cnt[rec[r] & (NB - 1)], 1);
    __syncthreads();
    int i0 = 2 * t, i1 = 2 * t + 1;
    int v0 = (i0 < nn) ? s_cnt[i0] + 1 : 0;
    int v1 = (i1 < nn) ? s_cnt[i1] + 1 : 0;
    int ps = v0 + v1;
    sums[t] = ps;
    __syncthreads();
    for (int off = 1; off < 256; off <<= 1) {
        int x = (t >= off) ? sums[t - off] : 0;
        __syncthreads();
        sums[t] += x;
        __syncthreads();
    }
    int ex = sums[t] - ps;
    s_off[i0] = ex;
    s_off[i1] = ex + v0;
    if (i0 < nn) { row[b * NB + i0] = base + ex;      csr[base + ex]      = b * NB + i0; }
    if (i1 < nn) { row[b * NB + i1] = base + ex + v0; csr[base + ex + v0] = b * NB + i1; }
    __syncthreads();
    s_cnt[t] = 1; s_cnt[t + 256] = 1;   // cursor: slot 0 = self loop
    __syncthreads();
    for (int r = t; r < total; r += 256) {
        unsigned rc = rec[r];
        int ld = rc & (NB - 1);
        int p = atomicAdd(&s_cnt[ld], 1);
        csr[base + s_off[ld] + p] = (int)(rc >> NBSHIFT);
    }
}

__global__ __launch_bounds__(256) void k_gmax1(const float* __restrict__ als, unsigned* gm, int n) {
    float m = -INFINITY;
    for (int i = blockIdx.x * 256 + threadIdx.x; i < n; i += 256 * 256) m = fmaxf(m, als[i]);
#pragma unroll
    for (int off = 32; off; off >>= 1) m = fmaxf(m, __shfl_xor(m, off));
    __shared__ float sm[4];
    int wid = threadIdx.x >> 6;
    if ((threadIdx.x & 63) == 0) sm[wid] = m;
    __syncthreads();
    if (threadIdx.x == 0)
        atomicMax(gm, fenc(fmaxf(fmaxf(sm[0], sm[1]), fmaxf(sm[2], sm[3]))));
}

// wave per dst node, single edge pass, prep-then-broadcast (2-deep, R12),
// packed fp16 accumulation (R14).
__global__ __launch_bounds__(256) void k_agg1(const int* __restrict__ row, const int* __restrict__ csr,
                                              const float* __restrict__ als, const float* __restrict__ ald,
                                              const __half* __restrict__ h, const float* __restrict__ b,
                                              const unsigned* __restrict__ gmaxu, __half* __restrict__ out,
                                              int n) {
    int node = blockIdx.x * 4 + (threadIdx.x >> 6);
    if (node >= n) return;
    int lane = threadIdx.x & 63;
    int start = __builtin_amdgcn_readfirstlane(row[node]);
    int end   = __builtin_amdgcn_readfirstlane(row[node + 1]);

    int g = lane >> 4;
    int lig = lane & 15;
    int head = lig >> 2;

    float4 adv = *(const float4*)(ald + (size_t)node * 4);
    uint4 gu = *(const uint4*)gmaxu;
    float mt, mh0, mh1, mh2, mh3;
    mt = fdec(gu.x) + adv.x; mh0 = mt > 0.f ? mt : SLOPE * mt;
    mt = fdec(gu.y) + adv.y; mh1 = mt > 0.f ? mt : SLOPE * mt;
    mt = fdec(gu.z) + adv.z; mh2 = mt > 0.f ? mt : SLOPE * mt;
    mt = fdec(gu.w) + adv.w; mh3 = mt > 0.f ? mt : SLOPE * mt;

    const __half2 z2 = __floats2half2_rn(0.f, 0.f);
    float den0 = 0.f, den1 = 0.f, den2 = 0.f, den3 = 0.f;
    __half2 ah0 = z2, ah1 = z2, ah2 = z2, ah3 = z2;

    for (int k0 = start; k0 < end; k0 += 64) {
        int nb = end - k0; if (nb > 64) nb = 64;
        int s_l = (lane < nb) ? csr[k0 + lane] : 0;
        float4 av = *(const float4*)(als + (size_t)s_l * 4);
        float e, x0, x1, x2, x3;
        e = av.x + adv.x; e = e > 0.f ? e : SLOPE * e; x0 = __expf(e - mh0);
        e = av.y + adv.y; e = e > 0.f ? e : SLOPE * e; x1 = __expf(e - mh1);
        e = av.z + adv.z; e = e > 0.f ? e : SLOPE * e; x2 = __expf(e - mh2);
        e = av.w + adv.w; e = e > 0.f ? e : SLOPE * e; x3 = __expf(e - mh3);
        bool valid = lane < nb;
        x0 = valid ? x0 : 0.f; x1 = valid ? x1 : 0.f;
        x2 = valid ? x2 : 0.f; x3 = valid ? x3 : 0.f;
        den0 += x0; den1 += x1; den2 += x2; den3 += x3;
        __half2 p01 = __floats2half2_rn(x0, x1);
        __half2 p23 = __floats2half2_rn(x2, x3);
        int w01 = h22i(p01);
        int w23 = h22i(p23);

        for (int jj = 0; jj < nb; jj += 8) {
            int eA = jj + g;
            int eB = jj + 4 + g;
            int sA = __shfl(s_l, eA);
            int sB = __shfl(s_l, eB);
            int wA01 = __shfl(w01, eA);
            int wA23 = __shfl(w23, eA);
            int wB01 = __shfl(w01, eB);
            int wB23 = __shfl(w23, eB);
            int wA = (head & 2) ? wA23 : wA01;
            int wB = (head & 2) ? wB23 : wB01;
            uint4 hvA = *(const uint4*)(h + ((size_t)sA << 7) + lig * 8);
            uint4 hvB = *(const uint4*)(h + ((size_t)sB << 7) + lig * 8);
            __half exhA = (head & 1) ? __high2half(i2h2(wA)) : __low2half(i2h2(wA));
            __half exhB = (head & 1) ? __high2half(i2h2(wB)) : __low2half(i2h2(wB));
            __half2 exA2 = __half2half2(exhA);
            __half2 exB2 = __half2half2(exhB);
            exA2 = (eA < nb) ? exA2 : z2;
            exB2 = (eB < nb) ? exB2 : z2;
            ah0 = __hfma2(exA2, i2h2((int)hvA.x), ah0);
            ah1 = __hfma2(exA2, i2h2((int)hvA.y), ah1);
            ah2 = __hfma2(exA2, i2h2((int)hvA.z), ah2);
            ah3 = __hfma2(exA2, i2h2((int)hvA.w), ah3);
            ah0 = __hfma2(exB2, i2h2((int)hvB.x), ah0);
            ah1 = __hfma2(exB2, i2h2((int)hvB.y), ah1);
            ah2 = __hfma2(exB2, i2h2((int)hvB.z), ah2);
            ah3 = __hfma2(exB2, i2h2((int)hvB.w), ah3);
        }
    }
#pragma unroll
    for (int off = 32; off; off >>= 1) {
        den0 += __shfl_xor(den0, off);
        den1 += __shfl_xor(den1, off);
        den2 += __shfl_xor(den2, off);
        den3 += __shfl_xor(den3, off);
    }
    ah0 = __hadd2(ah0, h2shflxor(ah0, 16));
    ah1 = __hadd2(ah1, h2shflxor(ah1, 16));
    ah2 = __hadd2(ah2, h2shflxor(ah2, 16));
    ah3 = __hadd2(ah3, h2shflxor(ah3, 16));
    ah0 = __hadd2(ah0, h2shflxor(ah0, 32));
    ah1 = __hadd2(ah1, h2shflxor(ah1, 32));
    ah2 = __hadd2(ah2, h2shflxor(ah2, 32));
    ah3 = __hadd2(ah3, h2shflxor(ah3, 32));
    if (g == 0) {
        float den_h = (head & 2) ? ((head & 1) ? den3 : den2) : ((head & 1) ? den1 : den0);
        float inv = 1.f / den_h;
        float2 f0 = __half22float2(ah0);
        float2 f1 = __half22float2(ah1);
        float2 f2 = __half22float2(ah2);
        float2 f3 = __half22float2(ah3);
        float4 bv0 = *(const float4*)(b + lig * 8);
        float4 bv1 = *(const float4*)(b + lig * 8 + 4);
        float o0, o1, o2, o3, o4, o5, o6, o7;
        o0 = f0.x * inv + bv0.x; o0 = o0 > 0.f ? o0 : expm1f(o0);
        o1 = f0.y * inv + bv0.y; o1 = o1 > 0.f ? o1 : expm1f(o1);
        o2 = f1.x * inv + bv0.z; o2 = o2 > 0.f ? o2 : expm1f(o2);
        o3 = f1.y * inv + bv0.w; o3 = o3 > 0.f ? o3 : expm1f(o3);
        o4 = f2.x * inv + bv1.x; o4 = o4 > 0.f ? o4 : expm1f(o4);
        o5 = f2.y * inv + bv1.y; o5 = o5 > 0.f ? o5 : expm1f(o5);
        o6 = f3.x * inv + bv1.z; o6 = o6 > 0.f ? o6 : expm1f(o6);
        o7 = f3.y * inv + bv1.w; o7 = o7 > 0.f ? o7 : expm1f(o7);
        __half2 q0 = __floats2half2_rn(o0, o1);
        __half2 q1 = __floats2half2_rn(o2, o3);
        __half2 q2 = __floats2half2_rn(o4, o5);
        __half2 q3 = __floats2half2_rn(o6, o7);
        uint4 st;
        st.x = (unsigned)h22i(q0);
        st.y = (unsigned)h22i(q1);
        st.z = (unsigned)h22i(q2);
        st.w = (unsigned)h22i(q3);
        *(uint4*)(out + ((size_t)node << 7) + lig * 8) = st;
    }
}

// ------- Layer 2 GEMM: h2 = hm(fp16) @ W2 (128->40), fp16 out -------

__global__ __launch_bounds__(640) void k_gemm2(const __half* __restrict__ hm, const float* __restrict__ W2,
                                               __half* __restrict__ h2h, int n) {
    __shared__ float xs[16][128];
    __shared__ float ws[128 * 40];
    int t = threadIdx.x;
    int row0 = blockIdx.x * 16;
    for (int i = t; i < 128 * 40; i += 640) ws[i] = W2[i];
    if (t < 256) {
        int r = t >> 4, c8 = t & 15;
        int gr = row0 + r;
        float* d = &xs[r][c8 * 8];
        if (gr < n) {
            uint4 v = *(const uint4*)(hm + (size_t)gr * 128 + c8 * 8);
            float2 f0 = __half22float2(*reinterpret_cast<__half2*>(&v.x));
            float2 f1 = __half22float2(*reinterpret_cast<__half2*>(&v.y));
            float2 f2 = __half22float2(*reinterpret_cast<__half2*>(&v.z));
            float2 f3 = __half22float2(*reinterpret_cast<__half2*>(&v.w));
            d[0] = f0.x; d[1] = f0.y; d[2] = f1.x; d[3] = f1.y;
            d[4] = f2.x; d[5] = f2.y; d[6] = f3.x; d[7] = f3.y;
        } else {
            for (int j = 0; j < 8; j++) d[j] = 0.f;
        }
    }
    __syncthreads();
    int r = t / 40, c = t - r * 40;
    int gr = row0 + r;
    float acc = 0.f;
#pragma unroll 8
    for (int k = 0; k < 128; ++k) acc += xs[r][k] * ws[k * 40 + c];
    if (gr < n) h2h[(size_t)gr * 40 + c] = __float2half_rn(acc);
}

// wave per node; lanes 0-19 load 2 ch each (no atomics).
__global__ __launch_bounds__(256) void k_al2(const __half* __restrict__ h2, const float* __restrict__ a_s,
                                             const float* __restrict__ a_d, float* als, float* ald, int n) {
    int t = threadIdx.x;
    int node = blockIdx.x * 4 + (t >> 6);
    int l = t & 63;
    if (node >= n) return;
    float ps = 0.f, pd = 0.f;
    if (l < 20) {
        unsigned hv = *(const unsigned*)(h2 + (size_t)node * 40 + l * 2);
        float2 f = __half22float2(*reinterpret_cast<__half2*>(&hv));
        float2 vs = *(const float2*)(a_s + l * 2);
        float2 vd = *(const float2*)(a_d + l * 2);
        ps = f.x * vs.x + f.y * vs.y;
        pd = f.x * vd.x + f.y * vd.y;
    }
#pragma unroll
    for (int off = 32; off; off >>= 1) { ps += __shfl_xor(ps, off); pd += __shfl_xor(pd, off); }
    if (l == 0) { als[node] = ps; ald[node] = pd; }
}

// wave per node, single edge pass + log_softmax (2-deep, packed fp16 acc).
__global__ __launch_bounds__(256) void k_agg2(const int* __restrict__ row, const int* __restrict__ csr,
                                              const float* __restrict__ als, const float* __restrict__ ald,
                                              const __half* __restrict__ h2, const float* __restrict__ b2,
                                              const unsigned* __restrict__ gmaxu, float* __restrict__ out,
                                              int n) {
    int node = blockIdx.x * 4 + (threadIdx.x >> 6);
    if (node >= n) return;
    int lane = threadIdx.x & 63;
    int start = __builtin_amdgcn_readfirstlane(row[node]);
    int end   = __builtin_amdgcn_readfirstlane(row[node + 1]);
    float ad = ald[node];
    float mt = fdec(gmaxu[0]) + ad;
    float mh = mt > 0.f ? mt : SLOPE * mt;

    int g = lane / 5;
    int lig = lane - g * 5;
    bool act = g < 12;

    const __half2 z2 = __floats2half2_rn(0.f, 0.f);
    float den = 0.f;
    __half2 ah0 = z2, ah1 = z2, ah2 = z2, ah3 = z2;
    for (int k0 = start; k0 < end; k0 += 64) {
        int nb = end - k0; if (nb > 64) nb = 64;
        int s_l = (lane < nb) ? csr[k0 + lane] : 0;
        float e = als[s_l] + ad; e = e > 0.f ? e : SLOPE * e;
        float ex_l = __expf(e - mh);
        ex_l = (lane < nb) ? ex_l : 0.f;
        den += ex_l;
        __half exh_l = __float2half_rn(ex_l);
        int exi_l = h22i(__half2half2(exh_l));

        for (int jj = 0; jj < nb; jj += 24) {
            int eA = jj + g;
            int eB = jj + 12 + g;
            int sA = __shfl(s_l, eA & 63);
            int sB = __shfl(s_l, eB & 63);
            int exAi = __shfl(exi_l, eA & 63);
            int exBi = __shfl(exi_l, eB & 63);
            uint4 hvA = *(const uint4*)(h2 + (size_t)sA * 40 + lig * 8);
            uint4 hvB = *(const uint4*)(h2 + (size_t)sB * 40 + lig * 8);
            __half2 exA2 = i2h2(exAi);
            __half2 exB2 = i2h2(exBi);
            exA2 = (act && eA < nb) ? exA2 : z2;
            exB2 = (act && eB < nb) ? exB2 : z2;
            ah0 = __hfma2(exA2, i2h2((int)hvA.x), ah0);
            ah1 = __hfma2(exA2, i2h2((int)hvA.y), ah1);
            ah2 = __hfma2(exA2, i2h2((int)hvA.z), ah2);
            ah3 = __hfma2(exA2, i2h2((int)hvA.w), ah3);
            ah0 = __hfma2(exB2, i2h2((int)hvB.x), ah0);
            ah1 = __hfma2(exB2, i2h2((int)hvB.y), ah1);
            ah2 = __hfma2(exB2, i2h2((int)hvB.z), ah2);
            ah3 = __hfma2(exB2, i2h2((int)hvB.w), ah3);
        }
    }
#pragma unroll
    for (int off = 32; off; off >>= 1) den += __shfl_xor(den, off);
    int t1i;
    t1i = __shfl(h22i(ah0), (lane + 30) & 63); ah0 = __hadd2(ah0, i2h2(t1i));
    t1i = __shfl(h22i(ah1), (lane + 30) & 63); ah1 = __hadd2(ah1, i2h2(t1i));
    t1i = __shfl(h22i(ah2), (lane + 30) & 63); ah2 = __hadd2(ah2, i2h2(t1i));
    t1i = __shfl(h22i(ah3), (lane + 30) & 63); ah3 = __hadd2(ah3, i2h2(t1i));
    t1i = __shfl(h22i(ah0), (lane + 15) & 63); ah0 = __hadd2(ah0, i2h2(t1i));
    t1i = __shfl(h22i(ah1), (lane + 15) & 63); ah1 = __hadd2(ah1, i2h2(t1i));
    t1i = __shfl(h22i(ah2), (lane + 15) & 63); ah2 = __hadd2(ah2, i2h2(t1i));
    t1i = __shfl(h22i(ah3), (lane + 15) & 63); ah3 = __hadd2(ah3, i2h2(t1i));
    int t2i;
    t1i = __shfl(h22i(ah0), (lane + 5) & 63); t2i = __shfl(h22i(ah0), (lane + 10) & 63);
    ah0 = __hadd2(__hadd2(ah0, i2h2(t1i)), i2h2(t2i));
    t1i = __shfl(h22i(ah1), (lane + 5) & 63); t2i = __shfl(h22i(ah1), (lane + 10) & 63);
    ah1 = __hadd2(__hadd2(ah1, i2h2(t1i)), i2h2(t2i));
    t1i = __shfl(h22i(ah2), (lane + 5) & 63); t2i = __shfl(h22i(ah2), (lane + 10) & 63);
    ah2 = __hadd2(__hadd2(ah2, i2h2(t1i)), i2h2(t2i));
    t1i = __shfl(h22i(ah3), (lane + 5) & 63); t2i = __shfl(h22i(ah3), (lane + 10) & 63);
    ah3 = __hadd2(__hadd2(ah3, i2h2(t1i)), i2h2(t2i));

    float v0 = 0.f, v1 = 0.f, v2 = 0.f, v3 = 0.f, v4 = 0.f, v5 = 0.f, v6 = 0.f, v7 = 0.f;
    float mv = -INFINITY;
    if (lane < 5) {
        float inv = 1.f / den;
        float2 f0 = __half22float2(ah0);
        float2 f1 = __half22float2(ah1);
        float2 f2 = __half22float2(ah2);
        float2 f3 = __half22float2(ah3);
        float4 bv0 = *(const float4*)(b2 + lane * 8);
        float4 bv1 = *(const float4*)(b2 + lane * 8 + 4);
        v0 = f0.x * inv + bv0.x; v1 = f0.y * inv + bv0.y;
        v2 = f1.x * inv + bv0.z; v3 = f1.y * inv + bv0.w;
        v4 = f2.x * inv + bv1.x; v5 = f2.y * inv + bv1.y;
        v6 = f3.x * inv + bv1.z; v7 = f3.y * inv + bv1.w;
        mv = fmaxf(fmaxf(fmaxf(v0, v1), fmaxf(v2, v3)),
                   fmaxf(fmaxf(v4, v5), fmaxf(v6, v7)));
    }
#pragma unroll
    for (int off = 32; off; off >>= 1) mv = fmaxf(mv, __shfl_xor(mv, off));
    float se = 0.f;
    if (lane < 5)
        se = __expf(v0 - mv) + __expf(v1 - mv) + __expf(v2 - mv) + __expf(v3 - mv)
           + __expf(v4 - mv) + __expf(v5 - mv) + __expf(v6 - mv) + __expf(v7 - mv);
#pragma unroll
    for (int off = 32; off; off >>= 1) se += __shfl_xor(se, off);
    if (lane < 5) {
        float lse = mv + __logf(se);
        float4 o0, o1;
        o0.x = v0 - lse; o0.y = v1 - lse; o0.z = v2 - lse; o0.w = v3 - lse;
        o1.x = v4 - lse; o1.y = v5 - lse; o1.z = v6 - lse; o1.w = v7 - lse;
        *(float4*)(out + (size_t)node * 40 + lane * 8) = o0;
        *(float4*)(out + (size_t)node * 40 + lane * 8 + 4) = o1;
    }
}

// ---------------- launch ----------------

extern "C" void kernel_launch(void* const* d_in, const int* in_sizes, int n_in,
                              void* d_out, int out_size, void* d_ws, size_t ws_size,
                              hipStream_t stream) {
    const float* x   = (const float*)d_in[0];
    const int*   ei  = (const int*)d_in[1];
    const float* W1  = (const float*)d_in[2];
    const float* as1 = (const float*)d_in[3];
    const float* ad1 = (const float*)d_in[4];
    const float* b1  = (const float*)d_in[5];
    const float* W2  = (const float*)d_in[6];
    const float* as2 = (const float*)d_in[7];
    const float* ad2 = (const float*)d_in[8];
    const float* b2  = (const float*)d_in[9];
    float* out = (float*)d_out;

    int n = in_sizes[0] / 128;
    int E = in_sizes[1] / 2;
    const int* src = ei;
    const int* dst = ei + E;
    int etot = E + n;

    int nbuck = (n + NB - 1) / NB;
    int cap = (2 * (E / nbuck) + 1023) / 1024 * 1024;

    char* ws = (char*)d_ws;
    size_t off = 0;
    auto alloc = [&](size_t bytes) {
        void* p = ws + off;
        off += (bytes + 255) & ~(size_t)255;
        return p;
    };
    int*      rowp   = (int*)alloc((size_t)(n + 1) * 4);
    int*      csr    = (int*)alloc((size_t)etot * 4);
    __half*   h1h    = (__half*)alloc((size_t)n * 128 * 2);
    __half*   hmh    = (__half*)alloc((size_t)n * 128 * 2);
    float*    als1   = (float*)alloc((size_t)n * 4 * 4);
    float*    ald1   = (float*)alloc((size_t)n * 4 * 4);
    unsigned* gmaxu  = (unsigned*)alloc(256);
    unsigned* gcnt   = (unsigned*)alloc((size_t)nbuck * 4);
    unsigned* gbase  = (unsigned*)alloc((size_t)nbuck * 4);
    unsigned* binbuf = (unsigned*)alloc((size_t)nbuck * cap * 4);  // own region (concurrent with gemm1)
    __half* h2h = h1h;
    float* als2 = als1;
    float* ald2 = ald1;

    int epb = (E + 1023) / 1024;
    int binBlocks = 1024;
    int gemm1Blocks = (n + 31) / 32;

    hipMemsetAsync(gcnt, 0, (size_t)nbuck * 4, stream);
    hipMemsetAsync(gmaxu, 0, 32, stream);

    k_binGemm1<<<binBlocks + gemm1Blocks, 256, 0, stream>>>(
        src, dst, gcnt, binbuf, E, nbuck, cap, epb, binBlocks,
        x, W1, as1, ad1, h1h, als1, ald1, n);
    k_bscanGmax4<<<257, 256, 0, stream>>>(gcnt, gbase, rowp, n, nbuck, etot,
                                          (const float4*)als1, gmaxu);
    k_build<<<nbuck, 256, 0, stream>>>(gcnt, gbase, binbuf, rowp, csr, n, cap);
    k_agg1<<<(n + 3) / 4, 256, 0, stream>>>(rowp, csr, als1, ald1, h1h, b1, gmaxu, hmh, n);

    k_gemm2<<<(n + 15) / 16, 640, 0, stream>>>(hmh, W2, h2h, n);
    k_al2<<<(n + 3) / 4, 256, 0, stream>>>(h2h, as2, ad2, als2, ald2, n);
    k_gmax1<<<256, 256, 0, stream>>>(als2, gmaxu + 4, n);
    k_agg2<<<(n + 3) / 4, 256, 0, stream>>>(rowp, csr, als2, ald2, h2h, b2, gmaxu + 4, out, n);
}

// Round 19
// 356.711 us; speedup vs baseline: 1.0050x; 1.0050x over previous
//
#include <hip/hip_runtime.h>
#include <hip/hip_fp16.h>
#include <math.h>

// GAT node classification: 2 GATConv layers + ELU + log_softmax.
// N=100000, E=1600000 (+N self loops), IN=128, HEADS=4, HID=32, OUT=40.
//
// Rules learned:
//  - R4: every __shfl executes with ALL 64 lanes active; wave-uniform bounds;
//    predicate VALUES not control flow.
//  - R8: __shfl returns the SOURCE lane's evaluation of its operand.
//  - R9/R15: same-address atomics serialize at every level.
//  - R10: diff-check unrolled blocks line-by-line after mechanical edits.
//  - R12: 2-deep gather unroll is the sweet spot.
//  - R14: feature accumulation in packed fp16 (__hfma2); logits/dens f32.
//  - R17: independent kernels grid-fused; k_init -> hipMemsetAsync.
//  - R18: fused-kernel LDS = union via one smem buffer.
//  - R19: GEMM tile widened to 64 rows/block (8x4/thread) so staging
//    amortizes 2x; W layout = [c][kk] with +2 pad (17-stride reads,
//    conflict-free); k-quad layout REVERTED (staging scatter was 8-way).

#define SLOPE 0.2f
#define NB 512
#define NBSHIFT 9

#if defined(__has_builtin)
#if __has_builtin(__builtin_amdgcn_fdot2)
#define HAS_FDOT2 1
#endif
#endif

typedef _Float16 h2v __attribute__((ext_vector_type(2)));

__device__ __forceinline__ float dot2f(__half2 a, __half2 b, float c) {
#ifdef HAS_FDOT2
    return __builtin_amdgcn_fdot2(*reinterpret_cast<h2v*>(&a),
                                  *reinterpret_cast<h2v*>(&b), c, false);
#else
    float2 af = __half22float2(a), bf = __half22float2(b);
    return fmaf(af.y, bf.y, fmaf(af.x, bf.x, c));
#endif
}

__device__ __forceinline__ unsigned fenc(float f) {
    unsigned b = __float_as_uint(f);
    return (b & 0x80000000u) ? ~b : (b | 0x80000000u);
}
__device__ __forceinline__ float fdec(unsigned u) {
    return __uint_as_float((u & 0x80000000u) ? (u ^ 0x80000000u) : ~u);
}
__device__ __forceinline__ __half2 i2h2(int i) { return *reinterpret_cast<__half2*>(&i); }
__device__ __forceinline__ int h22i(__half2 h) { return *reinterpret_cast<int*>(&h); }
__device__ __forceinline__ __half2 h2shflxor(__half2 v, int off) {
    int j = __shfl_xor(h22i(v), off);
    return i2h2(j);
}

// ---------------- CSR bin (device body, smem-carved) ----------------

__device__ void bin_body(const int* __restrict__ src, const int* __restrict__ dst,
                         unsigned* __restrict__ gcnt, unsigned* __restrict__ binbuf,
                         int E, int nbuck, int cap, int epb, int bid, char* smem) {
    unsigned* hist = (unsigned*)smem;
    unsigned* base = hist + 256;
    unsigned* cur  = base + 256;
    int t = threadIdx.x;
    if (t < nbuck) { hist[t] = 0u; cur[t] = 0u; }
    __syncthreads();
    int e0 = bid * epb;
    int e1 = min(E, e0 + epb);
    for (int e = e0 + t; e < e1; e += 256) {
        int bk = dst[e] >> NBSHIFT;
        atomicAdd(&hist[bk], 1u);
    }
    __syncthreads();
    if (t < nbuck) base[t] = hist[t] ? atomicAdd(&gcnt[t], hist[t]) : 0u;
    __syncthreads();
    for (int e = e0 + t; e < e1; e += 256) {
        int d = dst[e];
        int bk = d >> NBSHIFT;
        unsigned p = atomicAdd(&cur[bk], 1u);
        binbuf[(size_t)bk * cap + base[bk] + p] =
            ((unsigned)src[e] << NBSHIFT) | (unsigned)(d & (NB - 1));
    }
}

// ------- Layer1 GEMM (64 rows/block, 8x4/thread) + fused al1 -------

__device__ void gemm1_body(const float* __restrict__ x, const float* __restrict__ W,
                           const float* __restrict__ asrc, const float* __restrict__ adst,
                           __half* __restrict__ hh, float* __restrict__ als,
                           float* __restrict__ ald, int n, int bid, char* smem) {
    __half2 (*xs2)[64] = (__half2(*)[64])smem;             // 16KB: [64][64]
    __half  (*wst)[34] = (__half(*)[34])(smem + 16384);    // 8.7KB: [c][kk], +2 pad
    int t = threadIdx.x;
    int row0 = bid * 64;
#pragma unroll
    for (int i = 0; i < 8; i++) {
        int flat = t + 256 * i;          // 2048 float4 slots
        int r = flat >> 5, c4 = flat & 31;
        int gr = row0 + r;
        float4 v = make_float4(0.f, 0.f, 0.f, 0.f);
        if (gr < n) v = ((const float4*)(x + (size_t)gr * 128))[c4];
        xs2[r][c4 * 2]     = __floats2half2_rn(v.x, v.y);
        xs2[r][c4 * 2 + 1] = __floats2half2_rn(v.z, v.w);
    }
    int ty = t >> 5;   // 0..7
    int tx = t & 31;   // 0..31
    float acc[8][4] = {};
    for (int kc = 0; kc < 4; ++kc) {
        __syncthreads();
        // stage W chunk transposed (R17 layout): wst[c][kk] = W[kc*32+kk][c]
#pragma unroll
        for (int i = 0; i < 4; i++) {
            int flat = t + 256 * i;
            int kk = flat >> 5, c4 = flat & 31;
            float4 v = ((const float4*)(W + (size_t)(kc * 32 + kk) * 128))[c4];
            wst[c4 * 4 + 0][kk] = __float2half_rn(v.x);
            wst[c4 * 4 + 1][kk] = __float2half_rn(v.y);
            wst[c4 * 4 + 2][kk] = __float2half_rn(v.z);
            wst[c4 * 4 + 3][kk] = __float2half_rn(v.w);
        }
        __syncthreads();
#pragma unroll
        for (int kk2 = 0; kk2 < 16; ++kk2) {
            __half2 wv[4];
#pragma unroll
            for (int j = 0; j < 4; j++)
                wv[j] = *(const __half2*)&wst[tx + 32 * j][kk2 * 2];
#pragma unroll
            for (int r = 0; r < 8; r++) {
                __half2 xv = xs2[ty + 8 * r][kc * 16 + kk2];
#pragma unroll
                for (int j = 0; j < 4; j++)
                    acc[r][j] = dot2f(xv, wv[j], acc[r][j]);
            }
        }
    }
    float vs0 = asrc[tx], vs1 = asrc[32 + tx], vs2 = asrc[64 + tx], vs3 = asrc[96 + tx];
    float vd0 = adst[tx], vd1 = adst[32 + tx], vd2 = adst[64 + tx], vd3 = adst[96 + tx];
#pragma unroll
    for (int r = 0; r < 8; r++) {
        int gr = row0 + ty + 8 * r;
        if (gr < n) {
#pragma unroll
            for (int j = 0; j < 4; j++)
                hh[(size_t)gr * 128 + tx + 32 * j] = __float2half_rn(acc[r][j]);
        }
        // fused al1: 32-lane shfl reduce (no atomics); all lanes execute (R4).
        float ps0 = acc[r][0] * vs0, ps1 = acc[r][1] * vs1;
        float ps2 = acc[r][2] * vs2, ps3 = acc[r][3] * vs3;
        float pd0 = acc[r][0] * vd0, pd1 = acc[r][1] * vd1;
        float pd2 = acc[r][2] * vd2, pd3 = acc[r][3] * vd3;
#pragma unroll
        for (int off = 1; off <= 16; off <<= 1) {
            ps0 += __shfl_xor(ps0, off); ps1 += __shfl_xor(ps1, off);
            ps2 += __shfl_xor(ps2, off); ps3 += __shfl_xor(ps3, off);
            pd0 += __shfl_xor(pd0, off); pd1 += __shfl_xor(pd1, off);
            pd2 += __shfl_xor(pd2, off); pd3 += __shfl_xor(pd3, off);
        }
        if (tx == 0 && gr < n) {
            float4 s4 = make_float4(ps0, ps1, ps2, ps3);
            float4 d4 = make_float4(pd0, pd1, pd2, pd3);
            *(float4*)(als + (size_t)gr * 4) = s4;
            *(float4*)(ald + (size_t)gr * 4) = d4;
        }
    }
}

// fused: blocks [0,binBlocks) bin; [binBlocks, ...) gemm1. Shared smem union.
__global__ __launch_bounds__(256) void k_binGemm1(const int* src, const int* dst,
                                                  unsigned* gcnt, unsigned* binbuf,
                                                  int E, int nbuck, int cap, int epb, int binBlocks,
                                                  const float* x, const float* W,
                                                  const float* asrc, const float* adst,
                                                  __half* hh, float* als, float* ald, int n) {
    __shared__ __align__(16) char smem[25088];
    if ((int)blockIdx.x < binBlocks)
        bin_body(src, dst, gcnt, binbuf, E, nbuck, cap, epb, blockIdx.x, smem);
    else
        gemm1_body(x, W, asrc, adst, hh, als, ald, n, blockIdx.x - binBlocks, smem);
}

// ---------------- bscan + gmax4 (fused) ----------------

__device__ void bscan_body(const unsigned* __restrict__ gcnt, unsigned* __restrict__ gbase,
                           int* __restrict__ row, int n, int nbuck, int etot) {
    __shared__ unsigned s[256];
    int t = threadIdx.x;
    unsigned v = 0u;
    if (t < nbuck) {
        int nodes = min(NB, n - t * NB);
        v = gcnt[t] + (unsigned)nodes;
    }
    s[t] = v;
    __syncthreads();
    for (int off = 1; off < 256; off <<= 1) {
        unsigned x = (t >= off) ? s[t - off] : 0u;
        __syncthreads();
        s[t] += x;
        __syncthreads();
    }
    if (t < nbuck) gbase[t] = s[t] - v;  // exclusive
    if (t == 0) row[n] = etot;
}

__device__ void gmax4_body(const float4* __restrict__ als4, unsigned* gm, int n, int bid) {
    float m0 = -INFINITY, m1 = -INFINITY, m2 = -INFINITY, m3 = -INFINITY;
    for (int i = bid * 256 + threadIdx.x; i < n; i += 256 * 256) {
        float4 v = als4[i];
        m0 = fmaxf(m0, v.x); m1 = fmaxf(m1, v.y);
        m2 = fmaxf(m2, v.z); m3 = fmaxf(m3, v.w);
    }
#pragma unroll
    for (int off = 32; off; off >>= 1) {
        m0 = fmaxf(m0, __shfl_xor(m0, off));
        m1 = fmaxf(m1, __shfl_xor(m1, off));
        m2 = fmaxf(m2, __shfl_xor(m2, off));
        m3 = fmaxf(m3, __shfl_xor(m3, off));
    }
    __shared__ float sm[4][4];
    int wid = threadIdx.x >> 6;
    if ((threadIdx.x & 63) == 0) { sm[wid][0] = m0; sm[wid][1] = m1; sm[wid][2] = m2; sm[wid][3] = m3; }
    __syncthreads();
    if (threadIdx.x == 0) {
        float r0 = sm[0][0], r1 = sm[0][1], r2 = sm[0][2], r3 = sm[0][3];
        for (int w = 1; w < 4; w++) {
            r0 = fmaxf(r0, sm[w][0]); r1 = fmaxf(r1, sm[w][1]);
            r2 = fmaxf(r2, sm[w][2]); r3 = fmaxf(r3, sm[w][3]);
        }
        atomicMax(gm + 0, fenc(r0)); atomicMax(gm + 1, fenc(r1));
        atomicMax(gm + 2, fenc(r2)); atomicMax(gm + 3, fenc(r3));
    }
}

__global__ __launch_bounds__(256) void k_bscanGmax4(const unsigned* gcnt, unsigned* gbase,
                                                    int* row, int n, int nbuck, int etot,
                                                    const float4* als4, unsigned* gm) {
    if (blockIdx.x == 0)
        bscan_body(gcnt, gbase, row, n, nbuck, etot);
    else
        gmax4_body(als4, gm, n, blockIdx.x - 1);
}

__global__ __launch_bounds__(256) void k_build(const unsigned* __restrict__ gcnt, const unsigned* __restrict__ gbase,
                                               const unsigned* __restrict__ binbuf, int* __restrict__ row,
                                               int* __restrict__ csr, int n, int cap) {
    __shared__ int s_cnt[NB];
    __shared__ int s_off[NB];
    __shared__ int sums[256];
    int b = blockIdx.x;
    int t = threadIdx.x;
    int nn = min(NB, n - b * NB);
    int total = (int)gcnt[b];
    int base = (int)gbase[b];
    s_cnt[t] = 0; s_cnt[t + 256] = 0;
    __syncthreads();
    const unsigned* rec = binbuf + (size_t)b * cap;
    for (int r = t; r < total; r += 256) atomicAdd(&s_cnt[rec[r] & (NB - 1)], 1);
    __syncthreads();
    int i0 = 2 * t, i1 = 2 * t + 1;
    int v0 = (i0 < nn) ? s_cnt[i0] + 1 : 0;
    int v1 = (i1 < nn) ? s_cnt[i1] + 1 : 0;
    int ps = v0 + v1;
    sums[t] = ps;
    __syncthreads();
    for (int off = 1; off < 256; off <<= 1) {
        int x = (t >= off) ? sums[t - off] : 0;
        __syncthreads();
        sums[t] += x;
        __syncthreads();
    }
    int ex = sums[t] - ps;
    s_off[i0] = ex;
    s_off[i1] = ex + v0;
    if (i0 < nn) { row[b * NB + i0] = base + ex;      csr[base + ex]      = b * NB + i0; }
    if (i1 < nn) { row[b * NB + i1] = base + ex + v0; csr[base + ex + v0] = b * NB + i1; }
    __syncthreads();
    s_cnt[t] = 1; s_cnt[t + 256] = 1;   // cursor: slot 0 = self loop
    __syncthreads();
    for (int r = t; r < total; r += 256) {
        unsigned rc = rec[r];
        int ld = rc & (NB - 1);
        int p = atomicAdd(&s_cnt[ld], 1);
        csr[base + s_off[ld] + p] = (int)(rc >> NBSHIFT);
    }
}

__global__ __launch_bounds__(256) void k_gmax1(const float* __restrict__ als, unsigned* gm, int n) {
    float m = -INFINITY;
    for (int i = blockIdx.x * 256 + threadIdx.x; i < n; i += 256 * 256) m = fmaxf(m, als[i]);
#pragma unroll
    for (int off = 32; off; off >>= 1) m = fmaxf(m, __shfl_xor(m, off));
    __shared__ float sm[4];
    int wid = threadIdx.x >> 6;
    if ((threadIdx.x & 63) == 0) sm[wid] = m;
    __syncthreads();
    if (threadIdx.x == 0)
        atomicMax(gm, fenc(fmaxf(fmaxf(sm[0], sm[1]), fmaxf(sm[2], sm[3]))));
}

// wave per dst node, single edge pass, prep-then-broadcast (2-deep, R12),
// packed fp16 accumulation (R14).
__global__ __launch_bounds__(256) void k_agg1(const int* __restrict__ row, const int* __restrict__ csr,
                                              const float* __restrict__ als, const float* __restrict__ ald,
                                              const __half* __restrict__ h, const float* __restrict__ b,
                                              const unsigned* __restrict__ gmaxu, __half* __restrict__ out,
                                              int n) {
    int node = blockIdx.x * 4 + (threadIdx.x >> 6);
    if (node >= n) return;
    int lane = threadIdx.x & 63;
    int start = __builtin_amdgcn_readfirstlane(row[node]);
    int end   = __builtin_amdgcn_readfirstlane(row[node + 1]);

    int g = lane >> 4;
    int lig = lane & 15;
    int head = lig >> 2;

    float4 adv = *(const float4*)(ald + (size_t)node * 4);
    uint4 gu = *(const uint4*)gmaxu;
    float mt, mh0, mh1, mh2, mh3;
    mt = fdec(gu.x) + adv.x; mh0 = mt > 0.f ? mt : SLOPE * mt;
    mt = fdec(gu.y) + adv.y; mh1 = mt > 0.f ? mt : SLOPE * mt;
    mt = fdec(gu.z) + adv.z; mh2 = mt > 0.f ? mt : SLOPE * mt;
    mt = fdec(gu.w) + adv.w; mh3 = mt > 0.f ? mt : SLOPE * mt;

    const __half2 z2 = __floats2half2_rn(0.f, 0.f);
    float den0 = 0.f, den1 = 0.f, den2 = 0.f, den3 = 0.f;
    __half2 ah0 = z2, ah1 = z2, ah2 = z2, ah3 = z2;

    for (int k0 = start; k0 < end; k0 += 64) {
        int nb = end - k0; if (nb > 64) nb = 64;
        int s_l = (lane < nb) ? csr[k0 + lane] : 0;
        float4 av = *(const float4*)(als + (size_t)s_l * 4);
        float e, x0, x1, x2, x3;
        e = av.x + adv.x; e = e > 0.f ? e : SLOPE * e; x0 = __expf(e - mh0);
        e = av.y + adv.y; e = e > 0.f ? e : SLOPE * e; x1 = __expf(e - mh1);
        e = av.z + adv.z; e = e > 0.f ? e : SLOPE * e; x2 = __expf(e - mh2);
        e = av.w + adv.w; e = e > 0.f ? e : SLOPE * e; x3 = __expf(e - mh3);
        bool valid = lane < nb;
        x0 = valid ? x0 : 0.f; x1 = valid ? x1 : 0.f;
        x2 = valid ? x2 : 0.f; x3 = valid ? x3 : 0.f;
        den0 += x0; den1 += x1; den2 += x2; den3 += x3;
        __half2 p01 = __floats2half2_rn(x0, x1);
        __half2 p23 = __floats2half2_rn(x2, x3);
        int w01 = h22i(p01);
        int w23 = h22i(p23);

        for (int jj = 0; jj < nb; jj += 8) {
            int eA = jj + g;
            int eB = jj + 4 + g;
            int sA = __shfl(s_l, eA);
            int sB = __shfl(s_l, eB);
            int wA01 = __shfl(w01, eA);
            int wA23 = __shfl(w23, eA);
            int wB01 = __shfl(w01, eB);
            int wB23 = __shfl(w23, eB);
            int wA = (head & 2) ? wA23 : wA01;
            int wB = (head & 2) ? wB23 : wB01;
            uint4 hvA = *(const uint4*)(h + ((size_t)sA << 7) + lig * 8);
            uint4 hvB = *(const uint4*)(h + ((size_t)sB << 7) + lig * 8);
            __half exhA = (head & 1) ? __high2half(i2h2(wA)) : __low2half(i2h2(wA));
            __half exhB = (head & 1) ? __high2half(i2h2(wB)) : __low2half(i2h2(wB));
            __half2 exA2 = __half2half2(exhA);
            __half2 exB2 = __half2half2(exhB);
            exA2 = (eA < nb) ? exA2 : z2;
            exB2 = (eB < nb) ? exB2 : z2;
            ah0 = __hfma2(exA2, i2h2((int)hvA.x), ah0);
            ah1 = __hfma2(exA2, i2h2((int)hvA.y), ah1);
            ah2 = __hfma2(exA2, i2h2((int)hvA.z), ah2);
            ah3 = __hfma2(exA2, i2h2((int)hvA.w), ah3);
            ah0 = __hfma2(exB2, i2h2((int)hvB.x), ah0);
            ah1 = __hfma2(exB2, i2h2((int)hvB.y), ah1);
            ah2 = __hfma2(exB2, i2h2((int)hvB.z), ah2);
            ah3 = __hfma2(exB2, i2h2((int)hvB.w), ah3);
        }
    }
#pragma unroll
    for (int off = 32; off; off >>= 1) {
        den0 += __shfl_xor(den0, off);
        den1 += __shfl_xor(den1, off);
        den2 += __shfl_xor(den2, off);
        den3 += __shfl_xor(den3, off);
    }
    ah0 = __hadd2(ah0, h2shflxor(ah0, 16));
    ah1 = __hadd2(ah1, h2shflxor(ah1, 16));
    ah2 = __hadd2(ah2, h2shflxor(ah2, 16));
    ah3 = __hadd2(ah3, h2shflxor(ah3, 16));
    ah0 = __hadd2(ah0, h2shflxor(ah0, 32));
    ah1 = __hadd2(ah1, h2shflxor(ah1, 32));
    ah2 = __hadd2(ah2, h2shflxor(ah2, 32));
    ah3 = __hadd2(ah3, h2shflxor(ah3, 32));
    if (g == 0) {
        float den_h = (head & 2) ? ((head & 1) ? den3 : den2) : ((head & 1) ? den1 : den0);
        float inv = 1.f / den_h;
        float2 f0 = __half22float2(ah0);
        float2 f1 = __half22float2(ah1);
        float2 f2 = __half22float2(ah2);
        float2 f3 = __half22float2(ah3);
        float4 bv0 = *(const float4*)(b + lig * 8);
        float4 bv1 = *(const float4*)(b + lig * 8 + 4);
        float o0, o1, o2, o3, o4, o5, o6, o7;
        o0 = f0.x * inv + bv0.x; o0 = o0 > 0.f ? o0 : expm1f(o0);
        o1 = f0.y * inv + bv0.y; o1 = o1 > 0.f ? o1 : expm1f(o1);
        o2 = f1.x * inv + bv0.z; o2 = o2 > 0.f ? o2 : expm1f(o2);
        o3 = f1.y * inv + bv0.w; o3 = o3 > 0.f ? o3 : expm1f(o3);
        o4 = f2.x * inv + bv1.x; o4 = o4 > 0.f ? o4 : expm1f(o4);
        o5 = f2.y * inv + bv1.y; o5 = o5 > 0.f ? o5 : expm1f(o5);
        o6 = f3.x * inv + bv1.z; o6 = o6 > 0.f ? o6 : expm1f(o6);
        o7 = f3.y * inv + bv1.w; o7 = o7 > 0.f ? o7 : expm1f(o7);
        __half2 q0 = __floats2half2_rn(o0, o1);
        __half2 q1 = __floats2half2_rn(o2, o3);
        __half2 q2 = __floats2half2_rn(o4, o5);
        __half2 q3 = __floats2half2_rn(o6, o7);
        uint4 st;
        st.x = (unsigned)h22i(q0);
        st.y = (unsigned)h22i(q1);
        st.z = (unsigned)h22i(q2);
        st.w = (unsigned)h22i(q3);
        *(uint4*)(out + ((size_t)node << 7) + lig * 8) = st;
    }
}

// ------- Layer 2 GEMM: h2 = hm(fp16) @ W2 (128->40), fp16 out -------

__global__ __launch_bounds__(640) void k_gemm2(const __half* __restrict__ hm, const float* __restrict__ W2,
                                               __half* __restrict__ h2h, int n) {
    __shared__ float xs[16][128];
    __shared__ float ws[128 * 40];
    int t = threadIdx.x;
    int row0 = blockIdx.x * 16;
    for (int i = t; i < 128 * 40; i += 640) ws[i] = W2[i];
    if (t < 256) {
        int r = t >> 4, c8 = t & 15;
        int gr = row0 + r;
        float* d = &xs[r][c8 * 8];
        if (gr < n) {
            uint4 v = *(const uint4*)(hm + (size_t)gr * 128 + c8 * 8);
            float2 f0 = __half22float2(*reinterpret_cast<__half2*>(&v.x));
            float2 f1 = __half22float2(*reinterpret_cast<__half2*>(&v.y));
            float2 f2 = __half22float2(*reinterpret_cast<__half2*>(&v.z));
            float2 f3 = __half22float2(*reinterpret_cast<__half2*>(&v.w));
            d[0] = f0.x; d[1] = f0.y; d[2] = f1.x; d[3] = f1.y;
            d[4] = f2.x; d[5] = f2.y; d[6] = f3.x; d[7] = f3.y;
        } else {
            for (int j = 0; j < 8; j++) d[j] = 0.f;
        }
    }
    __syncthreads();
    int r = t / 40, c = t - r * 40;
    int gr = row0 + r;
    float acc = 0.f;
#pragma unroll 8
    for (int k = 0; k < 128; ++k) acc += xs[r][k] * ws[k * 40 + c];
    if (gr < n) h2h[(size_t)gr * 40 + c] = __float2half_rn(acc);
}

// wave per node; lanes 0-19 load 2 ch each (no atomics).
__global__ __launch_bounds__(256) void k_al2(const __half* __restrict__ h2, const float* __restrict__ a_s,
                                             const float* __restrict__ a_d, float* als, float* ald, int n) {
    int t = threadIdx.x;
    int node = blockIdx.x * 4 + (t >> 6);
    int l = t & 63;
    if (node >= n) return;
    float ps = 0.f, pd = 0.f;
    if (l < 20) {
        unsigned hv = *(const unsigned*)(h2 + (size_t)node * 40 + l * 2);
        float2 f = __half22float2(*reinterpret_cast<__half2*>(&hv));
        float2 vs = *(const float2*)(a_s + l * 2);
        float2 vd = *(const float2*)(a_d + l * 2);
        ps = f.x * vs.x + f.y * vs.y;
        pd = f.x * vd.x + f.y * vd.y;
    }
#pragma unroll
    for (int off = 32; off; off >>= 1) { ps += __shfl_xor(ps, off); pd += __shfl_xor(pd, off); }
    if (l == 0) { als[node] = ps; ald[node] = pd; }
}

// wave per node, single edge pass + log_softmax (2-deep, packed fp16 acc).
__global__ __launch_bounds__(256) void k_agg2(const int* __restrict__ row, const int* __restrict__ csr,
                                              const float* __restrict__ als, const float* __restrict__ ald,
                                              const __half* __restrict__ h2, const float* __restrict__ b2,
                                              const unsigned* __restrict__ gmaxu, float* __restrict__ out,
                                              int n) {
    int node = blockIdx.x * 4 + (threadIdx.x >> 6);
    if (node >= n) return;
    int lane = threadIdx.x & 63;
    int start = __builtin_amdgcn_readfirstlane(row[node]);
    int end   = __builtin_amdgcn_readfirstlane(row[node + 1]);
    float ad = ald[node];
    float mt = fdec(gmaxu[0]) + ad;
    float mh = mt > 0.f ? mt : SLOPE * mt;

    int g = lane / 5;
    int lig = lane - g * 5;
    bool act = g < 12;

    const __half2 z2 = __floats2half2_rn(0.f, 0.f);
    float den = 0.f;
    __half2 ah0 = z2, ah1 = z2, ah2 = z2, ah3 = z2;
    for (int k0 = start; k0 < end; k0 += 64) {
        int nb = end - k0; if (nb > 64) nb = 64;
        int s_l = (lane < nb) ? csr[k0 + lane] : 0;
        float e = als[s_l] + ad; e = e > 0.f ? e : SLOPE * e;
        float ex_l = __expf(e - mh);
        ex_l = (lane < nb) ? ex_l : 0.f;
        den += ex_l;
        __half exh_l = __float2half_rn(ex_l);
        int exi_l = h22i(__half2half2(exh_l));

        for (int jj = 0; jj < nb; jj += 24) {
            int eA = jj + g;
            int eB = jj + 12 + g;
            int sA = __shfl(s_l, eA & 63);
            int sB = __shfl(s_l, eB & 63);
            int exAi = __shfl(exi_l, eA & 63);
            int exBi = __shfl(exi_l, eB & 63);
            uint4 hvA = *(const uint4*)(h2 + (size_t)sA * 40 + lig * 8);
            uint4 hvB = *(const uint4*)(h2 + (size_t)sB * 40 + lig * 8);
            __half2 exA2 = i2h2(exAi);
            __half2 exB2 = i2h2(exBi);
            exA2 = (act && eA < nb) ? exA2 : z2;
            exB2 = (act && eB < nb) ? exB2 : z2;
            ah0 = __hfma2(exA2, i2h2((int)hvA.x), ah0);
            ah1 = __hfma2(exA2, i2h2((int)hvA.y), ah1);
            ah2 = __hfma2(exA2, i2h2((int)hvA.z), ah2);
            ah3 = __hfma2(exA2, i2h2((int)hvA.w), ah3);
            ah0 = __hfma2(exB2, i2h2((int)hvB.x), ah0);
            ah1 = __hfma2(exB2, i2h2((int)hvB.y), ah1);
            ah2 = __hfma2(exB2, i2h2((int)hvB.z), ah2);
            ah3 = __hfma2(exB2, i2h2((int)hvB.w), ah3);
        }
    }
#pragma unroll
    for (int off = 32; off; off >>= 1) den += __shfl_xor(den, off);
    int t1i;
    t1i = __shfl(h22i(ah0), (lane + 30) & 63); ah0 = __hadd2(ah0, i2h2(t1i));
    t1i = __shfl(h22i(ah1), (lane + 30) & 63); ah1 = __hadd2(ah1, i2h2(t1i));
    t1i = __shfl(h22i(ah2), (lane + 30) & 63); ah2 = __hadd2(ah2, i2h2(t1i));
    t1i = __shfl(h22i(ah3), (lane + 30) & 63); ah3 = __hadd2(ah3, i2h2(t1i));
    t1i = __shfl(h22i(ah0), (lane + 15) & 63); ah0 = __hadd2(ah0, i2h2(t1i));
    t1i = __shfl(h22i(ah1), (lane + 15) & 63); ah1 = __hadd2(ah1, i2h2(t1i));
    t1i = __shfl(h22i(ah2), (lane + 15) & 63); ah2 = __hadd2(ah2, i2h2(t1i));
    t1i = __shfl(h22i(ah3), (lane + 15) & 63); ah3 = __hadd2(ah3, i2h2(t1i));
    int t2i;
    t1i = __shfl(h22i(ah0), (lane + 5) & 63); t2i = __shfl(h22i(ah0), (lane + 10) & 63);
    ah0 = __hadd2(__hadd2(ah0, i2h2(t1i)), i2h2(t2i));
    t1i = __shfl(h22i(ah1), (lane + 5) & 63); t2i = __shfl(h22i(ah1), (lane + 10) & 63);
    ah1 = __hadd2(__hadd2(ah1, i2h2(t1i)), i2h2(t2i));
    t1i = __shfl(h22i(ah2), (lane + 5) & 63); t2i = __shfl(h22i(ah2), (lane + 10) & 63);
    ah2 = __hadd2(__hadd2(ah2, i2h2(t1i)), i2h2(t2i));
    t1i = __shfl(h22i(ah3), (lane + 5) & 63); t2i = __shfl(h22i(ah3), (lane + 10) & 63);
    ah3 = __hadd2(__hadd2(ah3, i2h2(t1i)), i2h2(t2i));

    float v0 = 0.f, v1 = 0.f, v2 = 0.f, v3 = 0.f, v4 = 0.f, v5 = 0.f, v6 = 0.f, v7 = 0.f;
    float mv = -INFINITY;
    if (lane < 5) {
        float inv = 1.f / den;
        float2 f0 = __half22float2(ah0);
        float2 f1 = __half22float2(ah1);
        float2 f2 = __half22float2(ah2);
        float2 f3 = __half22float2(ah3);
        float4 bv0 = *(const float4*)(b2 + lane * 8);
        float4 bv1 = *(const float4*)(b2 + lane * 8 + 4);
        v0 = f0.x * inv + bv0.x; v1 = f0.y * inv + bv0.y;
        v2 = f1.x * inv + bv0.z; v3 = f1.y * inv + bv0.w;
        v4 = f2.x * inv + bv1.x; v5 = f2.y * inv + bv1.y;
        v6 = f3.x * inv + bv1.z; v7 = f3.y * inv + bv1.w;
        mv = fmaxf(fmaxf(fmaxf(v0, v1), fmaxf(v2, v3)),
                   fmaxf(fmaxf(v4, v5), fmaxf(v6, v7)));
    }
#pragma unroll
    for (int off = 32; off; off >>= 1) mv = fmaxf(mv, __shfl_xor(mv, off));
    float se = 0.f;
    if (lane < 5)
        se = __expf(v0 - mv) + __expf(v1 - mv) + __expf(v2 - mv) + __expf(v3 - mv)
           + __expf(v4 - mv) + __expf(v5 - mv) + __expf(v6 - mv) + __expf(v7 - mv);
#pragma unroll
    for (int off = 32; off; off >>= 1) se += __shfl_xor(se, off);
    if (lane < 5) {
        float lse = mv + __logf(se);
        float4 o0, o1;
        o0.x = v0 - lse; o0.y = v1 - lse; o0.z = v2 - lse; o0.w = v3 - lse;
        o1.x = v4 - lse; o1.y = v5 - lse; o1.z = v6 - lse; o1.w = v7 - lse;
        *(float4*)(out + (size_t)node * 40 + lane * 8) = o0;
        *(float4*)(out + (size_t)node * 40 + lane * 8 + 4) = o1;
    }
}

// ---------------- launch ----------------

extern "C" void kernel_launch(void* const* d_in, const int* in_sizes, int n_in,
                              void* d_out, int out_size, void* d_ws, size_t ws_size,
                              hipStream_t stream) {
    const float* x   = (const float*)d_in[0];
    const int*   ei  = (const int*)d_in[1];
    const float* W1  = (const float*)d_in[2];
    const float* as1 = (const float*)d_in[3];
    const float* ad1 = (const float*)d_in[4];
    const float* b1  = (const float*)d_in[5];
    const float* W2  = (const float*)d_in[6];
    const float* as2 = (const float*)d_in[7];
    const float* ad2 = (const float*)d_in[8];
    const float* b2  = (const float*)d_in[9];
    float* out = (float*)d_out;

    int n = in_sizes[0] / 128;
    int E = in_sizes[1] / 2;
    const int* src = ei;
    const int* dst = ei + E;
    int etot = E + n;

    int nbuck = (n + NB - 1) / NB;
    int cap = (2 * (E / nbuck) + 1023) / 1024 * 1024;

    char* ws = (char*)d_ws;
    size_t off = 0;
    auto alloc = [&](size_t bytes) {
        void* p = ws + off;
        off += (bytes + 255) & ~(size_t)255;
        return p;
    };
    int*      rowp   = (int*)alloc((size_t)(n + 1) * 4);
    int*      csr    = (int*)alloc((size_t)etot * 4);
    __half*   h1h    = (__half*)alloc((size_t)n * 128 * 2);
    __half*   hmh    = (__half*)alloc((size_t)n * 128 * 2);
    float*    als1   = (float*)alloc((size_t)n * 4 * 4);
    float*    ald1   = (float*)alloc((size_t)n * 4 * 4);
    unsigned* gmaxu  = (unsigned*)alloc(256);
    unsigned* gcnt   = (unsigned*)alloc((size_t)nbuck * 4);
    unsigned* gbase  = (unsigned*)alloc((size_t)nbuck * 4);
    unsigned* binbuf = (unsigned*)alloc((size_t)nbuck * cap * 4);  // own region (concurrent with gemm1)
    __half* h2h = h1h;
    float* als2 = als1;
    float* ald2 = ald1;

    int epb = (E + 1023) / 1024;
    int binBlocks = 1024;
    int gemm1Blocks = (n + 63) / 64;

    hipMemsetAsync(gcnt, 0, (size_t)nbuck * 4, stream);
    hipMemsetAsync(gmaxu, 0, 32, stream);

    k_binGemm1<<<binBlocks + gemm1Blocks, 256, 0, stream>>>(
        src, dst, gcnt, binbuf, E, nbuck, cap, epb, binBlocks,
        x, W1, as1, ad1, h1h, als1, ald1, n);
    k_bscanGmax4<<<257, 256, 0, stream>>>(gcnt, gbase, rowp, n, nbuck, etot,
                                          (const float4*)als1, gmaxu);
    k_build<<<nbuck, 256, 0, stream>>>(gcnt, gbase, binbuf, rowp, csr, n, cap);
    k_agg1<<<(n + 3) / 4, 256, 0, stream>>>(rowp, csr, als1, ald1, h1h, b1, gmaxu, hmh, n);

    k_gemm2<<<(n + 15) / 16, 640, 0, stream>>>(hmh, W2, h2h, n);
    k_al2<<<(n + 3) / 4, 256, 0, stream>>>(h2h, as2, ad2, als2, ald2, n);
    k_gmax1<<<256, 256, 0, stream>>>(als2, gmaxu + 4, n);
    k_agg2<<<(n + 3) / 4, 256, 0, stream>>>(rowp, csr, als2, ald2, h2h, b2, gmaxu + 4, out, n);
}

// Round 20
// 339.017 us; speedup vs baseline: 1.0575x; 1.0522x over previous
//
#include <hip/hip_runtime.h>
#include <hip/hip_fp16.h>
#include <math.h>

// GAT node classification: 2 GATConv layers + ELU + log_softmax.
// N=100000, E=1600000 (+N self loops), IN=128, HEADS=4, HID=32, OUT=40.
//
// Rules learned:
//  - R4: every __shfl executes with ALL 64 lanes active; wave-uniform bounds;
//    predicate VALUES not control flow.
//  - R8: __shfl returns the SOURCE lane's evaluation of its operand.
//  - R9/R15: same-address atomics serialize at every level.
//  - R10: diff-check unrolled blocks line-by-line after mechanical edits.
//  - R12: 2-deep gather unroll is the sweet spot.
//  - R14: feature accumulation in packed fp16 (__hfma2); logits/dens f32.
//  - R17: independent kernels grid-fused; k_init -> hipMemsetAsync.
//  - R18: fused-kernel LDS = union via one smem buffer.
//  - R20: gemm1 on MFMA (mfma_f32_16x16x32_f16). C layout (HW-verified):
//    col=lane&15, row=(lane>>4)*4+reg. A/B k-order chosen IDENTICALLY for
//    both operands (k = kc*32 + (lane>>4)*8 + i) so any common hardware
//    k-permutation cancels. B-fragments read from global W^T(f16), L2-hot.

#define SLOPE 0.2f
#define NB 512
#define NBSHIFT 9

typedef _Float16 f16x8 __attribute__((ext_vector_type(8)));
typedef float f32x4 __attribute__((ext_vector_type(4)));

__device__ __forceinline__ unsigned fenc(float f) {
    unsigned b = __float_as_uint(f);
    return (b & 0x80000000u) ? ~b : (b | 0x80000000u);
}
__device__ __forceinline__ float fdec(unsigned u) {
    return __uint_as_float((u & 0x80000000u) ? (u ^ 0x80000000u) : ~u);
}
__device__ __forceinline__ __half2 i2h2(int i) { return *reinterpret_cast<__half2*>(&i); }
__device__ __forceinline__ int h22i(__half2 h) { return *reinterpret_cast<int*>(&h); }
__device__ __forceinline__ __half2 h2shflxor(__half2 v, int off) {
    int j = __shfl_xor(h22i(v), off);
    return i2h2(j);
}

// ---------------- W transpose to f16: wt[c][k] = W[k][c] ----------------

__global__ __launch_bounds__(256) void k_wt(const float* __restrict__ W, __half* __restrict__ wt) {
    int idx = blockIdx.x * 256 + threadIdx.x;   // 16384 elements
    int k = idx & 127, c = idx >> 7;
    wt[(size_t)c * 128 + k] = __float2half_rn(W[(size_t)k * 128 + c]);
}

// ---------------- CSR bin (device body, smem-carved) ----------------

__device__ void bin_body(const int* __restrict__ src, const int* __restrict__ dst,
                         unsigned* __restrict__ gcnt, unsigned* __restrict__ binbuf,
                         int E, int nbuck, int cap, int epb, int bid, char* smem) {
    unsigned* hist = (unsigned*)smem;
    unsigned* base = hist + 256;
    unsigned* cur  = base + 256;
    int t = threadIdx.x;
    if (t < nbuck) { hist[t] = 0u; cur[t] = 0u; }
    __syncthreads();
    int e0 = bid * epb;
    int e1 = min(E, e0 + epb);
    for (int e = e0 + t; e < e1; e += 256) {
        int bk = dst[e] >> NBSHIFT;
        atomicAdd(&hist[bk], 1u);
    }
    __syncthreads();
    if (t < nbuck) base[t] = hist[t] ? atomicAdd(&gcnt[t], hist[t]) : 0u;
    __syncthreads();
    for (int e = e0 + t; e < e1; e += 256) {
        int d = dst[e];
        int bk = d >> NBSHIFT;
        unsigned p = atomicAdd(&cur[bk], 1u);
        binbuf[(size_t)bk * cap + base[bk] + p] =
            ((unsigned)src[e] << NBSHIFT) | (unsigned)(d & (NB - 1));
    }
}

// ------- Layer1 GEMM via MFMA (64 rows/block, 4 waves) + fused al1 -------

__device__ void gemm1_body(const float* __restrict__ x, const __half* __restrict__ wt,
                           const float* __restrict__ asrc, const float* __restrict__ adst,
                           __half* __restrict__ hh, float* __restrict__ als,
                           float* __restrict__ ald, int n, int bid, char* smem) {
    __half* xs = (__half*)smem;          // [64][136] padded (2-way-free banks)
    int t = threadIdx.x;
    int row0 = bid * 64;
#pragma unroll
    for (int i = 0; i < 8; i++) {
        int flat = t + 256 * i;          // 2048 float4 slots
        int r = flat >> 5, c4 = flat & 31;
        int gr = row0 + r;
        float4 v = make_float4(0.f, 0.f, 0.f, 0.f);
        if (gr < n) v = ((const float4*)(x + (size_t)gr * 128))[c4];
        __half2* p = (__half2*)&xs[r * 136 + c4 * 4];
        p[0] = __floats2half2_rn(v.x, v.y);
        p[1] = __floats2half2_rn(v.z, v.w);
    }
    __syncthreads();
    int w = t >> 6;        // wave 0..3 -> rows row0 + w*16 .. +15
    int l = t & 63;
    int cc = l & 15;       // A row within tile; C col within tile
    int g  = l >> 4;       // k-group
    int R  = row0 + w * 16 + g * 4;   // C rows R..R+3 (reg 0..3)

    f32x4 acc[8] = {};     // 8 col-tiles (cols 16j .. 16j+15)
#pragma unroll
    for (int kc = 0; kc < 4; kc++) {
        f16x8 af = *(const f16x8*)&xs[(w * 16 + cc) * 136 + kc * 32 + g * 8];
#pragma unroll
        for (int j = 0; j < 8; j++) {
            f16x8 bf = *(const f16x8*)&wt[(size_t)(16 * j + cc) * 128 + kc * 32 + g * 8];
            acc[j] = __builtin_amdgcn_mfma_f32_16x16x32_f16(af, bf, acc[j], 0, 0, 0);
        }
    }
    // attention vectors at this lane's columns (channel 16j+cc, head j>>1)
    float vsx[8], vdx[8];
#pragma unroll
    for (int j = 0; j < 8; j++) { vsx[j] = asrc[16 * j + cc]; vdx[j] = adst[16 * j + cc]; }
#pragma unroll
    for (int reg = 0; reg < 4; reg++) {
        int gr = R + reg;
        if (gr < n) {
#pragma unroll
            for (int j = 0; j < 8; j++)
                hh[(size_t)gr * 128 + 16 * j + cc] = __float2half_rn(acc[j][reg]);
        }
        // fused al1: per-head dot; reduce over the 16-lane cc group
        // (shfl_xor offsets 1..8 stay inside the group; all lanes run -- R4).
        float ps0 = acc[0][reg] * vsx[0] + acc[1][reg] * vsx[1];
        float ps1 = acc[2][reg] * vsx[2] + acc[3][reg] * vsx[3];
        float ps2 = acc[4][reg] * vsx[4] + acc[5][reg] * vsx[5];
        float ps3 = acc[6][reg] * vsx[6] + acc[7][reg] * vsx[7];
        float pd0 = acc[0][reg] * vdx[0] + acc[1][reg] * vdx[1];
        float pd1 = acc[2][reg] * vdx[2] + acc[3][reg] * vdx[3];
        float pd2 = acc[4][reg] * vdx[4] + acc[5][reg] * vdx[5];
        float pd3 = acc[6][reg] * vdx[6] + acc[7][reg] * vdx[7];
#pragma unroll
        for (int off = 1; off <= 8; off <<= 1) {
            ps0 += __shfl_xor(ps0, off); ps1 += __shfl_xor(ps1, off);
            ps2 += __shfl_xor(ps2, off); ps3 += __shfl_xor(ps3, off);
            pd0 += __shfl_xor(pd0, off); pd1 += __shfl_xor(pd1, off);
            pd2 += __shfl_xor(pd2, off); pd3 += __shfl_xor(pd3, off);
        }
        if (cc == 0 && gr < n) {
            *(float4*)(als + (size_t)gr * 4) = make_float4(ps0, ps1, ps2, ps3);
            *(float4*)(ald + (size_t)gr * 4) = make_float4(pd0, pd1, pd2, pd3);
        }
    }
}

// fused: blocks [0,binBlocks) bin; [binBlocks, ...) gemm1. Shared smem union.
__global__ __launch_bounds__(256) void k_binGemm1(const int* src, const int* dst,
                                                  unsigned* gcnt, unsigned* binbuf,
                                                  int E, int nbuck, int cap, int epb, int binBlocks,
                                                  const float* x, const __half* wt,
                                                  const float* asrc, const float* adst,
                                                  __half* hh, float* als, float* ald, int n) {
    __shared__ __align__(16) char smem[17408];
    if ((int)blockIdx.x < binBlocks)
        bin_body(src, dst, gcnt, binbuf, E, nbuck, cap, epb, blockIdx.x, smem);
    else
        gemm1_body(x, wt, asrc, adst, hh, als, ald, n, blockIdx.x - binBlocks, smem);
}

// ---------------- bscan + gmax4 (fused) ----------------

__device__ void bscan_body(const unsigned* __restrict__ gcnt, unsigned* __restrict__ gbase,
                           int* __restrict__ row, int n, int nbuck, int etot) {
    __shared__ unsigned s[256];
    int t = threadIdx.x;
    unsigned v = 0u;
    if (t < nbuck) {
        int nodes = min(NB, n - t * NB);
        v = gcnt[t] + (unsigned)nodes;
    }
    s[t] = v;
    __syncthreads();
    for (int off = 1; off < 256; off <<= 1) {
        unsigned x = (t >= off) ? s[t - off] : 0u;
        __syncthreads();
        s[t] += x;
        __syncthreads();
    }
    if (t < nbuck) gbase[t] = s[t] - v;  // exclusive
    if (t == 0) row[n] = etot;
}

__device__ void gmax4_body(const float4* __restrict__ als4, unsigned* gm, int n, int bid) {
    float m0 = -INFINITY, m1 = -INFINITY, m2 = -INFINITY, m3 = -INFINITY;
    for (int i = bid * 256 + threadIdx.x; i < n; i += 256 * 256) {
        float4 v = als4[i];
        m0 = fmaxf(m0, v.x); m1 = fmaxf(m1, v.y);
        m2 = fmaxf(m2, v.z); m3 = fmaxf(m3, v.w);
    }
#pragma unroll
    for (int off = 32; off; off >>= 1) {
        m0 = fmaxf(m0, __shfl_xor(m0, off));
        m1 = fmaxf(m1, __shfl_xor(m1, off));
        m2 = fmaxf(m2, __shfl_xor(m2, off));
        m3 = fmaxf(m3, __shfl_xor(m3, off));
    }
    __shared__ float sm[4][4];
    int wid = threadIdx.x >> 6;
    if ((threadIdx.x & 63) == 0) { sm[wid][0] = m0; sm[wid][1] = m1; sm[wid][2] = m2; sm[wid][3] = m3; }
    __syncthreads();
    if (threadIdx.x == 0) {
        float r0 = sm[0][0], r1 = sm[0][1], r2 = sm[0][2], r3 = sm[0][3];
        for (int w = 1; w < 4; w++) {
            r0 = fmaxf(r0, sm[w][0]); r1 = fmaxf(r1, sm[w][1]);
            r2 = fmaxf(r2, sm[w][2]); r3 = fmaxf(r3, sm[w][3]);
        }
        atomicMax(gm + 0, fenc(r0)); atomicMax(gm + 1, fenc(r1));
        atomicMax(gm + 2, fenc(r2)); atomicMax(gm + 3, fenc(r3));
    }
}

__global__ __launch_bounds__(256) void k_bscanGmax4(const unsigned* gcnt, unsigned* gbase,
                                                    int* row, int n, int nbuck, int etot,
                                                    const float4* als4, unsigned* gm) {
    if (blockIdx.x == 0)
        bscan_body(gcnt, gbase, row, n, nbuck, etot);
    else
        gmax4_body(als4, gm, n, blockIdx.x - 1);
}

__global__ __launch_bounds__(256) void k_build(const unsigned* __restrict__ gcnt, const unsigned* __restrict__ gbase,
                                               const unsigned* __restrict__ binbuf, int* __restrict__ row,
                                               int* __restrict__ csr, int n, int cap) {
    __shared__ int s_cnt[NB];
    __shared__ int s_off[NB];
    __shared__ int sums[256];
    int b = blockIdx.x;
    int t = threadIdx.x;
    int nn = min(NB, n - b * NB);
    int total = (int)gcnt[b];
    int base = (int)gbase[b];
    s_cnt[t] = 0; s_cnt[t + 256] = 0;
    __syncthreads();
    const unsigned* rec = binbuf + (size_t)b * cap;
    for (int r = t; r < total; r += 256) atomicAdd(&s_cnt[rec[r] & (NB - 1)], 1);
    __syncthreads();
    int i0 = 2 * t, i1 = 2 * t + 1;
    int v0 = (i0 < nn) ? s_cnt[i0] + 1 : 0;
    int v1 = (i1 < nn) ? s_cnt[i1] + 1 : 0;
    int ps = v0 + v1;
    sums[t] = ps;
    __syncthreads();
    for (int off = 1; off < 256; off <<= 1) {
        int x = (t >= off) ? sums[t - off] : 0;
        __syncthreads();
        sums[t] += x;
        __syncthreads();
    }
    int ex = sums[t] - ps;
    s_off[i0] = ex;
    s_off[i1] = ex + v0;
    if (i0 < nn) { row[b * NB + i0] = base + ex;      csr[base + ex]      = b * NB + i0; }
    if (i1 < nn) { row[b * NB + i1] = base + ex + v0; csr[base + ex + v0] = b * NB + i1; }
    __syncthreads();
    s_cnt[t] = 1; s_cnt[t + 256] = 1;   // cursor: slot 0 = self loop
    __syncthreads();
    for (int r = t; r < total; r += 256) {
        unsigned rc = rec[r];
        int ld = rc & (NB - 1);
        int p = atomicAdd(&s_cnt[ld], 1);
        csr[base + s_off[ld] + p] = (int)(rc >> NBSHIFT);
    }
}

__global__ __launch_bounds__(256) void k_gmax1(const float* __restrict__ als, unsigned* gm, int n) {
    float m = -INFINITY;
    for (int i = blockIdx.x * 256 + threadIdx.x; i < n; i += 256 * 256) m = fmaxf(m, als[i]);
#pragma unroll
    for (int off = 32; off; off >>= 1) m = fmaxf(m, __shfl_xor(m, off));
    __shared__ float sm[4];
    int wid = threadIdx.x >> 6;
    if ((threadIdx.x & 63) == 0) sm[wid] = m;
    __syncthreads();
    if (threadIdx.x == 0)
        atomicMax(gm, fenc(fmaxf(fmaxf(sm[0], sm[1]), fmaxf(sm[2], sm[3]))));
}

// wave per dst node, single edge pass, prep-then-broadcast (2-deep, R12),
// packed fp16 accumulation (R14).
__global__ __launch_bounds__(256) void k_agg1(const int* __restrict__ row, const int* __restrict__ csr,
                                              const float* __restrict__ als, const float* __restrict__ ald,
                                              const __half* __restrict__ h, const float* __restrict__ b,
                                              const unsigned* __restrict__ gmaxu, __half* __restrict__ out,
                                              int n) {
    int node = blockIdx.x * 4 + (threadIdx.x >> 6);
    if (node >= n) return;
    int lane = threadIdx.x & 63;
    int start = __builtin_amdgcn_readfirstlane(row[node]);
    int end   = __builtin_amdgcn_readfirstlane(row[node + 1]);

    int g = lane >> 4;
    int lig = lane & 15;
    int head = lig >> 2;

    float4 adv = *(const float4*)(ald + (size_t)node * 4);
    uint4 gu = *(const uint4*)gmaxu;
    float mt, mh0, mh1, mh2, mh3;
    mt = fdec(gu.x) + adv.x; mh0 = mt > 0.f ? mt : SLOPE * mt;
    mt = fdec(gu.y) + adv.y; mh1 = mt > 0.f ? mt : SLOPE * mt;
    mt = fdec(gu.z) + adv.z; mh2 = mt > 0.f ? mt : SLOPE * mt;
    mt = fdec(gu.w) + adv.w; mh3 = mt > 0.f ? mt : SLOPE * mt;

    const __half2 z2 = __floats2half2_rn(0.f, 0.f);
    float den0 = 0.f, den1 = 0.f, den2 = 0.f, den3 = 0.f;
    __half2 ah0 = z2, ah1 = z2, ah2 = z2, ah3 = z2;

    for (int k0 = start; k0 < end; k0 += 64) {
        int nb = end - k0; if (nb > 64) nb = 64;
        int s_l = (lane < nb) ? csr[k0 + lane] : 0;
        float4 av = *(const float4*)(als + (size_t)s_l * 4);
        float e, x0, x1, x2, x3;
        e = av.x + adv.x; e = e > 0.f ? e : SLOPE * e; x0 = __expf(e - mh0);
        e = av.y + adv.y; e = e > 0.f ? e : SLOPE * e; x1 = __expf(e - mh1);
        e = av.z + adv.z; e = e > 0.f ? e : SLOPE * e; x2 = __expf(e - mh2);
        e = av.w + adv.w; e = e > 0.f ? e : SLOPE * e; x3 = __expf(e - mh3);
        bool valid = lane < nb;
        x0 = valid ? x0 : 0.f; x1 = valid ? x1 : 0.f;
        x2 = valid ? x2 : 0.f; x3 = valid ? x3 : 0.f;
        den0 += x0; den1 += x1; den2 += x2; den3 += x3;
        __half2 p01 = __floats2half2_rn(x0, x1);
        __half2 p23 = __floats2half2_rn(x2, x3);
        int w01 = h22i(p01);
        int w23 = h22i(p23);

        for (int jj = 0; jj < nb; jj += 8) {
            int eA = jj + g;
            int eB = jj + 4 + g;
            int sA = __shfl(s_l, eA);
            int sB = __shfl(s_l, eB);
            int wA01 = __shfl(w01, eA);
            int wA23 = __shfl(w23, eA);
            int wB01 = __shfl(w01, eB);
            int wB23 = __shfl(w23, eB);
            int wA = (head & 2) ? wA23 : wA01;
            int wB = (head & 2) ? wB23 : wB01;
            uint4 hvA = *(const uint4*)(h + ((size_t)sA << 7) + lig * 8);
            uint4 hvB = *(const uint4*)(h + ((size_t)sB << 7) + lig * 8);
            __half exhA = (head & 1) ? __high2half(i2h2(wA)) : __low2half(i2h2(wA));
            __half exhB = (head & 1) ? __high2half(i2h2(wB)) : __low2half(i2h2(wB));
            __half2 exA2 = __half2half2(exhA);
            __half2 exB2 = __half2half2(exhB);
            exA2 = (eA < nb) ? exA2 : z2;
            exB2 = (eB < nb) ? exB2 : z2;
            ah0 = __hfma2(exA2, i2h2((int)hvA.x), ah0);
            ah1 = __hfma2(exA2, i2h2((int)hvA.y), ah1);
            ah2 = __hfma2(exA2, i2h2((int)hvA.z), ah2);
            ah3 = __hfma2(exA2, i2h2((int)hvA.w), ah3);
            ah0 = __hfma2(exB2, i2h2((int)hvB.x), ah0);
            ah1 = __hfma2(exB2, i2h2((int)hvB.y), ah1);
            ah2 = __hfma2(exB2, i2h2((int)hvB.z), ah2);
            ah3 = __hfma2(exB2, i2h2((int)hvB.w), ah3);
        }
    }
#pragma unroll
    for (int off = 32; off; off >>= 1) {
        den0 += __shfl_xor(den0, off);
        den1 += __shfl_xor(den1, off);
        den2 += __shfl_xor(den2, off);
        den3 += __shfl_xor(den3, off);
    }
    ah0 = __hadd2(ah0, h2shflxor(ah0, 16));
    ah1 = __hadd2(ah1, h2shflxor(ah1, 16));
    ah2 = __hadd2(ah2, h2shflxor(ah2, 16));
    ah3 = __hadd2(ah3, h2shflxor(ah3, 16));
    ah0 = __hadd2(ah0, h2shflxor(ah0, 32));
    ah1 = __hadd2(ah1, h2shflxor(ah1, 32));
    ah2 = __hadd2(ah2, h2shflxor(ah2, 32));
    ah3 = __hadd2(ah3, h2shflxor(ah3, 32));
    if (g == 0) {
        float den_h = (head & 2) ? ((head & 1) ? den3 : den2) : ((head & 1) ? den1 : den0);
        float inv = 1.f / den_h;
        float2 f0 = __half22float2(ah0);
        float2 f1 = __half22float2(ah1);
        float2 f2 = __half22float2(ah2);
        float2 f3 = __half22float2(ah3);
        float4 bv0 = *(const float4*)(b + lig * 8);
        float4 bv1 = *(const float4*)(b + lig * 8 + 4);
        float o0, o1, o2, o3, o4, o5, o6, o7;
        o0 = f0.x * inv + bv0.x; o0 = o0 > 0.f ? o0 : expm1f(o0);
        o1 = f0.y * inv + bv0.y; o1 = o1 > 0.f ? o1 : expm1f(o1);
        o2 = f1.x * inv + bv0.z; o2 = o2 > 0.f ? o2 : expm1f(o2);
        o3 = f1.y * inv + bv0.w; o3 = o3 > 0.f ? o3 : expm1f(o3);
        o4 = f2.x * inv + bv1.x; o4 = o4 > 0.f ? o4 : expm1f(o4);
        o5 = f2.y * inv + bv1.y; o5 = o5 > 0.f ? o5 : expm1f(o5);
        o6 = f3.x * inv + bv1.z; o6 = o6 > 0.f ? o6 : expm1f(o6);
        o7 = f3.y * inv + bv1.w; o7 = o7 > 0.f ? o7 : expm1f(o7);
        __half2 q0 = __floats2half2_rn(o0, o1);
        __half2 q1 = __floats2half2_rn(o2, o3);
        __half2 q2 = __floats2half2_rn(o4, o5);
        __half2 q3 = __floats2half2_rn(o6, o7);
        uint4 st;
        st.x = (unsigned)h22i(q0);
        st.y = (unsigned)h22i(q1);
        st.z = (unsigned)h22i(q2);
        st.w = (unsigned)h22i(q3);
        *(uint4*)(out + ((size_t)node << 7) + lig * 8) = st;
    }
}

// ------- Layer 2 GEMM: h2 = hm(fp16) @ W2 (128->40), fp16 out -------

__global__ __launch_bounds__(640) void k_gemm2(const __half* __restrict__ hm, const float* __restrict__ W2,
                                               __half* __restrict__ h2h, int n) {
    __shared__ float xs[16][128];
    __shared__ float ws[128 * 40];
    int t = threadIdx.x;
    int row0 = blockIdx.x * 16;
    for (int i = t; i < 128 * 40; i += 640) ws[i] = W2[i];
    if (t < 256) {
        int r = t >> 4, c8 = t & 15;
        int gr = row0 + r;
        float* d = &xs[r][c8 * 8];
        if (gr < n) {
            uint4 v = *(const uint4*)(hm + (size_t)gr * 128 + c8 * 8);
            float2 f0 = __half22float2(*reinterpret_cast<__half2*>(&v.x));
            float2 f1 = __half22float2(*reinterpret_cast<__half2*>(&v.y));
            float2 f2 = __half22float2(*reinterpret_cast<__half2*>(&v.z));
            float2 f3 = __half22float2(*reinterpret_cast<__half2*>(&v.w));
            d[0] = f0.x; d[1] = f0.y; d[2] = f1.x; d[3] = f1.y;
            d[4] = f2.x; d[5] = f2.y; d[6] = f3.x; d[7] = f3.y;
        } else {
            for (int j = 0; j < 8; j++) d[j] = 0.f;
        }
    }
    __syncthreads();
    int r = t / 40, c = t - r * 40;
    int gr = row0 + r;
    float acc = 0.f;
#pragma unroll 8
    for (int k = 0; k < 128; ++k) acc += xs[r][k] * ws[k * 40 + c];
    if (gr < n) h2h[(size_t)gr * 40 + c] = __float2half_rn(acc);
}

// wave per node; lanes 0-19 load 2 ch each (no atomics).
__global__ __launch_bounds__(256) void k_al2(const __half* __restrict__ h2, const float* __restrict__ a_s,
                                             const float* __restrict__ a_d, float* als, float* ald, int n) {
    int t = threadIdx.x;
    int node = blockIdx.x * 4 + (t >> 6);
    int l = t & 63;
    if (node >= n) return;
    float ps = 0.f, pd = 0.f;
    if (l < 20) {
        unsigned hv = *(const unsigned*)(h2 + (size_t)node * 40 + l * 2);
        float2 f = __half22float2(*reinterpret_cast<__half2*>(&hv));
        float2 vs = *(const float2*)(a_s + l * 2);
        float2 vd = *(const float2*)(a_d + l * 2);
        ps = f.x * vs.x + f.y * vs.y;
        pd = f.x * vd.x + f.y * vd.y;
    }
#pragma unroll
    for (int off = 32; off; off >>= 1) { ps += __shfl_xor(ps, off); pd += __shfl_xor(pd, off); }
    if (l == 0) { als[node] = ps; ald[node] = pd; }
}

// wave per node, single edge pass + log_softmax (2-deep, packed fp16 acc).
__global__ __launch_bounds__(256) void k_agg2(const int* __restrict__ row, const int* __restrict__ csr,
                                              const float* __restrict__ als, const float* __restrict__ ald,
                                              const __half* __restrict__ h2, const float* __restrict__ b2,
                                              const unsigned* __restrict__ gmaxu, float* __restrict__ out,
                                              int n) {
    int node = blockIdx.x * 4 + (threadIdx.x >> 6);
    if (node >= n) return;
    int lane = threadIdx.x & 63;
    int start = __builtin_amdgcn_readfirstlane(row[node]);
    int end   = __builtin_amdgcn_readfirstlane(row[node + 1]);
    float ad = ald[node];
    float mt = fdec(gmaxu[0]) + ad;
    float mh = mt > 0.f ? mt : SLOPE * mt;

    int g = lane / 5;
    int lig = lane - g * 5;
    bool act = g < 12;

    const __half2 z2 = __floats2half2_rn(0.f, 0.f);
    float den = 0.f;
    __half2 ah0 = z2, ah1 = z2, ah2 = z2, ah3 = z2;
    for (int k0 = start; k0 < end; k0 += 64) {
        int nb = end - k0; if (nb > 64) nb = 64;
        int s_l = (lane < nb) ? csr[k0 + lane] : 0;
        float e = als[s_l] + ad; e = e > 0.f ? e : SLOPE * e;
        float ex_l = __expf(e - mh);
        ex_l = (lane < nb) ? ex_l : 0.f;
        den += ex_l;
        __half exh_l = __float2half_rn(ex_l);
        int exi_l = h22i(__half2half2(exh_l));

        for (int jj = 0; jj < nb; jj += 24) {
            int eA = jj + g;
            int eB = jj + 12 + g;
            int sA = __shfl(s_l, eA & 63);
            int sB = __shfl(s_l, eB & 63);
            int exAi = __shfl(exi_l, eA & 63);
            int exBi = __shfl(exi_l, eB & 63);
            uint4 hvA = *(const uint4*)(h2 + (size_t)sA * 40 + lig * 8);
            uint4 hvB = *(const uint4*)(h2 + (size_t)sB * 40 + lig * 8);
            __half2 exA2 = i2h2(exAi);
            __half2 exB2 = i2h2(exBi);
            exA2 = (act && eA < nb) ? exA2 : z2;
            exB2 = (act && eB < nb) ? exB2 : z2;
            ah0 = __hfma2(exA2, i2h2((int)hvA.x), ah0);
            ah1 = __hfma2(exA2, i2h2((int)hvA.y), ah1);
            ah2 = __hfma2(exA2, i2h2((int)hvA.z), ah2);
            ah3 = __hfma2(exA2, i2h2((int)hvA.w), ah3);
            ah0 = __hfma2(exB2, i2h2((int)hvB.x), ah0);
            ah1 = __hfma2(exB2, i2h2((int)hvB.y), ah1);
            ah2 = __hfma2(exB2, i2h2((int)hvB.z), ah2);
            ah3 = __hfma2(exB2, i2h2((int)hvB.w), ah3);
        }
    }
#pragma unroll
    for (int off = 32; off; off >>= 1) den += __shfl_xor(den, off);
    int t1i;
    t1i = __shfl(h22i(ah0), (lane + 30) & 63); ah0 = __hadd2(ah0, i2h2(t1i));
    t1i = __shfl(h22i(ah1), (lane + 30) & 63); ah1 = __hadd2(ah1, i2h2(t1i));
    t1i = __shfl(h22i(ah2), (lane + 30) & 63); ah2 = __hadd2(ah2, i2h2(t1i));
    t1i = __shfl(h22i(ah3), (lane + 30) & 63); ah3 = __hadd2(ah3, i2h2(t1i));
    t1i = __shfl(h22i(ah0), (lane + 15) & 63); ah0 = __hadd2(ah0, i2h2(t1i));
    t1i = __shfl(h22i(ah1), (lane + 15) & 63); ah1 = __hadd2(ah1, i2h2(t1i));
    t1i = __shfl(h22i(ah2), (lane + 15) & 63); ah2 = __hadd2(ah2, i2h2(t1i));
    t1i = __shfl(h22i(ah3), (lane + 15) & 63); ah3 = __hadd2(ah3, i2h2(t1i));
    int t2i;
    t1i = __shfl(h22i(ah0), (lane + 5) & 63); t2i = __shfl(h22i(ah0), (lane + 10) & 63);
    ah0 = __hadd2(__hadd2(ah0, i2h2(t1i)), i2h2(t2i));
    t1i = __shfl(h22i(ah1), (lane + 5) & 63); t2i = __shfl(h22i(ah1), (lane + 10) & 63);
    ah1 = __hadd2(__hadd2(ah1, i2h2(t1i)), i2h2(t2i));
    t1i = __shfl(h22i(ah2), (lane + 5) & 63); t2i = __shfl(h22i(ah2), (lane + 10) & 63);
    ah2 = __hadd2(__hadd2(ah2, i2h2(t1i)), i2h2(t2i));
    t1i = __shfl(h22i(ah3), (lane + 5) & 63); t2i = __shfl(h22i(ah3), (lane + 10) & 63);
    ah3 = __hadd2(__hadd2(ah3, i2h2(t1i)), i2h2(t2i));

    float v0 = 0.f, v1 = 0.f, v2 = 0.f, v3 = 0.f, v4 = 0.f, v5 = 0.f, v6 = 0.f, v7 = 0.f;
    float mv = -INFINITY;
    if (lane < 5) {
        float inv = 1.f / den;
        float2 f0 = __half22float2(ah0);
        float2 f1 = __half22float2(ah1);
        float2 f2 = __half22float2(ah2);
        float2 f3 = __half22float2(ah3);
        float4 bv0 = *(const float4*)(b2 + lane * 8);
        float4 bv1 = *(const float4*)(b2 + lane * 8 + 4);
        v0 = f0.x * inv + bv0.x; v1 = f0.y * inv + bv0.y;
        v2 = f1.x * inv + bv0.z; v3 = f1.y * inv + bv0.w;
        v4 = f2.x * inv + bv1.x; v5 = f2.y * inv + bv1.y;
        v6 = f3.x * inv + bv1.z; v7 = f3.y * inv + bv1.w;
        mv = fmaxf(fmaxf(fmaxf(v0, v1), fmaxf(v2, v3)),
                   fmaxf(fmaxf(v4, v5), fmaxf(v6, v7)));
    }
#pragma unroll
    for (int off = 32; off; off >>= 1) mv = fmaxf(mv, __shfl_xor(mv, off));
    float se = 0.f;
    if (lane < 5)
        se = __expf(v0 - mv) + __expf(v1 - mv) + __expf(v2 - mv) + __expf(v3 - mv)
           + __expf(v4 - mv) + __expf(v5 - mv) + __expf(v6 - mv) + __expf(v7 - mv);
#pragma unroll
    for (int off = 32; off; off >>= 1) se += __shfl_xor(se, off);
    if (lane < 5) {
        float lse = mv + __logf(se);
        float4 o0, o1;
        o0.x = v0 - lse; o0.y = v1 - lse; o0.z = v2 - lse; o0.w = v3 - lse;
        o1.x = v4 - lse; o1.y = v5 - lse; o1.z = v6 - lse; o1.w = v7 - lse;
        *(float4*)(out + (size_t)node * 40 + lane * 8) = o0;
        *(float4*)(out + (size_t)node * 40 + lane * 8 + 4) = o1;
    }
}

// ---------------- launch ----------------

extern "C" void kernel_launch(void* const* d_in, const int* in_sizes, int n_in,
                              void* d_out, int out_size, void* d_ws, size_t ws_size,
                              hipStream_t stream) {
    const float* x   = (const float*)d_in[0];
    const int*   ei  = (const int*)d_in[1];
    const float* W1  = (const float*)d_in[2];
    const float* as1 = (const float*)d_in[3];
    const float* ad1 = (const float*)d_in[4];
    const float* b1  = (const float*)d_in[5];
    const float* W2  = (const float*)d_in[6];
    const float* as2 = (const float*)d_in[7];
    const float* ad2 = (const float*)d_in[8];
    const float* b2  = (const float*)d_in[9];
    float* out = (float*)d_out;

    int n = in_sizes[0] / 128;
    int E = in_sizes[1] / 2;
    const int* src = ei;
    const int* dst = ei + E;
    int etot = E + n;

    int nbuck = (n + NB - 1) / NB;
    int cap = (2 * (E / nbuck) + 1023) / 1024 * 1024;

    char* ws = (char*)d_ws;
    size_t off = 0;
    auto alloc = [&](size_t bytes) {
        void* p = ws + off;
        off += (bytes + 255) & ~(size_t)255;
        return p;
    };
    int*      rowp   = (int*)alloc((size_t)(n + 1) * 4);
    int*      csr    = (int*)alloc((size_t)etot * 4);
    __half*   h1h    = (__half*)alloc((size_t)n * 128 * 2);
    __half*   hmh    = (__half*)alloc((size_t)n * 128 * 2);
    float*    als1   = (float*)alloc((size_t)n * 4 * 4);
    float*    ald1   = (float*)alloc((size_t)n * 4 * 4);
    unsigned* gmaxu  = (unsigned*)alloc(256);
    unsigned* gcnt   = (unsigned*)alloc((size_t)nbuck * 4);
    unsigned* gbase  = (unsigned*)alloc((size_t)nbuck * 4);
    __half*   wt16   = (__half*)alloc(128 * 128 * 2);
    unsigned* binbuf = (unsigned*)alloc((size_t)nbuck * cap * 4);
    __half* h2h = h1h;
    float* als2 = als1;
    float* ald2 = ald1;

    int epb = (E + 1023) / 1024;
    int binBlocks = 1024;
    int gemm1Blocks = (n + 63) / 64;

    hipMemsetAsync(gcnt, 0, (size_t)nbuck * 4, stream);
    hipMemsetAsync(gmaxu, 0, 32, stream);
    k_wt<<<64, 256, 0, stream>>>(W1, wt16);

    k_binGemm1<<<binBlocks + gemm1Blocks, 256, 0, stream>>>(
        src, dst, gcnt, binbuf, E, nbuck, cap, epb, binBlocks,
        x, wt16, as1, ad1, h1h, als1, ald1, n);
    k_bscanGmax4<<<257, 256, 0, stream>>>(gcnt, gbase, rowp, n, nbuck, etot,
                                          (const float4*)als1, gmaxu);
    k_build<<<nbuck, 256, 0, stream>>>(gcnt, gbase, binbuf, rowp, csr, n, cap);
    k_agg1<<<(n + 3) / 4, 256, 0, stream>>>(rowp, csr, als1, ald1, h1h, b1, gmaxu, hmh, n);

    k_gemm2<<<(n + 15) / 16, 640, 0, stream>>>(hmh, W2, h2h, n);
    k_al2<<<(n + 3) / 4, 256, 0, stream>>>(h2h, as2, ad2, als2, ald2, n);
    k_gmax1<<<256, 256, 0, stream>>>(als2, gmaxu + 4, n);
    k_agg2<<<(n + 3) / 4, 256, 0, stream>>>(rowp, csr, als2, ald2, h2h, b2, gmaxu + 4, out, n);
}

// Round 21
// 319.843 us; speedup vs baseline: 1.1209x; 1.0599x over previous
//
#include <hip/hip_runtime.h>
#include <hip/hip_fp16.h>
#include <math.h>

// GAT node classification: 2 GATConv layers + ELU + log_softmax.
// N=100000, E=1600000 (+N self loops), IN=128, HEADS=4, HID=32, OUT=40.
//
// Rules learned:
//  - R4: every __shfl executes with ALL 64 lanes active; wave-uniform bounds;
//    predicate VALUES not control flow.
//  - R8: __shfl returns the SOURCE lane's evaluation of its operand.
//  - R9/R15: same-address atomics serialize at every level.
//  - R10: diff-check unrolled blocks line-by-line after mechanical edits.
//  - R12: 2-deep gather unroll is the sweet spot.
//  - R14: feature accumulation in packed fp16 (__hfma2); logits/dens f32.
//  - R17: independent kernels grid-fused; k_init -> hipMemsetAsync.
//  - R18: fused-kernel LDS = union via one smem buffer.
//  - R20: gemm1 on MFMA; A/B k-order identical for both operands so any
//    common hardware k-permutation cancels.
//  - R21: random-ish streaming writes need >=128B contiguous runs per
//    destination region; binBlocks 1024->256 lengthens bucket runs 4x
//    (WRITE amplification was 8x at 32B runs).

#define SLOPE 0.2f
#define NB 512
#define NBSHIFT 9

typedef _Float16 f16x8 __attribute__((ext_vector_type(8)));
typedef float f32x4 __attribute__((ext_vector_type(4)));

__device__ __forceinline__ unsigned fenc(float f) {
    unsigned b = __float_as_uint(f);
    return (b & 0x80000000u) ? ~b : (b | 0x80000000u);
}
__device__ __forceinline__ float fdec(unsigned u) {
    return __uint_as_float((u & 0x80000000u) ? (u ^ 0x80000000u) : ~u);
}
__device__ __forceinline__ __half2 i2h2(int i) { return *reinterpret_cast<__half2*>(&i); }
__device__ __forceinline__ int h22i(__half2 h) { return *reinterpret_cast<int*>(&h); }
__device__ __forceinline__ __half2 h2shflxor(__half2 v, int off) {
    int j = __shfl_xor(h22i(v), off);
    return i2h2(j);
}

// ---------------- W transpose to f16: wt[c][k] = W[k][c] ----------------

__global__ __launch_bounds__(256) void k_wt(const float* __restrict__ W, __half* __restrict__ wt) {
    int idx = blockIdx.x * 256 + threadIdx.x;   // 16384 elements
    int k = idx & 127, c = idx >> 7;
    wt[(size_t)c * 128 + k] = __float2half_rn(W[(size_t)k * 128 + c]);
}

// ---------------- CSR bin (device body, smem-carved) ----------------

__device__ void bin_body(const int* __restrict__ src, const int* __restrict__ dst,
                         unsigned* __restrict__ gcnt, unsigned* __restrict__ binbuf,
                         int E, int nbuck, int cap, int epb, int bid, char* smem) {
    unsigned* hist = (unsigned*)smem;
    unsigned* base = hist + 256;
    unsigned* cur  = base + 256;
    int t = threadIdx.x;
    if (t < nbuck) { hist[t] = 0u; cur[t] = 0u; }
    __syncthreads();
    int e0 = bid * epb;
    int e1 = min(E, e0 + epb);
    for (int e = e0 + t; e < e1; e += 256) {
        int bk = dst[e] >> NBSHIFT;
        atomicAdd(&hist[bk], 1u);
    }
    __syncthreads();
    if (t < nbuck) base[t] = hist[t] ? atomicAdd(&gcnt[t], hist[t]) : 0u;
    __syncthreads();
    for (int e = e0 + t; e < e1; e += 256) {
        int d = dst[e];
        int bk = d >> NBSHIFT;
        unsigned p = atomicAdd(&cur[bk], 1u);
        binbuf[(size_t)bk * cap + base[bk] + p] =
            ((unsigned)src[e] << NBSHIFT) | (unsigned)(d & (NB - 1));
    }
}

// ------- Layer1 GEMM via MFMA (64 rows/block, 4 waves) + fused al1 -------

__device__ void gemm1_body(const float* __restrict__ x, const __half* __restrict__ wt,
                           const float* __restrict__ asrc, const float* __restrict__ adst,
                           __half* __restrict__ hh, float* __restrict__ als,
                           float* __restrict__ ald, int n, int bid, char* smem) {
    __half* xs = (__half*)smem;          // [64][136] padded
    int t = threadIdx.x;
    int row0 = bid * 64;
#pragma unroll
    for (int i = 0; i < 8; i++) {
        int flat = t + 256 * i;          // 2048 float4 slots
        int r = flat >> 5, c4 = flat & 31;
        int gr = row0 + r;
        float4 v = make_float4(0.f, 0.f, 0.f, 0.f);
        if (gr < n) v = ((const float4*)(x + (size_t)gr * 128))[c4];
        __half2* p = (__half2*)&xs[r * 136 + c4 * 4];
        p[0] = __floats2half2_rn(v.x, v.y);
        p[1] = __floats2half2_rn(v.z, v.w);
    }
    __syncthreads();
    int w = t >> 6;
    int l = t & 63;
    int cc = l & 15;
    int g  = l >> 4;
    int R  = row0 + w * 16 + g * 4;

    f32x4 acc[8] = {};
#pragma unroll
    for (int kc = 0; kc < 4; kc++) {
        f16x8 af = *(const f16x8*)&xs[(w * 16 + cc) * 136 + kc * 32 + g * 8];
#pragma unroll
        for (int j = 0; j < 8; j++) {
            f16x8 bf = *(const f16x8*)&wt[(size_t)(16 * j + cc) * 128 + kc * 32 + g * 8];
            acc[j] = __builtin_amdgcn_mfma_f32_16x16x32_f16(af, bf, acc[j], 0, 0, 0);
        }
    }
    float vsx[8], vdx[8];
#pragma unroll
    for (int j = 0; j < 8; j++) { vsx[j] = asrc[16 * j + cc]; vdx[j] = adst[16 * j + cc]; }
#pragma unroll
    for (int reg = 0; reg < 4; reg++) {
        int gr = R + reg;
        if (gr < n) {
#pragma unroll
            for (int j = 0; j < 8; j++)
                hh[(size_t)gr * 128 + 16 * j + cc] = __float2half_rn(acc[j][reg]);
        }
        float ps0 = acc[0][reg] * vsx[0] + acc[1][reg] * vsx[1];
        float ps1 = acc[2][reg] * vsx[2] + acc[3][reg] * vsx[3];
        float ps2 = acc[4][reg] * vsx[4] + acc[5][reg] * vsx[5];
        float ps3 = acc[6][reg] * vsx[6] + acc[7][reg] * vsx[7];
        float pd0 = acc[0][reg] * vdx[0] + acc[1][reg] * vdx[1];
        float pd1 = acc[2][reg] * vdx[2] + acc[3][reg] * vdx[3];
        float pd2 = acc[4][reg] * vdx[4] + acc[5][reg] * vdx[5];
        float pd3 = acc[6][reg] * vdx[6] + acc[7][reg] * vdx[7];
#pragma unroll
        for (int off = 1; off <= 8; off <<= 1) {
            ps0 += __shfl_xor(ps0, off); ps1 += __shfl_xor(ps1, off);
            ps2 += __shfl_xor(ps2, off); ps3 += __shfl_xor(ps3, off);
            pd0 += __shfl_xor(pd0, off); pd1 += __shfl_xor(pd1, off);
            pd2 += __shfl_xor(pd2, off); pd3 += __shfl_xor(pd3, off);
        }
        if (cc == 0 && gr < n) {
            *(float4*)(als + (size_t)gr * 4) = make_float4(ps0, ps1, ps2, ps3);
            *(float4*)(ald + (size_t)gr * 4) = make_float4(pd0, pd1, pd2, pd3);
        }
    }
}

// fused: blocks [0,binBlocks) bin; [binBlocks, ...) gemm1. Shared smem union.
__global__ __launch_bounds__(256) void k_binGemm1(const int* src, const int* dst,
                                                  unsigned* gcnt, unsigned* binbuf,
                                                  int E, int nbuck, int cap, int epb, int binBlocks,
                                                  const float* x, const __half* wt,
                                                  const float* asrc, const float* adst,
                                                  __half* hh, float* als, float* ald, int n) {
    __shared__ __align__(16) char smem[17408];
    if ((int)blockIdx.x < binBlocks)
        bin_body(src, dst, gcnt, binbuf, E, nbuck, cap, epb, blockIdx.x, smem);
    else
        gemm1_body(x, wt, asrc, adst, hh, als, ald, n, blockIdx.x - binBlocks, smem);
}

// ---------------- bscan + gmax4 (fused) ----------------

__device__ void bscan_body(const unsigned* __restrict__ gcnt, unsigned* __restrict__ gbase,
                           int* __restrict__ row, int n, int nbuck, int etot) {
    __shared__ unsigned s[256];
    int t = threadIdx.x;
    unsigned v = 0u;
    if (t < nbuck) {
        int nodes = min(NB, n - t * NB);
        v = gcnt[t] + (unsigned)nodes;
    }
    s[t] = v;
    __syncthreads();
    for (int off = 1; off < 256; off <<= 1) {
        unsigned x = (t >= off) ? s[t - off] : 0u;
        __syncthreads();
        s[t] += x;
        __syncthreads();
    }
    if (t < nbuck) gbase[t] = s[t] - v;  // exclusive
    if (t == 0) row[n] = etot;
}

__device__ void gmax4_body(const float4* __restrict__ als4, unsigned* gm, int n, int bid) {
    float m0 = -INFINITY, m1 = -INFINITY, m2 = -INFINITY, m3 = -INFINITY;
    for (int i = bid * 256 + threadIdx.x; i < n; i += 256 * 256) {
        float4 v = als4[i];
        m0 = fmaxf(m0, v.x); m1 = fmaxf(m1, v.y);
        m2 = fmaxf(m2, v.z); m3 = fmaxf(m3, v.w);
    }
#pragma unroll
    for (int off = 32; off; off >>= 1) {
        m0 = fmaxf(m0, __shfl_xor(m0, off));
        m1 = fmaxf(m1, __shfl_xor(m1, off));
        m2 = fmaxf(m2, __shfl_xor(m2, off));
        m3 = fmaxf(m3, __shfl_xor(m3, off));
    }
    __shared__ float sm[4][4];
    int wid = threadIdx.x >> 6;
    if ((threadIdx.x & 63) == 0) { sm[wid][0] = m0; sm[wid][1] = m1; sm[wid][2] = m2; sm[wid][3] = m3; }
    __syncthreads();
    if (threadIdx.x == 0) {
        float r0 = sm[0][0], r1 = sm[0][1], r2 = sm[0][2], r3 = sm[0][3];
        for (int w = 1; w < 4; w++) {
            r0 = fmaxf(r0, sm[w][0]); r1 = fmaxf(r1, sm[w][1]);
            r2 = fmaxf(r2, sm[w][2]); r3 = fmaxf(r3, sm[w][3]);
        }
        atomicMax(gm + 0, fenc(r0)); atomicMax(gm + 1, fenc(r1));
        atomicMax(gm + 2, fenc(r2)); atomicMax(gm + 3, fenc(r3));
    }
}

__global__ __launch_bounds__(256) void k_bscanGmax4(const unsigned* gcnt, unsigned* gbase,
                                                    int* row, int n, int nbuck, int etot,
                                                    const float4* als4, unsigned* gm) {
    if (blockIdx.x == 0)
        bscan_body(gcnt, gbase, row, n, nbuck, etot);
    else
        gmax4_body(als4, gm, n, blockIdx.x - 1);
}

__global__ __launch_bounds__(256) void k_build(const unsigned* __restrict__ gcnt, const unsigned* __restrict__ gbase,
                                               const unsigned* __restrict__ binbuf, int* __restrict__ row,
                                               int* __restrict__ csr, int n, int cap) {
    __shared__ int s_cnt[NB];
    __shared__ int s_off[NB];
    __shared__ int sums[256];
    int b = blockIdx.x;
    int t = threadIdx.x;
    int nn = min(NB, n - b * NB);
    int total = (int)gcnt[b];
    int base = (int)gbase[b];
    s_cnt[t] = 0; s_cnt[t + 256] = 0;
    __syncthreads();
    const unsigned* rec = binbuf + (size_t)b * cap;
    for (int r = t; r < total; r += 256) atomicAdd(&s_cnt[rec[r] & (NB - 1)], 1);
    __syncthreads();
    int i0 = 2 * t, i1 = 2 * t + 1;
    int v0 = (i0 < nn) ? s_cnt[i0] + 1 : 0;
    int v1 = (i1 < nn) ? s_cnt[i1] + 1 : 0;
    int ps = v0 + v1;
    sums[t] = ps;
    __syncthreads();
    for (int off = 1; off < 256; off <<= 1) {
        int x = (t >= off) ? sums[t - off] : 0;
        __syncthreads();
        sums[t] += x;
        __syncthreads();
    }
    int ex = sums[t] - ps;
    s_off[i0] = ex;
    s_off[i1] = ex + v0;
    if (i0 < nn) { row[b * NB + i0] = base + ex;      csr[base + ex]      = b * NB + i0; }
    if (i1 < nn) { row[b * NB + i1] = base + ex + v0; csr[base + ex + v0] = b * NB + i1; }
    __syncthreads();
    s_cnt[t] = 1; s_cnt[t + 256] = 1;   // cursor: slot 0 = self loop
    __syncthreads();
    for (int r = t; r < total; r += 256) {
        unsigned rc = rec[r];
        int ld = rc & (NB - 1);
        int p = atomicAdd(&s_cnt[ld], 1);
        csr[base + s_off[ld] + p] = (int)(rc >> NBSHIFT);
    }
}

__global__ __launch_bounds__(256) void k_gmax1(const float* __restrict__ als, unsigned* gm, int n) {
    float m = -INFINITY;
    for (int i = blockIdx.x * 256 + threadIdx.x; i < n; i += 256 * 256) m = fmaxf(m, als[i]);
#pragma unroll
    for (int off = 32; off; off >>= 1) m = fmaxf(m, __shfl_xor(m, off));
    __shared__ float sm[4];
    int wid = threadIdx.x >> 6;
    if ((threadIdx.x & 63) == 0) sm[wid] = m;
    __syncthreads();
    if (threadIdx.x == 0)
        atomicMax(gm, fenc(fmaxf(fmaxf(sm[0], sm[1]), fmaxf(sm[2], sm[3]))));
}

// wave per dst node, single edge pass, prep-then-broadcast (2-deep, R12),
// packed fp16 accumulation (R14).
__global__ __launch_bounds__(256) void k_agg1(const int* __restrict__ row, const int* __restrict__ csr,
                                              const float* __restrict__ als, const float* __restrict__ ald,
                                              const __half* __restrict__ h, const float* __restrict__ b,
                                              const unsigned* __restrict__ gmaxu, __half* __restrict__ out,
                                              int n) {
    int node = blockIdx.x * 4 + (threadIdx.x >> 6);
    if (node >= n) return;
    int lane = threadIdx.x & 63;
    int start = __builtin_amdgcn_readfirstlane(row[node]);
    int end   = __builtin_amdgcn_readfirstlane(row[node + 1]);

    int g = lane >> 4;
    int lig = lane & 15;
    int head = lig >> 2;

    float4 adv = *(const float4*)(ald + (size_t)node * 4);
    uint4 gu = *(const uint4*)gmaxu;
    float mt, mh0, mh1, mh2, mh3;
    mt = fdec(gu.x) + adv.x; mh0 = mt > 0.f ? mt : SLOPE * mt;
    mt = fdec(gu.y) + adv.y; mh1 = mt > 0.f ? mt : SLOPE * mt;
    mt = fdec(gu.z) + adv.z; mh2 = mt > 0.f ? mt : SLOPE * mt;
    mt = fdec(gu.w) + adv.w; mh3 = mt > 0.f ? mt : SLOPE * mt;

    const __half2 z2 = __floats2half2_rn(0.f, 0.f);
    float den0 = 0.f, den1 = 0.f, den2 = 0.f, den3 = 0.f;
    __half2 ah0 = z2, ah1 = z2, ah2 = z2, ah3 = z2;

    for (int k0 = start; k0 < end; k0 += 64) {
        int nb = end - k0; if (nb > 64) nb = 64;
        int s_l = (lane < nb) ? csr[k0 + lane] : 0;
        float4 av = *(const float4*)(als + (size_t)s_l * 4);
        float e, x0, x1, x2, x3;
        e = av.x + adv.x; e = e > 0.f ? e : SLOPE * e; x0 = __expf(e - mh0);
        e = av.y + adv.y; e = e > 0.f ? e : SLOPE * e; x1 = __expf(e - mh1);
        e = av.z + adv.z; e = e > 0.f ? e : SLOPE * e; x2 = __expf(e - mh2);
        e = av.w + adv.w; e = e > 0.f ? e : SLOPE * e; x3 = __expf(e - mh3);
        bool valid = lane < nb;
        x0 = valid ? x0 : 0.f; x1 = valid ? x1 : 0.f;
        x2 = valid ? x2 : 0.f; x3 = valid ? x3 : 0.f;
        den0 += x0; den1 += x1; den2 += x2; den3 += x3;
        __half2 p01 = __floats2half2_rn(x0, x1);
        __half2 p23 = __floats2half2_rn(x2, x3);
        int w01 = h22i(p01);
        int w23 = h22i(p23);

        for (int jj = 0; jj < nb; jj += 8) {
            int eA = jj + g;
            int eB = jj + 4 + g;
            int sA = __shfl(s_l, eA);
            int sB = __shfl(s_l, eB);
            int wA01 = __shfl(w01, eA);
            int wA23 = __shfl(w23, eA);
            int wB01 = __shfl(w01, eB);
            int wB23 = __shfl(w23, eB);
            int wA = (head & 2) ? wA23 : wA01;
            int wB = (head & 2) ? wB23 : wB01;
            uint4 hvA = *(const uint4*)(h + ((size_t)sA << 7) + lig * 8);
            uint4 hvB = *(const uint4*)(h + ((size_t)sB << 7) + lig * 8);
            __half exhA = (head & 1) ? __high2half(i2h2(wA)) : __low2half(i2h2(wA));
            __half exhB = (head & 1) ? __high2half(i2h2(wB)) : __low2half(i2h2(wB));
            __half2 exA2 = __half2half2(exhA);
            __half2 exB2 = __half2half2(exhB);
            exA2 = (eA < nb) ? exA2 : z2;
            exB2 = (eB < nb) ? exB2 : z2;
            ah0 = __hfma2(exA2, i2h2((int)hvA.x), ah0);
            ah1 = __hfma2(exA2, i2h2((int)hvA.y), ah1);
            ah2 = __hfma2(exA2, i2h2((int)hvA.z), ah2);
            ah3 = __hfma2(exA2, i2h2((int)hvA.w), ah3);
            ah0 = __hfma2(exB2, i2h2((int)hvB.x), ah0);
            ah1 = __hfma2(exB2, i2h2((int)hvB.y), ah1);
            ah2 = __hfma2(exB2, i2h2((int)hvB.z), ah2);
            ah3 = __hfma2(exB2, i2h2((int)hvB.w), ah3);
        }
    }
#pragma unroll
    for (int off = 32; off; off >>= 1) {
        den0 += __shfl_xor(den0, off);
        den1 += __shfl_xor(den1, off);
        den2 += __shfl_xor(den2, off);
        den3 += __shfl_xor(den3, off);
    }
    ah0 = __hadd2(ah0, h2shflxor(ah0, 16));
    ah1 = __hadd2(ah1, h2shflxor(ah1, 16));
    ah2 = __hadd2(ah2, h2shflxor(ah2, 16));
    ah3 = __hadd2(ah3, h2shflxor(ah3, 16));
    ah0 = __hadd2(ah0, h2shflxor(ah0, 32));
    ah1 = __hadd2(ah1, h2shflxor(ah1, 32));
    ah2 = __hadd2(ah2, h2shflxor(ah2, 32));
    ah3 = __hadd2(ah3, h2shflxor(ah3, 32));
    if (g == 0) {
        float den_h = (head & 2) ? ((head & 1) ? den3 : den2) : ((head & 1) ? den1 : den0);
        float inv = 1.f / den_h;
        float2 f0 = __half22float2(ah0);
        float2 f1 = __half22float2(ah1);
        float2 f2 = __half22float2(ah2);
        float2 f3 = __half22float2(ah3);
        float4 bv0 = *(const float4*)(b + lig * 8);
        float4 bv1 = *(const float4*)(b + lig * 8 + 4);
        float o0, o1, o2, o3, o4, o5, o6, o7;
        o0 = f0.x * inv + bv0.x; o0 = o0 > 0.f ? o0 : expm1f(o0);
        o1 = f0.y * inv + bv0.y; o1 = o1 > 0.f ? o1 : expm1f(o1);
        o2 = f1.x * inv + bv0.z; o2 = o2 > 0.f ? o2 : expm1f(o2);
        o3 = f1.y * inv + bv0.w; o3 = o3 > 0.f ? o3 : expm1f(o3);
        o4 = f2.x * inv + bv1.x; o4 = o4 > 0.f ? o4 : expm1f(o4);
        o5 = f2.y * inv + bv1.y; o5 = o5 > 0.f ? o5 : expm1f(o5);
        o6 = f3.x * inv + bv1.z; o6 = o6 > 0.f ? o6 : expm1f(o6);
        o7 = f3.y * inv + bv1.w; o7 = o7 > 0.f ? o7 : expm1f(o7);
        __half2 q0 = __floats2half2_rn(o0, o1);
        __half2 q1 = __floats2half2_rn(o2, o3);
        __half2 q2 = __floats2half2_rn(o4, o5);
        __half2 q3 = __floats2half2_rn(o6, o7);
        uint4 st;
        st.x = (unsigned)h22i(q0);
        st.y = (unsigned)h22i(q1);
        st.z = (unsigned)h22i(q2);
        st.w = (unsigned)h22i(q3);
        *(uint4*)(out + ((size_t)node << 7) + lig * 8) = st;
    }
}

// ------- Layer 2 GEMM: h2 = hm(fp16) @ W2 (128->40), fp16 out -------

__global__ __launch_bounds__(640) void k_gemm2(const __half* __restrict__ hm, const float* __restrict__ W2,
                                               __half* __restrict__ h2h, int n) {
    __shared__ float xs[16][128];
    __shared__ float ws[128 * 40];
    int t = threadIdx.x;
    int row0 = blockIdx.x * 16;
    for (int i = t; i < 128 * 40; i += 640) ws[i] = W2[i];
    if (t < 256) {
        int r = t >> 4, c8 = t & 15;
        int gr = row0 + r;
        float* d = &xs[r][c8 * 8];
        if (gr < n) {
            uint4 v = *(const uint4*)(hm + (size_t)gr * 128 + c8 * 8);
            float2 f0 = __half22float2(*reinterpret_cast<__half2*>(&v.x));
            float2 f1 = __half22float2(*reinterpret_cast<__half2*>(&v.y));
            float2 f2 = __half22float2(*reinterpret_cast<__half2*>(&v.z));
            float2 f3 = __half22float2(*reinterpret_cast<__half2*>(&v.w));
            d[0] = f0.x; d[1] = f0.y; d[2] = f1.x; d[3] = f1.y;
            d[4] = f2.x; d[5] = f2.y; d[6] = f3.x; d[7] = f3.y;
        } else {
            for (int j = 0; j < 8; j++) d[j] = 0.f;
        }
    }
    __syncthreads();
    int r = t / 40, c = t - r * 40;
    int gr = row0 + r;
    float acc = 0.f;
#pragma unroll 8
    for (int k = 0; k < 128; ++k) acc += xs[r][k] * ws[k * 40 + c];
    if (gr < n) h2h[(size_t)gr * 40 + c] = __float2half_rn(acc);
}

// wave per node; lanes 0-19 load 2 ch each (no atomics).
__global__ __launch_bounds__(256) void k_al2(const __half* __restrict__ h2, const float* __restrict__ a_s,
                                             const float* __restrict__ a_d, float* als, float* ald, int n) {
    int t = threadIdx.x;
    int node = blockIdx.x * 4 + (t >> 6);
    int l = t & 63;
    if (node >= n) return;
    float ps = 0.f, pd = 0.f;
    if (l < 20) {
        unsigned hv = *(const unsigned*)(h2 + (size_t)node * 40 + l * 2);
        float2 f = __half22float2(*reinterpret_cast<__half2*>(&hv));
        float2 vs = *(const float2*)(a_s + l * 2);
        float2 vd = *(const float2*)(a_d + l * 2);
        ps = f.x * vs.x + f.y * vs.y;
        pd = f.x * vd.x + f.y * vd.y;
    }
#pragma unroll
    for (int off = 32; off; off >>= 1) { ps += __shfl_xor(ps, off); pd += __shfl_xor(pd, off); }
    if (l == 0) { als[node] = ps; ald[node] = pd; }
}

// wave per node, single edge pass + log_softmax (2-deep, packed fp16 acc).
__global__ __launch_bounds__(256) void k_agg2(const int* __restrict__ row, const int* __restrict__ csr,
                                              const float* __restrict__ als, const float* __restrict__ ald,
                                              const __half* __restrict__ h2, const float* __restrict__ b2,
                                              const unsigned* __restrict__ gmaxu, float* __restrict__ out,
                                              int n) {
    int node = blockIdx.x * 4 + (threadIdx.x >> 6);
    if (node >= n) return;
    int lane = threadIdx.x & 63;
    int start = __builtin_amdgcn_readfirstlane(row[node]);
    int end   = __builtin_amdgcn_readfirstlane(row[node + 1]);
    float ad = ald[node];
    float mt = fdec(gmaxu[0]) + ad;
    float mh = mt > 0.f ? mt : SLOPE * mt;

    int g = lane / 5;
    int lig = lane - g * 5;
    bool act = g < 12;

    const __half2 z2 = __floats2half2_rn(0.f, 0.f);
    float den = 0.f;
    __half2 ah0 = z2, ah1 = z2, ah2 = z2, ah3 = z2;
    for (int k0 = start; k0 < end; k0 += 64) {
        int nb = end - k0; if (nb > 64) nb = 64;
        int s_l = (lane < nb) ? csr[k0 + lane] : 0;
        float e = als[s_l] + ad; e = e > 0.f ? e : SLOPE * e;
        float ex_l = __expf(e - mh);
        ex_l = (lane < nb) ? ex_l : 0.f;
        den += ex_l;
        __half exh_l = __float2half_rn(ex_l);
        int exi_l = h22i(__half2half2(exh_l));

        for (int jj = 0; jj < nb; jj += 24) {
            int eA = jj + g;
            int eB = jj + 12 + g;
            int sA = __shfl(s_l, eA & 63);
            int sB = __shfl(s_l, eB & 63);
            int exAi = __shfl(exi_l, eA & 63);
            int exBi = __shfl(exi_l, eB & 63);
            uint4 hvA = *(const uint4*)(h2 + (size_t)sA * 40 + lig * 8);
            uint4 hvB = *(const uint4*)(h2 + (size_t)sB * 40 + lig * 8);
            __half2 exA2 = i2h2(exAi);
            __half2 exB2 = i2h2(exBi);
            exA2 = (act && eA < nb) ? exA2 : z2;
            exB2 = (act && eB < nb) ? exB2 : z2;
            ah0 = __hfma2(exA2, i2h2((int)hvA.x), ah0);
            ah1 = __hfma2(exA2, i2h2((int)hvA.y), ah1);
            ah2 = __hfma2(exA2, i2h2((int)hvA.z), ah2);
            ah3 = __hfma2(exA2, i2h2((int)hvA.w), ah3);
            ah0 = __hfma2(exB2, i2h2((int)hvB.x), ah0);
            ah1 = __hfma2(exB2, i2h2((int)hvB.y), ah1);
            ah2 = __hfma2(exB2, i2h2((int)hvB.z), ah2);
            ah3 = __hfma2(exB2, i2h2((int)hvB.w), ah3);
        }
    }
#pragma unroll
    for (int off = 32; off; off >>= 1) den += __shfl_xor(den, off);
    int t1i;
    t1i = __shfl(h22i(ah0), (lane + 30) & 63); ah0 = __hadd2(ah0, i2h2(t1i));
    t1i = __shfl(h22i(ah1), (lane + 30) & 63); ah1 = __hadd2(ah1, i2h2(t1i));
    t1i = __shfl(h22i(ah2), (lane + 30) & 63); ah2 = __hadd2(ah2, i2h2(t1i));
    t1i = __shfl(h22i(ah3), (lane + 30) & 63); ah3 = __hadd2(ah3, i2h2(t1i));
    t1i = __shfl(h22i(ah0), (lane + 15) & 63); ah0 = __hadd2(ah0, i2h2(t1i));
    t1i = __shfl(h22i(ah1), (lane + 15) & 63); ah1 = __hadd2(ah1, i2h2(t1i));
    t1i = __shfl(h22i(ah2), (lane + 15) & 63); ah2 = __hadd2(ah2, i2h2(t1i));
    t1i = __shfl(h22i(ah3), (lane + 15) & 63); ah3 = __hadd2(ah3, i2h2(t1i));
    int t2i;
    t1i = __shfl(h22i(ah0), (lane + 5) & 63); t2i = __shfl(h22i(ah0), (lane + 10) & 63);
    ah0 = __hadd2(__hadd2(ah0, i2h2(t1i)), i2h2(t2i));
    t1i = __shfl(h22i(ah1), (lane + 5) & 63); t2i = __shfl(h22i(ah1), (lane + 10) & 63);
    ah1 = __hadd2(__hadd2(ah1, i2h2(t1i)), i2h2(t2i));
    t1i = __shfl(h22i(ah2), (lane + 5) & 63); t2i = __shfl(h22i(ah2), (lane + 10) & 63);
    ah2 = __hadd2(__hadd2(ah2, i2h2(t1i)), i2h2(t2i));
    t1i = __shfl(h22i(ah3), (lane + 5) & 63); t2i = __shfl(h22i(ah3), (lane + 10) & 63);
    ah3 = __hadd2(__hadd2(ah3, i2h2(t1i)), i2h2(t2i));

    float v0 = 0.f, v1 = 0.f, v2 = 0.f, v3 = 0.f, v4 = 0.f, v5 = 0.f, v6 = 0.f, v7 = 0.f;
    float mv = -INFINITY;
    if (lane < 5) {
        float inv = 1.f / den;
        float2 f0 = __half22float2(ah0);
        float2 f1 = __half22float2(ah1);
        float2 f2 = __half22float2(ah2);
        float2 f3 = __half22float2(ah3);
        float4 bv0 = *(const float4*)(b2 + lane * 8);
        float4 bv1 = *(const float4*)(b2 + lane * 8 + 4);
        v0 = f0.x * inv + bv0.x; v1 = f0.y * inv + bv0.y;
        v2 = f1.x * inv + bv0.z; v3 = f1.y * inv + bv0.w;
        v4 = f2.x * inv + bv1.x; v5 = f2.y * inv + bv1.y;
        v6 = f3.x * inv + bv1.z; v7 = f3.y * inv + bv1.w;
        mv = fmaxf(fmaxf(fmaxf(v0, v1), fmaxf(v2, v3)),
                   fmaxf(fmaxf(v4, v5), fmaxf(v6, v7)));
    }
#pragma unroll
    for (int off = 32; off; off >>= 1) mv = fmaxf(mv, __shfl_xor(mv, off));
    float se = 0.f;
    if (lane < 5)
        se = __expf(v0 - mv) + __expf(v1 - mv) + __expf(v2 - mv) + __expf(v3 - mv)
           + __expf(v4 - mv) + __expf(v5 - mv) + __expf(v6 - mv) + __expf(v7 - mv);
#pragma unroll
    for (int off = 32; off; off >>= 1) se += __shfl_xor(se, off);
    if (lane < 5) {
        float lse = mv + __logf(se);
        float4 o0, o1;
        o0.x = v0 - lse; o0.y = v1 - lse; o0.z = v2 - lse; o0.w = v3 - lse;
        o1.x = v4 - lse; o1.y = v5 - lse; o1.z = v6 - lse; o1.w = v7 - lse;
        *(float4*)(out + (size_t)node * 40 + lane * 8) = o0;
        *(float4*)(out + (size_t)node * 40 + lane * 8 + 4) = o1;
    }
}

// ---------------- launch ----------------

extern "C" void kernel_launch(void* const* d_in, const int* in_sizes, int n_in,
                              void* d_out, int out_size, void* d_ws, size_t ws_size,
                              hipStream_t stream) {
    const float* x   = (const float*)d_in[0];
    const int*   ei  = (const int*)d_in[1];
    const float* W1  = (const float*)d_in[2];
    const float* as1 = (const float*)d_in[3];
    const float* ad1 = (const float*)d_in[4];
    const float* b1  = (const float*)d_in[5];
    const float* W2  = (const float*)d_in[6];
    const float* as2 = (const float*)d_in[7];
    const float* ad2 = (const float*)d_in[8];
    const float* b2  = (const float*)d_in[9];
    float* out = (float*)d_out;

    int n = in_sizes[0] / 128;
    int E = in_sizes[1] / 2;
    const int* src = ei;
    const int* dst = ei + E;
    int etot = E + n;

    int nbuck = (n + NB - 1) / NB;
    int cap = (2 * (E / nbuck) + 1023) / 1024 * 1024;

    char* ws = (char*)d_ws;
    size_t off = 0;
    auto alloc = [&](size_t bytes) {
        void* p = ws + off;
        off += (bytes + 255) & ~(size_t)255;
        return p;
    };
    int*      rowp   = (int*)alloc((size_t)(n + 1) * 4);
    int*      csr    = (int*)alloc((size_t)etot * 4);
    __half*   h1h    = (__half*)alloc((size_t)n * 128 * 2);
    __half*   hmh    = (__half*)alloc((size_t)n * 128 * 2);
    float*    als1   = (float*)alloc((size_t)n * 4 * 4);
    float*    ald1   = (float*)alloc((size_t)n * 4 * 4);
    unsigned* gmaxu  = (unsigned*)alloc(256);
    unsigned* gcnt   = (unsigned*)alloc((size_t)nbuck * 4);
    unsigned* gbase  = (unsigned*)alloc((size_t)nbuck * 4);
    __half*   wt16   = (__half*)alloc(128 * 128 * 2);
    unsigned* binbuf = (unsigned*)alloc((size_t)nbuck * cap * 4);
    __half* h2h = h1h;
    float* als2 = als1;
    float* ald2 = ald1;

    int binBlocks = 256;                    // R21: long bucket runs (>=128B)
    int epb = (E + binBlocks - 1) / binBlocks;
    int gemm1Blocks = (n + 63) / 64;

    hipMemsetAsync(gcnt, 0, (size_t)nbuck * 4, stream);
    hipMemsetAsync(gmaxu, 0, 32, stream);
    k_wt<<<64, 256, 0, stream>>>(W1, wt16);

    k_binGemm1<<<binBlocks + gemm1Blocks, 256, 0, stream>>>(
        src, dst, gcnt, binbuf, E, nbuck, cap, epb, binBlocks,
        x, wt16, as1, ad1, h1h, als1, ald1, n);
    k_bscanGmax4<<<257, 256, 0, stream>>>(gcnt, gbase, rowp, n, nbuck, etot,
                                          (const float4*)als1, gmaxu);
    k_build<<<nbuck, 256, 0, stream>>>(gcnt, gbase, binbuf, rowp, csr, n, cap);
    k_agg1<<<(n + 3) / 4, 256, 0, stream>>>(rowp, csr, als1, ald1, h1h, b1, gmaxu, hmh, n);

    k_gemm2<<<(n + 15) / 16, 640, 0, stream>>>(hmh, W2, h2h, n);
    k_al2<<<(n + 3) / 4, 256, 0, stream>>>(h2h, as2, ad2, als2, ald2, n);
    k_gmax1<<<256, 256, 0, stream>>>(als2, gmaxu + 4, n);
    k_agg2<<<(n + 3) / 4, 256, 0, stream>>>(rowp, csr, als2, ald2, h2h, b2, gmaxu + 4, out, n);
}

// Round 22
// 306.571 us; speedup vs baseline: 1.1694x; 1.0433x over previous
//
#include <hip/hip_runtime.h>
#include <hip/hip_fp16.h>
#include <math.h>

// GAT node classification: 2 GATConv layers + ELU + log_softmax.
// N=100000, E=1600000 (+N self loops), IN=128, HEADS=4, HID=32, OUT=40.
//
// Rules learned:
//  - R4: every __shfl executes with ALL 64 lanes active; wave-uniform bounds;
//    predicate VALUES not control flow.
//  - R8: __shfl returns the SOURCE lane's evaluation of its operand.
//  - R9/R15: same-address atomics serialize at every level; many-writer
//    reductions use shfl/LDS-tree form, never atomics.
//  - R10: diff-check unrolled blocks line-by-line after mechanical edits.
//  - R12: 2-deep gather unroll is the sweet spot.
//  - R14: feature accumulation in packed fp16 (__hfma2); logits/dens f32.
//  - R17/R18: independent kernels grid-fused; smem union.
//  - R20: gemm1 on MFMA; identical A/B k-order cancels HW k-permutation.
//  - R21: streaming scatter needs >=128B runs; binBlocks=256.
//  - R22: fixed-stride csr regions kill the bucket scan (rowe[] stores ends);
//    build fuses with gmax4; al2 fused into gemm2 epilogue via LDS tree.

#define SLOPE 0.2f
#define NB 512
#define NBSHIFT 9

typedef _Float16 f16x8 __attribute__((ext_vector_type(8)));
typedef float f32x4 __attribute__((ext_vector_type(4)));

__device__ __forceinline__ unsigned fenc(float f) {
    unsigned b = __float_as_uint(f);
    return (b & 0x80000000u) ? ~b : (b | 0x80000000u);
}
__device__ __forceinline__ float fdec(unsigned u) {
    return __uint_as_float((u & 0x80000000u) ? (u ^ 0x80000000u) : ~u);
}
__device__ __forceinline__ __half2 i2h2(int i) { return *reinterpret_cast<__half2*>(&i); }
__device__ __forceinline__ int h22i(__half2 h) { return *reinterpret_cast<int*>(&h); }
__device__ __forceinline__ __half2 h2shflxor(__half2 v, int off) {
    int j = __shfl_xor(h22i(v), off);
    return i2h2(j);
}

// ---------------- W transpose to f16: wt[c][k] = W[k][c] ----------------

__global__ __launch_bounds__(256) void k_wt(const float* __restrict__ W, __half* __restrict__ wt) {
    int idx = blockIdx.x * 256 + threadIdx.x;   // 16384 elements
    int k = idx & 127, c = idx >> 7;
    wt[(size_t)c * 128 + k] = __float2half_rn(W[(size_t)k * 128 + c]);
}

// ---------------- CSR bin (device body, smem-carved) ----------------

__device__ void bin_body(const int* __restrict__ src, const int* __restrict__ dst,
                         unsigned* __restrict__ gcnt, unsigned* __restrict__ binbuf,
                         int E, int nbuck, int cap, int epb, int bid, char* smem) {
    unsigned* hist = (unsigned*)smem;
    unsigned* base = hist + 256;
    unsigned* cur  = base + 256;
    int t = threadIdx.x;
    if (t < nbuck) { hist[t] = 0u; cur[t] = 0u; }
    __syncthreads();
    int e0 = bid * epb;
    int e1 = min(E, e0 + epb);
    for (int e = e0 + t; e < e1; e += 256) {
        int bk = dst[e] >> NBSHIFT;
        atomicAdd(&hist[bk], 1u);
    }
    __syncthreads();
    if (t < nbuck) base[t] = hist[t] ? atomicAdd(&gcnt[t], hist[t]) : 0u;
    __syncthreads();
    for (int e = e0 + t; e < e1; e += 256) {
        int d = dst[e];
        int bk = d >> NBSHIFT;
        unsigned p = atomicAdd(&cur[bk], 1u);
        binbuf[(size_t)bk * cap + base[bk] + p] =
            ((unsigned)src[e] << NBSHIFT) | (unsigned)(d & (NB - 1));
    }
}

// ------- Layer1 GEMM via MFMA (64 rows/block, 4 waves) + fused al1 -------

__device__ void gemm1_body(const float* __restrict__ x, const __half* __restrict__ wt,
                           const float* __restrict__ asrc, const float* __restrict__ adst,
                           __half* __restrict__ hh, float* __restrict__ als,
                           float* __restrict__ ald, int n, int bid, char* smem) {
    __half* xs = (__half*)smem;          // [64][136] padded
    int t = threadIdx.x;
    int row0 = bid * 64;
#pragma unroll
    for (int i = 0; i < 8; i++) {
        int flat = t + 256 * i;          // 2048 float4 slots
        int r = flat >> 5, c4 = flat & 31;
        int gr = row0 + r;
        float4 v = make_float4(0.f, 0.f, 0.f, 0.f);
        if (gr < n) v = ((const float4*)(x + (size_t)gr * 128))[c4];
        __half2* p = (__half2*)&xs[r * 136 + c4 * 4];
        p[0] = __floats2half2_rn(v.x, v.y);
        p[1] = __floats2half2_rn(v.z, v.w);
    }
    __syncthreads();
    int w = t >> 6;
    int l = t & 63;
    int cc = l & 15;
    int g  = l >> 4;
    int R  = row0 + w * 16 + g * 4;

    f32x4 acc[8] = {};
#pragma unroll
    for (int kc = 0; kc < 4; kc++) {
        f16x8 af = *(const f16x8*)&xs[(w * 16 + cc) * 136 + kc * 32 + g * 8];
#pragma unroll
        for (int j = 0; j < 8; j++) {
            f16x8 bf = *(const f16x8*)&wt[(size_t)(16 * j + cc) * 128 + kc * 32 + g * 8];
            acc[j] = __builtin_amdgcn_mfma_f32_16x16x32_f16(af, bf, acc[j], 0, 0, 0);
        }
    }
    float vsx[8], vdx[8];
#pragma unroll
    for (int j = 0; j < 8; j++) { vsx[j] = asrc[16 * j + cc]; vdx[j] = adst[16 * j + cc]; }
#pragma unroll
    for (int reg = 0; reg < 4; reg++) {
        int gr = R + reg;
        if (gr < n) {
#pragma unroll
            for (int j = 0; j < 8; j++)
                hh[(size_t)gr * 128 + 16 * j + cc] = __float2half_rn(acc[j][reg]);
        }
        float ps0 = acc[0][reg] * vsx[0] + acc[1][reg] * vsx[1];
        float ps1 = acc[2][reg] * vsx[2] + acc[3][reg] * vsx[3];
        float ps2 = acc[4][reg] * vsx[4] + acc[5][reg] * vsx[5];
        float ps3 = acc[6][reg] * vsx[6] + acc[7][reg] * vsx[7];
        float pd0 = acc[0][reg] * vdx[0] + acc[1][reg] * vdx[1];
        float pd1 = acc[2][reg] * vdx[2] + acc[3][reg] * vdx[3];
        float pd2 = acc[4][reg] * vdx[4] + acc[5][reg] * vdx[5];
        float pd3 = acc[6][reg] * vdx[6] + acc[7][reg] * vdx[7];
#pragma unroll
        for (int off = 1; off <= 8; off <<= 1) {
            ps0 += __shfl_xor(ps0, off); ps1 += __shfl_xor(ps1, off);
            ps2 += __shfl_xor(ps2, off); ps3 += __shfl_xor(ps3, off);
            pd0 += __shfl_xor(pd0, off); pd1 += __shfl_xor(pd1, off);
            pd2 += __shfl_xor(pd2, off); pd3 += __shfl_xor(pd3, off);
        }
        if (cc == 0 && gr < n) {
            *(float4*)(als + (size_t)gr * 4) = make_float4(ps0, ps1, ps2, ps3);
            *(float4*)(ald + (size_t)gr * 4) = make_float4(pd0, pd1, pd2, pd3);
        }
    }
}

// fused: blocks [0,binBlocks) bin; [binBlocks, ...) gemm1. Shared smem union.
__global__ __launch_bounds__(256) void k_binGemm1(const int* src, const int* dst,
                                                  unsigned* gcnt, unsigned* binbuf,
                                                  int E, int nbuck, int cap, int epb, int binBlocks,
                                                  const float* x, const __half* wt,
                                                  const float* asrc, const float* adst,
                                                  __half* hh, float* als, float* ald, int n) {
    __shared__ __align__(16) char smem[17408];
    if ((int)blockIdx.x < binBlocks)
        bin_body(src, dst, gcnt, binbuf, E, nbuck, cap, epb, blockIdx.x, smem);
    else
        gemm1_body(x, wt, asrc, adst, hh, als, ald, n, blockIdx.x - binBlocks, smem);
}

// ------- build (fixed-stride csr regions, writes rowp+rowe) + gmax4 fused -------

__device__ void build_body(const unsigned* __restrict__ gcnt, const unsigned* __restrict__ binbuf,
                           int* __restrict__ rowp, int* __restrict__ rowe,
                           int* __restrict__ csr, int n, int cap, int b) {
    __shared__ int s_cnt[NB];
    __shared__ int s_off[NB];
    __shared__ int sums[256];
    int t = threadIdx.x;
    int nn = min(NB, n - b * NB);
    int total = (int)gcnt[b];
    int base = b * (cap + NB);           // R22: fixed region, no bucket scan
    s_cnt[t] = 0; s_cnt[t + 256] = 0;
    __syncthreads();
    const unsigned* rec = binbuf + (size_t)b * cap;
    for (int r = t; r < total; r += 256) atomicAdd(&s_cnt[rec[r] & (NB - 1)], 1);
    __syncthreads();
    int i0 = 2 * t, i1 = 2 * t + 1;
    int v0 = (i0 < nn) ? s_cnt[i0] + 1 : 0;
    int v1 = (i1 < nn) ? s_cnt[i1] + 1 : 0;
    int ps = v0 + v1;
    sums[t] = ps;
    __syncthreads();
    for (int off = 1; off < 256; off <<= 1) {
        int x = (t >= off) ? sums[t - off] : 0;
        __syncthreads();
        sums[t] += x;
        __syncthreads();
    }
    int ex = sums[t] - ps;
    s_off[i0] = ex;
    s_off[i1] = ex + v0;
    if (i0 < nn) {
        rowp[b * NB + i0] = base + ex;
        rowe[b * NB + i0] = base + ex + v0;
        csr[base + ex] = b * NB + i0;
    }
    if (i1 < nn) {
        rowp[b * NB + i1] = base + ex + v0;
        rowe[b * NB + i1] = base + ex + v0 + v1;
        csr[base + ex + v0] = b * NB + i1;
    }
    __syncthreads();
    s_cnt[t] = 1; s_cnt[t + 256] = 1;   // cursor: slot 0 = self loop
    __syncthreads();
    for (int r = t; r < total; r += 256) {
        unsigned rc = rec[r];
        int ld = rc & (NB - 1);
        int p = atomicAdd(&s_cnt[ld], 1);
        csr[base + s_off[ld] + p] = (int)(rc >> NBSHIFT);
    }
}

__device__ void gmax4_body(const float4* __restrict__ als4, unsigned* gm, int n, int bid) {
    float m0 = -INFINITY, m1 = -INFINITY, m2 = -INFINITY, m3 = -INFINITY;
    for (int i = bid * 256 + threadIdx.x; i < n; i += 256 * 256) {
        float4 v = als4[i];
        m0 = fmaxf(m0, v.x); m1 = fmaxf(m1, v.y);
        m2 = fmaxf(m2, v.z); m3 = fmaxf(m3, v.w);
    }
#pragma unroll
    for (int off = 32; off; off >>= 1) {
        m0 = fmaxf(m0, __shfl_xor(m0, off));
        m1 = fmaxf(m1, __shfl_xor(m1, off));
        m2 = fmaxf(m2, __shfl_xor(m2, off));
        m3 = fmaxf(m3, __shfl_xor(m3, off));
    }
    __shared__ float sm[4][4];
    int wid = threadIdx.x >> 6;
    if ((threadIdx.x & 63) == 0) { sm[wid][0] = m0; sm[wid][1] = m1; sm[wid][2] = m2; sm[wid][3] = m3; }
    __syncthreads();
    if (threadIdx.x == 0) {
        float r0 = sm[0][0], r1 = sm[0][1], r2 = sm[0][2], r3 = sm[0][3];
        for (int w = 1; w < 4; w++) {
            r0 = fmaxf(r0, sm[w][0]); r1 = fmaxf(r1, sm[w][1]);
            r2 = fmaxf(r2, sm[w][2]); r3 = fmaxf(r3, sm[w][3]);
        }
        atomicMax(gm + 0, fenc(r0)); atomicMax(gm + 1, fenc(r1));
        atomicMax(gm + 2, fenc(r2)); atomicMax(gm + 3, fenc(r3));
    }
}

__global__ __launch_bounds__(256) void k_buildGmax4(const unsigned* gcnt, const unsigned* binbuf,
                                                    int* rowp, int* rowe, int* csr,
                                                    int n, int cap, int nbuck,
                                                    const float4* als4, unsigned* gm) {
    if ((int)blockIdx.x < nbuck)
        build_body(gcnt, binbuf, rowp, rowe, csr, n, cap, blockIdx.x);
    else
        gmax4_body(als4, gm, n, blockIdx.x - nbuck);
}

__global__ __launch_bounds__(256) void k_gmax1(const float* __restrict__ als, unsigned* gm, int n) {
    float m = -INFINITY;
    for (int i = blockIdx.x * 256 + threadIdx.x; i < n; i += 256 * 256) m = fmaxf(m, als[i]);
#pragma unroll
    for (int off = 32; off; off >>= 1) m = fmaxf(m, __shfl_xor(m, off));
    __shared__ float sm[4];
    int wid = threadIdx.x >> 6;
    if ((threadIdx.x & 63) == 0) sm[wid] = m;
    __syncthreads();
    if (threadIdx.x == 0)
        atomicMax(gm, fenc(fmaxf(fmaxf(sm[0], sm[1]), fmaxf(sm[2], sm[3]))));
}

// wave per dst node, single edge pass, prep-then-broadcast (2-deep, R12),
// packed fp16 accumulation (R14).
__global__ __launch_bounds__(256) void k_agg1(const int* __restrict__ rowp, const int* __restrict__ rowe,
                                              const int* __restrict__ csr,
                                              const float* __restrict__ als, const float* __restrict__ ald,
                                              const __half* __restrict__ h, const float* __restrict__ b,
                                              const unsigned* __restrict__ gmaxu, __half* __restrict__ out,
                                              int n) {
    int node = blockIdx.x * 4 + (threadIdx.x >> 6);
    if (node >= n) return;
    int lane = threadIdx.x & 63;
    int start = __builtin_amdgcn_readfirstlane(rowp[node]);
    int end   = __builtin_amdgcn_readfirstlane(rowe[node]);

    int g = lane >> 4;
    int lig = lane & 15;
    int head = lig >> 2;

    float4 adv = *(const float4*)(ald + (size_t)node * 4);
    uint4 gu = *(const uint4*)gmaxu;
    float mt, mh0, mh1, mh2, mh3;
    mt = fdec(gu.x) + adv.x; mh0 = mt > 0.f ? mt : SLOPE * mt;
    mt = fdec(gu.y) + adv.y; mh1 = mt > 0.f ? mt : SLOPE * mt;
    mt = fdec(gu.z) + adv.z; mh2 = mt > 0.f ? mt : SLOPE * mt;
    mt = fdec(gu.w) + adv.w; mh3 = mt > 0.f ? mt : SLOPE * mt;

    const __half2 z2 = __floats2half2_rn(0.f, 0.f);
    float den0 = 0.f, den1 = 0.f, den2 = 0.f, den3 = 0.f;
    __half2 ah0 = z2, ah1 = z2, ah2 = z2, ah3 = z2;

    for (int k0 = start; k0 < end; k0 += 64) {
        int nb = end - k0; if (nb > 64) nb = 64;
        int s_l = (lane < nb) ? csr[k0 + lane] : 0;
        float4 av = *(const float4*)(als + (size_t)s_l * 4);
        float e, x0, x1, x2, x3;
        e = av.x + adv.x; e = e > 0.f ? e : SLOPE * e; x0 = __expf(e - mh0);
        e = av.y + adv.y; e = e > 0.f ? e : SLOPE * e; x1 = __expf(e - mh1);
        e = av.z + adv.z; e = e > 0.f ? e : SLOPE * e; x2 = __expf(e - mh2);
        e = av.w + adv.w; e = e > 0.f ? e : SLOPE * e; x3 = __expf(e - mh3);
        bool valid = lane < nb;
        x0 = valid ? x0 : 0.f; x1 = valid ? x1 : 0.f;
        x2 = valid ? x2 : 0.f; x3 = valid ? x3 : 0.f;
        den0 += x0; den1 += x1; den2 += x2; den3 += x3;
        __half2 p01 = __floats2half2_rn(x0, x1);
        __half2 p23 = __floats2half2_rn(x2, x3);
        int w01 = h22i(p01);
        int w23 = h22i(p23);

        for (int jj = 0; jj < nb; jj += 8) {
            int eA = jj + g;
            int eB = jj + 4 + g;
            int sA = __shfl(s_l, eA);
            int sB = __shfl(s_l, eB);
            int wA01 = __shfl(w01, eA);
            int wA23 = __shfl(w23, eA);
            int wB01 = __shfl(w01, eB);
            int wB23 = __shfl(w23, eB);
            int wA = (head & 2) ? wA23 : wA01;
            int wB = (head & 2) ? wB23 : wB01;
            uint4 hvA = *(const uint4*)(h + ((size_t)sA << 7) + lig * 8);
            uint4 hvB = *(const uint4*)(h + ((size_t)sB << 7) + lig * 8);
            __half exhA = (head & 1) ? __high2half(i2h2(wA)) : __low2half(i2h2(wA));
            __half exhB = (head & 1) ? __high2half(i2h2(wB)) : __low2half(i2h2(wB));
            __half2 exA2 = __half2half2(exhA);
            __half2 exB2 = __half2half2(exhB);
            exA2 = (eA < nb) ? exA2 : z2;
            exB2 = (eB < nb) ? exB2 : z2;
            ah0 = __hfma2(exA2, i2h2((int)hvA.x), ah0);
            ah1 = __hfma2(exA2, i2h2((int)hvA.y), ah1);
            ah2 = __hfma2(exA2, i2h2((int)hvA.z), ah2);
            ah3 = __hfma2(exA2, i2h2((int)hvA.w), ah3);
            ah0 = __hfma2(exB2, i2h2((int)hvB.x), ah0);
            ah1 = __hfma2(exB2, i2h2((int)hvB.y), ah1);
            ah2 = __hfma2(exB2, i2h2((int)hvB.z), ah2);
            ah3 = __hfma2(exB2, i2h2((int)hvB.w), ah3);
        }
    }
#pragma unroll
    for (int off = 32; off; off >>= 1) {
        den0 += __shfl_xor(den0, off);
        den1 += __shfl_xor(den1, off);
        den2 += __shfl_xor(den2, off);
        den3 += __shfl_xor(den3, off);
    }
    ah0 = __hadd2(ah0, h2shflxor(ah0, 16));
    ah1 = __hadd2(ah1, h2shflxor(ah1, 16));
    ah2 = __hadd2(ah2, h2shflxor(ah2, 16));
    ah3 = __hadd2(ah3, h2shflxor(ah3, 16));
    ah0 = __hadd2(ah0, h2shflxor(ah0, 32));
    ah1 = __hadd2(ah1, h2shflxor(ah1, 32));
    ah2 = __hadd2(ah2, h2shflxor(ah2, 32));
    ah3 = __hadd2(ah3, h2shflxor(ah3, 32));
    if (g == 0) {
        float den_h = (head & 2) ? ((head & 1) ? den3 : den2) : ((head & 1) ? den1 : den0);
        float inv = 1.f / den_h;
        float2 f0 = __half22float2(ah0);
        float2 f1 = __half22float2(ah1);
        float2 f2 = __half22float2(ah2);
        float2 f3 = __half22float2(ah3);
        float4 bv0 = *(const float4*)(b + lig * 8);
        float4 bv1 = *(const float4*)(b + lig * 8 + 4);
        float o0, o1, o2, o3, o4, o5, o6, o7;
        o0 = f0.x * inv + bv0.x; o0 = o0 > 0.f ? o0 : expm1f(o0);
        o1 = f0.y * inv + bv0.y; o1 = o1 > 0.f ? o1 : expm1f(o1);
        o2 = f1.x * inv + bv0.z; o2 = o2 > 0.f ? o2 : expm1f(o2);
        o3 = f1.y * inv + bv0.w; o3 = o3 > 0.f ? o3 : expm1f(o3);
        o4 = f2.x * inv + bv1.x; o4 = o4 > 0.f ? o4 : expm1f(o4);
        o5 = f2.y * inv + bv1.y; o5 = o5 > 0.f ? o5 : expm1f(o5);
        o6 = f3.x * inv + bv1.z; o6 = o6 > 0.f ? o6 : expm1f(o6);
        o7 = f3.y * inv + bv1.w; o7 = o7 > 0.f ? o7 : expm1f(o7);
        __half2 q0 = __floats2half2_rn(o0, o1);
        __half2 q1 = __floats2half2_rn(o2, o3);
        __half2 q2 = __floats2half2_rn(o4, o5);
        __half2 q3 = __floats2half2_rn(o6, o7);
        uint4 st;
        st.x = (unsigned)h22i(q0);
        st.y = (unsigned)h22i(q1);
        st.z = (unsigned)h22i(q2);
        st.w = (unsigned)h22i(q3);
        *(uint4*)(out + ((size_t)node << 7) + lig * 8) = st;
    }
}

// ------- Layer 2 GEMM + fused al2 (LDS tree, no atomics -- R15/R22) -------

__global__ __launch_bounds__(640) void k_gemm2(const __half* __restrict__ hm, const float* __restrict__ W2,
                                               const float* __restrict__ a_s, const float* __restrict__ a_d,
                                               __half* __restrict__ h2h, float* __restrict__ als,
                                               float* __restrict__ ald, int n) {
    __shared__ float xs[16][128];
    __shared__ float wsbuf[128 * 40];
    __shared__ float sredS[16][41];
    __shared__ float sredD[16][41];
    int t = threadIdx.x;
    int row0 = blockIdx.x * 16;
    for (int i = t; i < 128 * 40; i += 640) wsbuf[i] = W2[i];
    if (t < 256) {
        int r = t >> 4, c8 = t & 15;
        int gr = row0 + r;
        float* d = &xs[r][c8 * 8];
        if (gr < n) {
            uint4 v = *(const uint4*)(hm + (size_t)gr * 128 + c8 * 8);
            float2 f0 = __half22float2(*reinterpret_cast<__half2*>(&v.x));
            float2 f1 = __half22float2(*reinterpret_cast<__half2*>(&v.y));
            float2 f2 = __half22float2(*reinterpret_cast<__half2*>(&v.z));
            float2 f3 = __half22float2(*reinterpret_cast<__half2*>(&v.w));
            d[0] = f0.x; d[1] = f0.y; d[2] = f1.x; d[3] = f1.y;
            d[4] = f2.x; d[5] = f2.y; d[6] = f3.x; d[7] = f3.y;
        } else {
            for (int j = 0; j < 8; j++) d[j] = 0.f;
        }
    }
    __syncthreads();
    int r = t / 40, c = t - r * 40;
    int gr = row0 + r;
    float acc = 0.f;
#pragma unroll 8
    for (int k = 0; k < 128; ++k) acc += xs[r][k] * wsbuf[k * 40 + c];
    if (gr < n) h2h[(size_t)gr * 40 + c] = __float2half_rn(acc);
    // fused al2: acc==0 for OOB rows (xs zero-filled) -> safe unconditional
    sredS[r][c] = acc * a_s[c];
    sredD[r][c] = acc * a_d[c];
    __syncthreads();
    if (t < 16) {
        int g2 = row0 + t;
        if (g2 < n) {
            float ss = 0.f, dd = 0.f;
#pragma unroll 8
            for (int c2 = 0; c2 < 40; ++c2) { ss += sredS[t][c2]; dd += sredD[t][c2]; }
            als[g2] = ss;
            ald[g2] = dd;
        }
    }
}

// wave per node, single edge pass + log_softmax (2-deep, packed fp16 acc).
__global__ __launch_bounds__(256) void k_agg2(const int* __restrict__ rowp, const int* __restrict__ rowe,
                                              const int* __restrict__ csr,
                                              const float* __restrict__ als, const float* __restrict__ ald,
                                              const __half* __restrict__ h2, const float* __restrict__ b2,
                                              const unsigned* __restrict__ gmaxu, float* __restrict__ out,
                                              int n) {
    int node = blockIdx.x * 4 + (threadIdx.x >> 6);
    if (node >= n) return;
    int lane = threadIdx.x & 63;
    int start = __builtin_amdgcn_readfirstlane(rowp[node]);
    int end   = __builtin_amdgcn_readfirstlane(rowe[node]);
    float ad = ald[node];
    float mt = fdec(gmaxu[0]) + ad;
    float mh = mt > 0.f ? mt : SLOPE * mt;

    int g = lane / 5;
    int lig = lane - g * 5;
    bool act = g < 12;

    const __half2 z2 = __floats2half2_rn(0.f, 0.f);
    float den = 0.f;
    __half2 ah0 = z2, ah1 = z2, ah2 = z2, ah3 = z2;
    for (int k0 = start; k0 < end; k0 += 64) {
        int nb = end - k0; if (nb > 64) nb = 64;
        int s_l = (lane < nb) ? csr[k0 + lane] : 0;
        float e = als[s_l] + ad; e = e > 0.f ? e : SLOPE * e;
        float ex_l = __expf(e - mh);
        ex_l = (lane < nb) ? ex_l : 0.f;
        den += ex_l;
        __half exh_l = __float2half_rn(ex_l);
        int exi_l = h22i(__half2half2(exh_l));

        for (int jj = 0; jj < nb; jj += 24) {
            int eA = jj + g;
            int eB = jj + 12 + g;
            int sA = __shfl(s_l, eA & 63);
            int sB = __shfl(s_l, eB & 63);
            int exAi = __shfl(exi_l, eA & 63);
            int exBi = __shfl(exi_l, eB & 63);
            uint4 hvA = *(const uint4*)(h2 + (size_t)sA * 40 + lig * 8);
            uint4 hvB = *(const uint4*)(h2 + (size_t)sB * 40 + lig * 8);
            __half2 exA2 = i2h2(exAi);
            __half2 exB2 = i2h2(exBi);
            exA2 = (act && eA < nb) ? exA2 : z2;
            exB2 = (act && eB < nb) ? exB2 : z2;
            ah0 = __hfma2(exA2, i2h2((int)hvA.x), ah0);
            ah1 = __hfma2(exA2, i2h2((int)hvA.y), ah1);
            ah2 = __hfma2(exA2, i2h2((int)hvA.z), ah2);
            ah3 = __hfma2(exA2, i2h2((int)hvA.w), ah3);
            ah0 = __hfma2(exB2, i2h2((int)hvB.x), ah0);
            ah1 = __hfma2(exB2, i2h2((int)hvB.y), ah1);
            ah2 = __hfma2(exB2, i2h2((int)hvB.z), ah2);
            ah3 = __hfma2(exB2, i2h2((int)hvB.w), ah3);
        }
    }
#pragma unroll
    for (int off = 32; off; off >>= 1) den += __shfl_xor(den, off);
    int t1i;
    t1i = __shfl(h22i(ah0), (lane + 30) & 63); ah0 = __hadd2(ah0, i2h2(t1i));
    t1i = __shfl(h22i(ah1), (lane + 30) & 63); ah1 = __hadd2(ah1, i2h2(t1i));
    t1i = __shfl(h22i(ah2), (lane + 30) & 63); ah2 = __hadd2(ah2, i2h2(t1i));
    t1i = __shfl(h22i(ah3), (lane + 30) & 63); ah3 = __hadd2(ah3, i2h2(t1i));
    t1i = __shfl(h22i(ah0), (lane + 15) & 63); ah0 = __hadd2(ah0, i2h2(t1i));
    t1i = __shfl(h22i(ah1), (lane + 15) & 63); ah1 = __hadd2(ah1, i2h2(t1i));
    t1i = __shfl(h22i(ah2), (lane + 15) & 63); ah2 = __hadd2(ah2, i2h2(t1i));
    t1i = __shfl(h22i(ah3), (lane + 15) & 63); ah3 = __hadd2(ah3, i2h2(t1i));
    int t2i;
    t1i = __shfl(h22i(ah0), (lane + 5) & 63); t2i = __shfl(h22i(ah0), (lane + 10) & 63);
    ah0 = __hadd2(__hadd2(ah0, i2h2(t1i)), i2h2(t2i));
    t1i = __shfl(h22i(ah1), (lane + 5) & 63); t2i = __shfl(h22i(ah1), (lane + 10) & 63);
    ah1 = __hadd2(__hadd2(ah1, i2h2(t1i)), i2h2(t2i));
    t1i = __shfl(h22i(ah2), (lane + 5) & 63); t2i = __shfl(h22i(ah2), (lane + 10) & 63);
    ah2 = __hadd2(__hadd2(ah2, i2h2(t1i)), i2h2(t2i));
    t1i = __shfl(h22i(ah3), (lane + 5) & 63); t2i = __shfl(h22i(ah3), (lane + 10) & 63);
    ah3 = __hadd2(__hadd2(ah3, i2h2(t1i)), i2h2(t2i));

    float v0 = 0.f, v1 = 0.f, v2 = 0.f, v3 = 0.f, v4 = 0.f, v5 = 0.f, v6 = 0.f, v7 = 0.f;
    float mv = -INFINITY;
    if (lane < 5) {
        float inv = 1.f / den;
        float2 f0 = __half22float2(ah0);
        float2 f1 = __half22float2(ah1);
        float2 f2 = __half22float2(ah2);
        float2 f3 = __half22float2(ah3);
        float4 bv0 = *(const float4*)(b2 + lane * 8);
        float4 bv1 = *(const float4*)(b2 + lane * 8 + 4);
        v0 = f0.x * inv + bv0.x; v1 = f0.y * inv + bv0.y;
        v2 = f1.x * inv + bv0.z; v3 = f1.y * inv + bv0.w;
        v4 = f2.x * inv + bv1.x; v5 = f2.y * inv + bv1.y;
        v6 = f3.x * inv + bv1.z; v7 = f3.y * inv + bv1.w;
        mv = fmaxf(fmaxf(fmaxf(v0, v1), fmaxf(v2, v3)),
                   fmaxf(fmaxf(v4, v5), fmaxf(v6, v7)));
    }
#pragma unroll
    for (int off = 32; off; off >>= 1) mv = fmaxf(mv, __shfl_xor(mv, off));
    float se = 0.f;
    if (lane < 5)
        se = __expf(v0 - mv) + __expf(v1 - mv) + __expf(v2 - mv) + __expf(v3 - mv)
           + __expf(v4 - mv) + __expf(v5 - mv) + __expf(v6 - mv) + __expf(v7 - mv);
#pragma unroll
    for (int off = 32; off; off >>= 1) se += __shfl_xor(se, off);
    if (lane < 5) {
        float lse = mv + __logf(se);
        float4 o0, o1;
        o0.x = v0 - lse; o0.y = v1 - lse; o0.z = v2 - lse; o0.w = v3 - lse;
        o1.x = v4 - lse; o1.y = v5 - lse; o1.z = v6 - lse; o1.w = v7 - lse;
        *(float4*)(out + (size_t)node * 40 + lane * 8) = o0;
        *(float4*)(out + (size_t)node * 40 + lane * 8 + 4) = o1;
    }
}

// ---------------- launch ----------------

extern "C" void kernel_launch(void* const* d_in, const int* in_sizes, int n_in,
                              void* d_out, int out_size, void* d_ws, size_t ws_size,
                              hipStream_t stream) {
    const float* x   = (const float*)d_in[0];
    const int*   ei  = (const int*)d_in[1];
    const float* W1  = (const float*)d_in[2];
    const float* as1 = (const float*)d_in[3];
    const float* ad1 = (const float*)d_in[4];
    const float* b1  = (const float*)d_in[5];
    const float* W2  = (const float*)d_in[6];
    const float* as2 = (const float*)d_in[7];
    const float* ad2 = (const float*)d_in[8];
    const float* b2  = (const float*)d_in[9];
    float* out = (float*)d_out;

    int n = in_sizes[0] / 128;
    int E = in_sizes[1] / 2;
    const int* src = ei;
    const int* dst = ei + E;

    int nbuck = (n + NB - 1) / NB;
    int cap = (2 * (E / nbuck) + 1023) / 1024 * 1024;

    char* ws = (char*)d_ws;
    size_t off = 0;
    auto alloc = [&](size_t bytes) {
        void* p = ws + off;
        off += (bytes + 255) & ~(size_t)255;
        return p;
    };
    int*      rowp   = (int*)alloc((size_t)n * 4);
    int*      rowe   = (int*)alloc((size_t)n * 4);
    int*      csr    = (int*)alloc((size_t)nbuck * (cap + NB) * 4);   // fixed-stride regions
    __half*   h1h    = (__half*)alloc((size_t)n * 128 * 2);
    __half*   hmh    = (__half*)alloc((size_t)n * 128 * 2);
    float*    als1   = (float*)alloc((size_t)n * 4 * 4);
    float*    ald1   = (float*)alloc((size_t)n * 4 * 4);
    unsigned* gmaxu  = (unsigned*)alloc(256);
    unsigned* gcnt   = (unsigned*)alloc((size_t)nbuck * 4);
    __half*   wt16   = (__half*)alloc(128 * 128 * 2);
    unsigned* binbuf = (unsigned*)alloc((size_t)nbuck * cap * 4);
    __half* h2h = h1h;
    float* als2 = als1;
    float* ald2 = ald1;

    int binBlocks = 256;                    // R21: long bucket runs
    int epb = (E + binBlocks - 1) / binBlocks;
    int gemm1Blocks = (n + 63) / 64;

    hipMemsetAsync(gcnt, 0, (size_t)nbuck * 4, stream);
    hipMemsetAsync(gmaxu, 0, 32, stream);
    k_wt<<<64, 256, 0, stream>>>(W1, wt16);

    k_binGemm1<<<binBlocks + gemm1Blocks, 256, 0, stream>>>(
        src, dst, gcnt, binbuf, E, nbuck, cap, epb, binBlocks,
        x, wt16, as1, ad1, h1h, als1, ald1, n);
    k_buildGmax4<<<nbuck + 256, 256, 0, stream>>>(gcnt, binbuf, rowp, rowe, csr,
                                                  n, cap, nbuck,
                                                  (const float4*)als1, gmaxu);
    k_agg1<<<(n + 3) / 4, 256, 0, stream>>>(rowp, rowe, csr, als1, ald1, h1h, b1, gmaxu, hmh, n);

    k_gemm2<<<(n + 15) / 16, 640, 0, stream>>>(hmh, W2, as2, ad2, h2h, als2, ald2, n);
    k_gmax1<<<256, 256, 0, stream>>>(als2, gmaxu + 4, n);
    k_agg2<<<(n + 3) / 4, 256, 0, stream>>>(rowp, rowe, csr, als2, ald2, h2h, b2, gmaxu + 4, out, n);
}

// Round 23
// 247.117 us; speedup vs baseline: 1.4507x; 1.2406x over previous
//
#include <hip/hip_runtime.h>
#include <hip/hip_fp16.h>
#include <math.h>

// GAT node classification: 2 GATConv layers + ELU + log_softmax.
// N=100000, E=1600000 (+N self loops), IN=128, HEADS=4, HID=32, OUT=40.
//
// Rules learned:
//  - R4: every __shfl executes with ALL 64 lanes active; wave-uniform bounds;
//    predicate VALUES not control flow.
//  - R8: __shfl returns the SOURCE lane's evaluation of its operand.
//  - R9/R15: same-address atomics serialize at every level; many-writer
//    reductions use shfl/LDS-tree form, never atomics.
//  - R10: diff-check unrolled blocks line-by-line after mechanical edits.
//  - R12: 2-deep gather unroll is the sweet spot.
//  - R14: feature accumulation in packed fp16 (__hfma2); logits/dens f32.
//  - R17/R18: independent kernels grid-fused; smem union.
//  - R20: GEMMs on MFMA; identical A/B k-order cancels HW k-permutation.
//  - R21: streaming scatter needs >=128B runs; binBlocks=256.
//  - R22: fixed-stride csr regions kill the bucket scan; al fusions via
//    shfl reduce in the GEMM epilogue.
//  - R23: gemm2 also MFMA (scalar-LDS inner loop was 83us: 256 ds_read_b32
//    per thread for 128 FMAs); pad cols to 48, zero B rows 40-47.

#define SLOPE 0.2f
#define NB 512
#define NBSHIFT 9

typedef _Float16 f16x8 __attribute__((ext_vector_type(8)));
typedef float f32x4 __attribute__((ext_vector_type(4)));

__device__ __forceinline__ unsigned fenc(float f) {
    unsigned b = __float_as_uint(f);
    return (b & 0x80000000u) ? ~b : (b | 0x80000000u);
}
__device__ __forceinline__ float fdec(unsigned u) {
    return __uint_as_float((u & 0x80000000u) ? (u ^ 0x80000000u) : ~u);
}
__device__ __forceinline__ __half2 i2h2(int i) { return *reinterpret_cast<__half2*>(&i); }
__device__ __forceinline__ int h22i(__half2 h) { return *reinterpret_cast<int*>(&h); }
__device__ __forceinline__ __half2 h2shflxor(__half2 v, int off) {
    int j = __shfl_xor(h22i(v), off);
    return i2h2(j);
}

// ------- W transposes to f16: wt[c][k]=W1[k][c]; wt2[c][k]=W2[k][c] (48 rows, 40-47 zero) -------

__global__ __launch_bounds__(256) void k_wtAll(const float* __restrict__ W1, const float* __restrict__ W2,
                                               __half* __restrict__ wt, __half* __restrict__ wt2) {
    int b = blockIdx.x;
    int t = threadIdx.x;
    if (b < 64) {
        int idx = b * 256 + t;               // 16384 elements
        int k = idx & 127, c = idx >> 7;
        wt[(size_t)c * 128 + k] = __float2half_rn(W1[(size_t)k * 128 + c]);
    } else {
        int idx = (b - 64) * 256 + t;        // 6144 elements (48x128)
        int k = idx & 127, c = idx >> 7;
        wt2[(size_t)c * 128 + k] = (c < 40) ? __float2half_rn(W2[(size_t)k * 40 + c])
                                            : __float2half_rn(0.f);
    }
}

// ---------------- CSR bin (device body, smem-carved) ----------------

__device__ void bin_body(const int* __restrict__ src, const int* __restrict__ dst,
                         unsigned* __restrict__ gcnt, unsigned* __restrict__ binbuf,
                         int E, int nbuck, int cap, int epb, int bid, char* smem) {
    unsigned* hist = (unsigned*)smem;
    unsigned* base = hist + 256;
    unsigned* cur  = base + 256;
    int t = threadIdx.x;
    if (t < nbuck) { hist[t] = 0u; cur[t] = 0u; }
    __syncthreads();
    int e0 = bid * epb;
    int e1 = min(E, e0 + epb);
    for (int e = e0 + t; e < e1; e += 256) {
        int bk = dst[e] >> NBSHIFT;
        atomicAdd(&hist[bk], 1u);
    }
    __syncthreads();
    if (t < nbuck) base[t] = hist[t] ? atomicAdd(&gcnt[t], hist[t]) : 0u;
    __syncthreads();
    for (int e = e0 + t; e < e1; e += 256) {
        int d = dst[e];
        int bk = d >> NBSHIFT;
        unsigned p = atomicAdd(&cur[bk], 1u);
        binbuf[(size_t)bk * cap + base[bk] + p] =
            ((unsigned)src[e] << NBSHIFT) | (unsigned)(d & (NB - 1));
    }
}

// ------- Layer1 GEMM via MFMA (64 rows/block, 4 waves) + fused al1 -------

__device__ void gemm1_body(const float* __restrict__ x, const __half* __restrict__ wt,
                           const float* __restrict__ asrc, const float* __restrict__ adst,
                           __half* __restrict__ hh, float* __restrict__ als,
                           float* __restrict__ ald, int n, int bid, char* smem) {
    __half* xs = (__half*)smem;          // [64][136] padded
    int t = threadIdx.x;
    int row0 = bid * 64;
#pragma unroll
    for (int i = 0; i < 8; i++) {
        int flat = t + 256 * i;          // 2048 float4 slots
        int r = flat >> 5, c4 = flat & 31;
        int gr = row0 + r;
        float4 v = make_float4(0.f, 0.f, 0.f, 0.f);
        if (gr < n) v = ((const float4*)(x + (size_t)gr * 128))[c4];
        __half2* p = (__half2*)&xs[r * 136 + c4 * 4];
        p[0] = __floats2half2_rn(v.x, v.y);
        p[1] = __floats2half2_rn(v.z, v.w);
    }
    __syncthreads();
    int w = t >> 6;
    int l = t & 63;
    int cc = l & 15;
    int g  = l >> 4;
    int R  = row0 + w * 16 + g * 4;

    f32x4 acc[8] = {};
#pragma unroll
    for (int kc = 0; kc < 4; kc++) {
        f16x8 af = *(const f16x8*)&xs[(w * 16 + cc) * 136 + kc * 32 + g * 8];
#pragma unroll
        for (int j = 0; j < 8; j++) {
            f16x8 bf = *(const f16x8*)&wt[(size_t)(16 * j + cc) * 128 + kc * 32 + g * 8];
            acc[j] = __builtin_amdgcn_mfma_f32_16x16x32_f16(af, bf, acc[j], 0, 0, 0);
        }
    }
    float vsx[8], vdx[8];
#pragma unroll
    for (int j = 0; j < 8; j++) { vsx[j] = asrc[16 * j + cc]; vdx[j] = adst[16 * j + cc]; }
#pragma unroll
    for (int reg = 0; reg < 4; reg++) {
        int gr = R + reg;
        if (gr < n) {
#pragma unroll
            for (int j = 0; j < 8; j++)
                hh[(size_t)gr * 128 + 16 * j + cc] = __float2half_rn(acc[j][reg]);
        }
        float ps0 = acc[0][reg] * vsx[0] + acc[1][reg] * vsx[1];
        float ps1 = acc[2][reg] * vsx[2] + acc[3][reg] * vsx[3];
        float ps2 = acc[4][reg] * vsx[4] + acc[5][reg] * vsx[5];
        float ps3 = acc[6][reg] * vsx[6] + acc[7][reg] * vsx[7];
        float pd0 = acc[0][reg] * vdx[0] + acc[1][reg] * vdx[1];
        float pd1 = acc[2][reg] * vdx[2] + acc[3][reg] * vdx[3];
        float pd2 = acc[4][reg] * vdx[4] + acc[5][reg] * vdx[5];
        float pd3 = acc[6][reg] * vdx[6] + acc[7][reg] * vdx[7];
#pragma unroll
        for (int off = 1; off <= 8; off <<= 1) {
            ps0 += __shfl_xor(ps0, off); ps1 += __shfl_xor(ps1, off);
            ps2 += __shfl_xor(ps2, off); ps3 += __shfl_xor(ps3, off);
            pd0 += __shfl_xor(pd0, off); pd1 += __shfl_xor(pd1, off);
            pd2 += __shfl_xor(pd2, off); pd3 += __shfl_xor(pd3, off);
        }
        if (cc == 0 && gr < n) {
            *(float4*)(als + (size_t)gr * 4) = make_float4(ps0, ps1, ps2, ps3);
            *(float4*)(ald + (size_t)gr * 4) = make_float4(pd0, pd1, pd2, pd3);
        }
    }
}

// fused: blocks [0,binBlocks) bin; [binBlocks, ...) gemm1. Shared smem union.
__global__ __launch_bounds__(256) void k_binGemm1(const int* src, const int* dst,
                                                  unsigned* gcnt, unsigned* binbuf,
                                                  int E, int nbuck, int cap, int epb, int binBlocks,
                                                  const float* x, const __half* wt,
                                                  const float* asrc, const float* adst,
                                                  __half* hh, float* als, float* ald, int n) {
    __shared__ __align__(16) char smem[17408];
    if ((int)blockIdx.x < binBlocks)
        bin_body(src, dst, gcnt, binbuf, E, nbuck, cap, epb, blockIdx.x, smem);
    else
        gemm1_body(x, wt, asrc, adst, hh, als, ald, n, blockIdx.x - binBlocks, smem);
}

// ------- build (fixed-stride csr regions, writes rowp+rowe) + gmax4 fused -------

__device__ void build_body(const unsigned* __restrict__ gcnt, const unsigned* __restrict__ binbuf,
                           int* __restrict__ rowp, int* __restrict__ rowe,
                           int* __restrict__ csr, int n, int cap, int b) {
    __shared__ int s_cnt[NB];
    __shared__ int s_off[NB];
    __shared__ int sums[256];
    int t = threadIdx.x;
    int nn = min(NB, n - b * NB);
    int total = (int)gcnt[b];
    int base = b * (cap + NB);           // fixed region, no bucket scan
    s_cnt[t] = 0; s_cnt[t + 256] = 0;
    __syncthreads();
    const unsigned* rec = binbuf + (size_t)b * cap;
    for (int r = t; r < total; r += 256) atomicAdd(&s_cnt[rec[r] & (NB - 1)], 1);
    __syncthreads();
    int i0 = 2 * t, i1 = 2 * t + 1;
    int v0 = (i0 < nn) ? s_cnt[i0] + 1 : 0;
    int v1 = (i1 < nn) ? s_cnt[i1] + 1 : 0;
    int ps = v0 + v1;
    sums[t] = ps;
    __syncthreads();
    for (int off = 1; off < 256; off <<= 1) {
        int x = (t >= off) ? sums[t - off] : 0;
        __syncthreads();
        sums[t] += x;
        __syncthreads();
    }
    int ex = sums[t] - ps;
    s_off[i0] = ex;
    s_off[i1] = ex + v0;
    if (i0 < nn) {
        rowp[b * NB + i0] = base + ex;
        rowe[b * NB + i0] = base + ex + v0;
        csr[base + ex] = b * NB + i0;
    }
    if (i1 < nn) {
        rowp[b * NB + i1] = base + ex + v0;
        rowe[b * NB + i1] = base + ex + v0 + v1;
        csr[base + ex + v0] = b * NB + i1;
    }
    __syncthreads();
    s_cnt[t] = 1; s_cnt[t + 256] = 1;   // cursor: slot 0 = self loop
    __syncthreads();
    for (int r = t; r < total; r += 256) {
        unsigned rc = rec[r];
        int ld = rc & (NB - 1);
        int p = atomicAdd(&s_cnt[ld], 1);
        csr[base + s_off[ld] + p] = (int)(rc >> NBSHIFT);
    }
}

__device__ void gmax4_body(const float4* __restrict__ als4, unsigned* gm, int n, int bid) {
    float m0 = -INFINITY, m1 = -INFINITY, m2 = -INFINITY, m3 = -INFINITY;
    for (int i = bid * 256 + threadIdx.x; i < n; i += 256 * 256) {
        float4 v = als4[i];
        m0 = fmaxf(m0, v.x); m1 = fmaxf(m1, v.y);
        m2 = fmaxf(m2, v.z); m3 = fmaxf(m3, v.w);
    }
#pragma unroll
    for (int off = 32; off; off >>= 1) {
        m0 = fmaxf(m0, __shfl_xor(m0, off));
        m1 = fmaxf(m1, __shfl_xor(m1, off));
        m2 = fmaxf(m2, __shfl_xor(m2, off));
        m3 = fmaxf(m3, __shfl_xor(m3, off));
    }
    __shared__ float sm[4][4];
    int wid = threadIdx.x >> 6;
    if ((threadIdx.x & 63) == 0) { sm[wid][0] = m0; sm[wid][1] = m1; sm[wid][2] = m2; sm[wid][3] = m3; }
    __syncthreads();
    if (threadIdx.x == 0) {
        float r0 = sm[0][0], r1 = sm[0][1], r2 = sm[0][2], r3 = sm[0][3];
        for (int w = 1; w < 4; w++) {
            r0 = fmaxf(r0, sm[w][0]); r1 = fmaxf(r1, sm[w][1]);
            r2 = fmaxf(r2, sm[w][2]); r3 = fmaxf(r3, sm[w][3]);
        }
        atomicMax(gm + 0, fenc(r0)); atomicMax(gm + 1, fenc(r1));
        atomicMax(gm + 2, fenc(r2)); atomicMax(gm + 3, fenc(r3));
    }
}

__global__ __launch_bounds__(256) void k_buildGmax4(const unsigned* gcnt, const unsigned* binbuf,
                                                    int* rowp, int* rowe, int* csr,
                                                    int n, int cap, int nbuck,
                                                    const float4* als4, unsigned* gm) {
    if ((int)blockIdx.x < nbuck)
        build_body(gcnt, binbuf, rowp, rowe, csr, n, cap, blockIdx.x);
    else
        gmax4_body(als4, gm, n, blockIdx.x - nbuck);
}

__global__ __launch_bounds__(256) void k_gmax1(const float* __restrict__ als, unsigned* gm, int n) {
    float m = -INFINITY;
    for (int i = blockIdx.x * 256 + threadIdx.x; i < n; i += 256 * 256) m = fmaxf(m, als[i]);
#pragma unroll
    for (int off = 32; off; off >>= 1) m = fmaxf(m, __shfl_xor(m, off));
    __shared__ float sm[4];
    int wid = threadIdx.x >> 6;
    if ((threadIdx.x & 63) == 0) sm[wid] = m;
    __syncthreads();
    if (threadIdx.x == 0)
        atomicMax(gm, fenc(fmaxf(fmaxf(sm[0], sm[1]), fmaxf(sm[2], sm[3]))));
}

// wave per dst node, single edge pass, prep-then-broadcast (2-deep, R12),
// packed fp16 accumulation (R14).
__global__ __launch_bounds__(256) void k_agg1(const int* __restrict__ rowp, const int* __restrict__ rowe,
                                              const int* __restrict__ csr,
                                              const float* __restrict__ als, const float* __restrict__ ald,
                                              const __half* __restrict__ h, const float* __restrict__ b,
                                              const unsigned* __restrict__ gmaxu, __half* __restrict__ out,
                                              int n) {
    int node = blockIdx.x * 4 + (threadIdx.x >> 6);
    if (node >= n) return;
    int lane = threadIdx.x & 63;
    int start = __builtin_amdgcn_readfirstlane(rowp[node]);
    int end   = __builtin_amdgcn_readfirstlane(rowe[node]);

    int g = lane >> 4;
    int lig = lane & 15;
    int head = lig >> 2;

    float4 adv = *(const float4*)(ald + (size_t)node * 4);
    uint4 gu = *(const uint4*)gmaxu;
    float mt, mh0, mh1, mh2, mh3;
    mt = fdec(gu.x) + adv.x; mh0 = mt > 0.f ? mt : SLOPE * mt;
    mt = fdec(gu.y) + adv.y; mh1 = mt > 0.f ? mt : SLOPE * mt;
    mt = fdec(gu.z) + adv.z; mh2 = mt > 0.f ? mt : SLOPE * mt;
    mt = fdec(gu.w) + adv.w; mh3 = mt > 0.f ? mt : SLOPE * mt;

    const __half2 z2 = __floats2half2_rn(0.f, 0.f);
    float den0 = 0.f, den1 = 0.f, den2 = 0.f, den3 = 0.f;
    __half2 ah0 = z2, ah1 = z2, ah2 = z2, ah3 = z2;

    for (int k0 = start; k0 < end; k0 += 64) {
        int nb = end - k0; if (nb > 64) nb = 64;
        int s_l = (lane < nb) ? csr[k0 + lane] : 0;
        float4 av = *(const float4*)(als + (size_t)s_l * 4);
        float e, x0, x1, x2, x3;
        e = av.x + adv.x; e = e > 0.f ? e : SLOPE * e; x0 = __expf(e - mh0);
        e = av.y + adv.y; e = e > 0.f ? e : SLOPE * e; x1 = __expf(e - mh1);
        e = av.z + adv.z; e = e > 0.f ? e : SLOPE * e; x2 = __expf(e - mh2);
        e = av.w + adv.w; e = e > 0.f ? e : SLOPE * e; x3 = __expf(e - mh3);
        bool valid = lane < nb;
        x0 = valid ? x0 : 0.f; x1 = valid ? x1 : 0.f;
        x2 = valid ? x2 : 0.f; x3 = valid ? x3 : 0.f;
        den0 += x0; den1 += x1; den2 += x2; den3 += x3;
        __half2 p01 = __floats2half2_rn(x0, x1);
        __half2 p23 = __floats2half2_rn(x2, x3);
        int w01 = h22i(p01);
        int w23 = h22i(p23);

        for (int jj = 0; jj < nb; jj += 8) {
            int eA = jj + g;
            int eB = jj + 4 + g;
            int sA = __shfl(s_l, eA);
            int sB = __shfl(s_l, eB);
            int wA01 = __shfl(w01, eA);
            int wA23 = __shfl(w23, eA);
            int wB01 = __shfl(w01, eB);
            int wB23 = __shfl(w23, eB);
            int wA = (head & 2) ? wA23 : wA01;
            int wB = (head & 2) ? wB23 : wB01;
            uint4 hvA = *(const uint4*)(h + ((size_t)sA << 7) + lig * 8);
            uint4 hvB = *(const uint4*)(h + ((size_t)sB << 7) + lig * 8);
            __half exhA = (head & 1) ? __high2half(i2h2(wA)) : __low2half(i2h2(wA));
            __half exhB = (head & 1) ? __high2half(i2h2(wB)) : __low2half(i2h2(wB));
            __half2 exA2 = __half2half2(exhA);
            __half2 exB2 = __half2half2(exhB);
            exA2 = (eA < nb) ? exA2 : z2;
            exB2 = (eB < nb) ? exB2 : z2;
            ah0 = __hfma2(exA2, i2h2((int)hvA.x), ah0);
            ah1 = __hfma2(exA2, i2h2((int)hvA.y), ah1);
            ah2 = __hfma2(exA2, i2h2((int)hvA.z), ah2);
            ah3 = __hfma2(exA2, i2h2((int)hvA.w), ah3);
            ah0 = __hfma2(exB2, i2h2((int)hvB.x), ah0);
            ah1 = __hfma2(exB2, i2h2((int)hvB.y), ah1);
            ah2 = __hfma2(exB2, i2h2((int)hvB.z), ah2);
            ah3 = __hfma2(exB2, i2h2((int)hvB.w), ah3);
        }
    }
#pragma unroll
    for (int off = 32; off; off >>= 1) {
        den0 += __shfl_xor(den0, off);
        den1 += __shfl_xor(den1, off);
        den2 += __shfl_xor(den2, off);
        den3 += __shfl_xor(den3, off);
    }
    ah0 = __hadd2(ah0, h2shflxor(ah0, 16));
    ah1 = __hadd2(ah1, h2shflxor(ah1, 16));
    ah2 = __hadd2(ah2, h2shflxor(ah2, 16));
    ah3 = __hadd2(ah3, h2shflxor(ah3, 16));
    ah0 = __hadd2(ah0, h2shflxor(ah0, 32));
    ah1 = __hadd2(ah1, h2shflxor(ah1, 32));
    ah2 = __hadd2(ah2, h2shflxor(ah2, 32));
    ah3 = __hadd2(ah3, h2shflxor(ah3, 32));
    if (g == 0) {
        float den_h = (head & 2) ? ((head & 1) ? den3 : den2) : ((head & 1) ? den1 : den0);
        float inv = 1.f / den_h;
        float2 f0 = __half22float2(ah0);
        float2 f1 = __half22float2(ah1);
        float2 f2 = __half22float2(ah2);
        float2 f3 = __half22float2(ah3);
        float4 bv0 = *(const float4*)(b + lig * 8);
        float4 bv1 = *(const float4*)(b + lig * 8 + 4);
        float o0, o1, o2, o3, o4, o5, o6, o7;
        o0 = f0.x * inv + bv0.x; o0 = o0 > 0.f ? o0 : expm1f(o0);
        o1 = f0.y * inv + bv0.y; o1 = o1 > 0.f ? o1 : expm1f(o1);
        o2 = f1.x * inv + bv0.z; o2 = o2 > 0.f ? o2 : expm1f(o2);
        o3 = f1.y * inv + bv0.w; o3 = o3 > 0.f ? o3 : expm1f(o3);
        o4 = f2.x * inv + bv1.x; o4 = o4 > 0.f ? o4 : expm1f(o4);
        o5 = f2.y * inv + bv1.y; o5 = o5 > 0.f ? o5 : expm1f(o5);
        o6 = f3.x * inv + bv1.z; o6 = o6 > 0.f ? o6 : expm1f(o6);
        o7 = f3.y * inv + bv1.w; o7 = o7 > 0.f ? o7 : expm1f(o7);
        __half2 q0 = __floats2half2_rn(o0, o1);
        __half2 q1 = __floats2half2_rn(o2, o3);
        __half2 q2 = __floats2half2_rn(o4, o5);
        __half2 q3 = __floats2half2_rn(o6, o7);
        uint4 st;
        st.x = (unsigned)h22i(q0);
        st.y = (unsigned)h22i(q1);
        st.z = (unsigned)h22i(q2);
        st.w = (unsigned)h22i(q3);
        *(uint4*)(out + ((size_t)node << 7) + lig * 8) = st;
    }
}

// ------- Layer 2 GEMM via MFMA (64 rows/block, 4 waves, 3 col-tiles) + fused al2 -------

__global__ __launch_bounds__(256) void k_gemm2(const __half* __restrict__ hm, const __half* __restrict__ wt2,
                                               const float* __restrict__ a_s, const float* __restrict__ a_d,
                                               __half* __restrict__ h2h, float* __restrict__ als,
                                               float* __restrict__ ald, int n) {
    __shared__ __align__(16) __half xs[64 * 136];   // padded rows (17 uint4 each)
    int t = threadIdx.x;
    int row0 = blockIdx.x * 64;
#pragma unroll
    for (int i = 0; i < 4; i++) {
        int flat = t + 256 * i;          // 1024 uint4 slots
        int r = flat >> 4, c16 = flat & 15;
        int gr = row0 + r;
        uint4 v = make_uint4(0u, 0u, 0u, 0u);
        if (gr < n) v = *(const uint4*)(hm + (size_t)gr * 128 + c16 * 8);
        *(uint4*)&xs[r * 136 + c16 * 8] = v;
    }
    __syncthreads();
    int w = t >> 6;
    int l = t & 63;
    int cc = l & 15;
    int g  = l >> 4;
    int R  = row0 + w * 16 + g * 4;

    f32x4 acc[3] = {};
#pragma unroll
    for (int kc = 0; kc < 4; kc++) {
        f16x8 af = *(const f16x8*)&xs[(w * 16 + cc) * 136 + kc * 32 + g * 8];
#pragma unroll
        for (int j = 0; j < 3; j++) {
            f16x8 bf = *(const f16x8*)&wt2[(size_t)(16 * j + cc) * 128 + kc * 32 + g * 8];
            acc[j] = __builtin_amdgcn_mfma_f32_16x16x32_f16(af, bf, acc[j], 0, 0, 0);
        }
    }
    float vsx[3], vdx[3];
#pragma unroll
    for (int j = 0; j < 3; j++) {
        int c = 16 * j + cc;
        vsx[j] = (c < 40) ? a_s[c] : 0.f;
        vdx[j] = (c < 40) ? a_d[c] : 0.f;
    }
#pragma unroll
    for (int reg = 0; reg < 4; reg++) {
        int gr = R + reg;
        if (gr < n) {
#pragma unroll
            for (int j = 0; j < 3; j++) {
                int c = 16 * j + cc;
                if (c < 40) h2h[(size_t)gr * 40 + c] = __float2half_rn(acc[j][reg]);
            }
        }
        // fused al2: single head; 16-lane shfl reduce (all lanes run -- R4).
        float ps = acc[0][reg] * vsx[0] + acc[1][reg] * vsx[1] + acc[2][reg] * vsx[2];
        float pd = acc[0][reg] * vdx[0] + acc[1][reg] * vdx[1] + acc[2][reg] * vdx[2];
#pragma unroll
        for (int off = 1; off <= 8; off <<= 1) {
            ps += __shfl_xor(ps, off);
            pd += __shfl_xor(pd, off);
        }
        if (cc == 0 && gr < n) {
            als[gr] = ps;
            ald[gr] = pd;
        }
    }
}

// wave per node, single edge pass + log_softmax (2-deep, packed fp16 acc).
__global__ __launch_bounds__(256) void k_agg2(const int* __restrict__ rowp, const int* __restrict__ rowe,
                                              const int* __restrict__ csr,
                                              const float* __restrict__ als, const float* __restrict__ ald,
                                              const __half* __restrict__ h2, const float* __restrict__ b2,
                                              const unsigned* __restrict__ gmaxu, float* __restrict__ out,
                                              int n) {
    int node = blockIdx.x * 4 + (threadIdx.x >> 6);
    if (node >= n) return;
    int lane = threadIdx.x & 63;
    int start = __builtin_amdgcn_readfirstlane(rowp[node]);
    int end   = __builtin_amdgcn_readfirstlane(rowe[node]);
    float ad = ald[node];
    float mt = fdec(gmaxu[0]) + ad;
    float mh = mt > 0.f ? mt : SLOPE * mt;

    int g = lane / 5;
    int lig = lane - g * 5;
    bool act = g < 12;

    const __half2 z2 = __floats2half2_rn(0.f, 0.f);
    float den = 0.f;
    __half2 ah0 = z2, ah1 = z2, ah2 = z2, ah3 = z2;
    for (int k0 = start; k0 < end; k0 += 64) {
        int nb = end - k0; if (nb > 64) nb = 64;
        int s_l = (lane < nb) ? csr[k0 + lane] : 0;
        float e = als[s_l] + ad; e = e > 0.f ? e : SLOPE * e;
        float ex_l = __expf(e - mh);
        ex_l = (lane < nb) ? ex_l : 0.f;
        den += ex_l;
        __half exh_l = __float2half_rn(ex_l);
        int exi_l = h22i(__half2half2(exh_l));

        for (int jj = 0; jj < nb; jj += 24) {
            int eA = jj + g;
            int eB = jj + 12 + g;
            int sA = __shfl(s_l, eA & 63);
            int sB = __shfl(s_l, eB & 63);
            int exAi = __shfl(exi_l, eA & 63);
            int exBi = __shfl(exi_l, eB & 63);
            uint4 hvA = *(const uint4*)(h2 + (size_t)sA * 40 + lig * 8);
            uint4 hvB = *(const uint4*)(h2 + (size_t)sB * 40 + lig * 8);
            __half2 exA2 = i2h2(exAi);
            __half2 exB2 = i2h2(exBi);
            exA2 = (act && eA < nb) ? exA2 : z2;
            exB2 = (act && eB < nb) ? exB2 : z2;
            ah0 = __hfma2(exA2, i2h2((int)hvA.x), ah0);
            ah1 = __hfma2(exA2, i2h2((int)hvA.y), ah1);
            ah2 = __hfma2(exA2, i2h2((int)hvA.z), ah2);
            ah3 = __hfma2(exA2, i2h2((int)hvA.w), ah3);
            ah0 = __hfma2(exB2, i2h2((int)hvB.x), ah0);
            ah1 = __hfma2(exB2, i2h2((int)hvB.y), ah1);
            ah2 = __hfma2(exB2, i2h2((int)hvB.z), ah2);
            ah3 = __hfma2(exB2, i2h2((int)hvB.w), ah3);
        }
    }
#pragma unroll
    for (int off = 32; off; off >>= 1) den += __shfl_xor(den, off);
    int t1i;
    t1i = __shfl(h22i(ah0), (lane + 30) & 63); ah0 = __hadd2(ah0, i2h2(t1i));
    t1i = __shfl(h22i(ah1), (lane + 30) & 63); ah1 = __hadd2(ah1, i2h2(t1i));
    t1i = __shfl(h22i(ah2), (lane + 30) & 63); ah2 = __hadd2(ah2, i2h2(t1i));
    t1i = __shfl(h22i(ah3), (lane + 30) & 63); ah3 = __hadd2(ah3, i2h2(t1i));
    t1i = __shfl(h22i(ah0), (lane + 15) & 63); ah0 = __hadd2(ah0, i2h2(t1i));
    t1i = __shfl(h22i(ah1), (lane + 15) & 63); ah1 = __hadd2(ah1, i2h2(t1i));
    t1i = __shfl(h22i(ah2), (lane + 15) & 63); ah2 = __hadd2(ah2, i2h2(t1i));
    t1i = __shfl(h22i(ah3), (lane + 15) & 63); ah3 = __hadd2(ah3, i2h2(t1i));
    int t2i;
    t1i = __shfl(h22i(ah0), (lane + 5) & 63); t2i = __shfl(h22i(ah0), (lane + 10) & 63);
    ah0 = __hadd2(__hadd2(ah0, i2h2(t1i)), i2h2(t2i));
    t1i = __shfl(h22i(ah1), (lane + 5) & 63); t2i = __shfl(h22i(ah1), (lane + 10) & 63);
    ah1 = __hadd2(__hadd2(ah1, i2h2(t1i)), i2h2(t2i));
    t1i = __shfl(h22i(ah2), (lane + 5) & 63); t2i = __shfl(h22i(ah2), (lane + 10) & 63);
    ah2 = __hadd2(__hadd2(ah2, i2h2(t1i)), i2h2(t2i));
    t1i = __shfl(h22i(ah3), (lane + 5) & 63); t2i = __shfl(h22i(ah3), (lane + 10) & 63);
    ah3 = __hadd2(__hadd2(ah3, i2h2(t1i)), i2h2(t2i));

    float v0 = 0.f, v1 = 0.f, v2 = 0.f, v3 = 0.f, v4 = 0.f, v5 = 0.f, v6 = 0.f, v7 = 0.f;
    float mv = -INFINITY;
    if (lane < 5) {
        float inv = 1.f / den;
        float2 f0 = __half22float2(ah0);
        float2 f1 = __half22float2(ah1);
        float2 f2 = __half22float2(ah2);
        float2 f3 = __half22float2(ah3);
        float4 bv0 = *(const float4*)(b2 + lane * 8);
        float4 bv1 = *(const float4*)(b2 + lane * 8 + 4);
        v0 = f0.x * inv + bv0.x; v1 = f0.y * inv + bv0.y;
        v2 = f1.x * inv + bv0.z; v3 = f1.y * inv + bv0.w;
        v4 = f2.x * inv + bv1.x; v5 = f2.y * inv + bv1.y;
        v6 = f3.x * inv + bv1.z; v7 = f3.y * inv + bv1.w;
        mv = fmaxf(fmaxf(fmaxf(v0, v1), fmaxf(v2, v3)),
                   fmaxf(fmaxf(v4, v5), fmaxf(v6, v7)));
    }
#pragma unroll
    for (int off = 32; off; off >>= 1) mv = fmaxf(mv, __shfl_xor(mv, off));
    float se = 0.f;
    if (lane < 5)
        se = __expf(v0 - mv) + __expf(v1 - mv) + __expf(v2 - mv) + __expf(v3 - mv)
           + __expf(v4 - mv) + __expf(v5 - mv) + __expf(v6 - mv) + __expf(v7 - mv);
#pragma unroll
    for (int off = 32; off; off >>= 1) se += __shfl_xor(se, off);
    if (lane < 5) {
        float lse = mv + __logf(se);
        float4 o0, o1;
        o0.x = v0 - lse; o0.y = v1 - lse; o0.z = v2 - lse; o0.w = v3 - lse;
        o1.x = v4 - lse; o1.y = v5 - lse; o1.z = v6 - lse; o1.w = v7 - lse;
        *(float4*)(out + (size_t)node * 40 + lane * 8) = o0;
        *(float4*)(out + (size_t)node * 40 + lane * 8 + 4) = o1;
    }
}

// ---------------- launch ----------------

extern "C" void kernel_launch(void* const* d_in, const int* in_sizes, int n_in,
                              void* d_out, int out_size, void* d_ws, size_t ws_size,
                              hipStream_t stream) {
    const float* x   = (const float*)d_in[0];
    const int*   ei  = (const int*)d_in[1];
    const float* W1  = (const float*)d_in[2];
    const float* as1 = (const float*)d_in[3];
    const float* ad1 = (const float*)d_in[4];
    const float* b1  = (const float*)d_in[5];
    const float* W2  = (const float*)d_in[6];
    const float* as2 = (const float*)d_in[7];
    const float* ad2 = (const float*)d_in[8];
    const float* b2  = (const float*)d_in[9];
    float* out = (float*)d_out;

    int n = in_sizes[0] / 128;
    int E = in_sizes[1] / 2;
    const int* src = ei;
    const int* dst = ei + E;

    int nbuck = (n + NB - 1) / NB;
    int cap = (2 * (E / nbuck) + 1023) / 1024 * 1024;

    char* ws = (char*)d_ws;
    size_t off = 0;
    auto alloc = [&](size_t bytes) {
        void* p = ws + off;
        off += (bytes + 255) & ~(size_t)255;
        return p;
    };
    int*      rowp   = (int*)alloc((size_t)n * 4);
    int*      rowe   = (int*)alloc((size_t)n * 4);
    int*      csr    = (int*)alloc((size_t)nbuck * (cap + NB) * 4);
    __half*   h1h    = (__half*)alloc((size_t)n * 128 * 2);
    __half*   hmh    = (__half*)alloc((size_t)n * 128 * 2);
    float*    als1   = (float*)alloc((size_t)n * 4 * 4);
    float*    ald1   = (float*)alloc((size_t)n * 4 * 4);
    unsigned* gmaxu  = (unsigned*)alloc(256);
    unsigned* gcnt   = (unsigned*)alloc((size_t)nbuck * 4);
    __half*   wt16   = (__half*)alloc(128 * 128 * 2);
    __half*   wt2    = (__half*)alloc(48 * 128 * 2);
    unsigned* binbuf = (unsigned*)alloc((size_t)nbuck * cap * 4);
    __half* h2h = h1h;
    float* als2 = als1;
    float* ald2 = ald1;

    int binBlocks = 256;                    // R21: long bucket runs
    int epb = (E + binBlocks - 1) / binBlocks;
    int gemmBlocks = (n + 63) / 64;

    hipMemsetAsync(gcnt, 0, (size_t)nbuck * 4, stream);
    hipMemsetAsync(gmaxu, 0, 32, stream);
    k_wtAll<<<88, 256, 0, stream>>>(W1, W2, wt16, wt2);

    k_binGemm1<<<binBlocks + gemmBlocks, 256, 0, stream>>>(
        src, dst, gcnt, binbuf, E, nbuck, cap, epb, binBlocks,
        x, wt16, as1, ad1, h1h, als1, ald1, n);
    k_buildGmax4<<<nbuck + 256, 256, 0, stream>>>(gcnt, binbuf, rowp, rowe, csr,
                                                  n, cap, nbuck,
                                                  (const float4*)als1, gmaxu);
    k_agg1<<<(n + 3) / 4, 256, 0, stream>>>(rowp, rowe, csr, als1, ald1, h1h, b1, gmaxu, hmh, n);

    k_gemm2<<<gemmBlocks, 256, 0, stream>>>(hmh, wt2, as2, ad2, h2h, als2, ald2, n);
    k_gmax1<<<256, 256, 0, stream>>>(als2, gmaxu + 4, n);
    k_agg2<<<(n + 3) / 4, 256, 0, stream>>>(rowp, rowe, csr, als2, ald2, h2h, b2, gmaxu + 4, out, n);
}

// Round 24
// 242.297 us; speedup vs baseline: 1.4796x; 1.0199x over previous
//
#include <hip/hip_runtime.h>
#include <hip/hip_fp16.h>
#include <math.h>

// GAT node classification: 2 GATConv layers + ELU + log_softmax.
// N=100000, E=1600000 (+N self loops), IN=128, HEADS=4, HID=32, OUT=40.
//
// Rules learned:
//  - R4: every __shfl executes with ALL 64 lanes active; wave-uniform bounds;
//    predicate VALUES not control flow.
//  - R8: __shfl returns the SOURCE lane's evaluation of its operand.
//  - R9/R15: same-address atomics serialize at every level; many-writer
//    reductions use shfl/LDS-tree form, never atomics.
//  - R10: diff-check unrolled blocks line-by-line after mechanical edits.
//  - R12: 2-deep gather unroll is the sweet spot.
//  - R14: feature accumulation in packed fp16 (__hfma2); logits/dens f32.
//  - R17/R18: independent kernels grid-fused; smem union.
//  - R20/R23: both GEMMs on MFMA; identical A/B k-order cancels HW k-perm.
//  - R21: streaming scatter needs >=128B runs; binBlocks=256.
//  - R22: fixed-stride csr regions; al fusions via shfl reduce in GEMM epilogue.
//  - R24: dispatch-tail consolidation -- memsets folded into k_wtAll;
//    gemm2 emits per-block maxes so gmax1 reduces 1563 floats in 1 block.

#define SLOPE 0.2f
#define NB 512
#define NBSHIFT 9

typedef _Float16 f16x8 __attribute__((ext_vector_type(8)));
typedef float f32x4 __attribute__((ext_vector_type(4)));

__device__ __forceinline__ unsigned fenc(float f) {
    unsigned b = __float_as_uint(f);
    return (b & 0x80000000u) ? ~b : (b | 0x80000000u);
}
__device__ __forceinline__ float fdec(unsigned u) {
    return __uint_as_float((u & 0x80000000u) ? (u ^ 0x80000000u) : ~u);
}
__device__ __forceinline__ __half2 i2h2(int i) { return *reinterpret_cast<__half2*>(&i); }
__device__ __forceinline__ int h22i(__half2 h) { return *reinterpret_cast<int*>(&h); }
__device__ __forceinline__ __half2 h2shflxor(__half2 v, int off) {
    int j = __shfl_xor(h22i(v), off);
    return i2h2(j);
}

// ------- W transposes + scratch zeroing (R24: block 88 zeroes gcnt/gmaxu) -------

__global__ __launch_bounds__(256) void k_wtAll(const float* __restrict__ W1, const float* __restrict__ W2,
                                               __half* __restrict__ wt, __half* __restrict__ wt2,
                                               unsigned* __restrict__ gcnt, unsigned* __restrict__ gmaxu,
                                               int nbuck) {
    int b = blockIdx.x;
    int t = threadIdx.x;
    if (b < 64) {
        int idx = b * 256 + t;               // 16384 elements
        int k = idx & 127, c = idx >> 7;
        wt[(size_t)c * 128 + k] = __float2half_rn(W1[(size_t)k * 128 + c]);
    } else if (b < 88) {
        int idx = (b - 64) * 256 + t;        // 6144 elements (48x128)
        int k = idx & 127, c = idx >> 7;
        wt2[(size_t)c * 128 + k] = (c < 40) ? __float2half_rn(W2[(size_t)k * 40 + c])
                                            : __float2half_rn(0.f);
    } else {
        if (t < nbuck) gcnt[t] = 0u;
        if (t >= 248) gmaxu[t - 248] = 0u;   // 8 slots
    }
}

// ---------------- CSR bin (device body, smem-carved) ----------------

__device__ void bin_body(const int* __restrict__ src, const int* __restrict__ dst,
                         unsigned* __restrict__ gcnt, unsigned* __restrict__ binbuf,
                         int E, int nbuck, int cap, int epb, int bid, char* smem) {
    unsigned* hist = (unsigned*)smem;
    unsigned* base = hist + 256;
    unsigned* cur  = base + 256;
    int t = threadIdx.x;
    if (t < nbuck) { hist[t] = 0u; cur[t] = 0u; }
    __syncthreads();
    int e0 = bid * epb;
    int e1 = min(E, e0 + epb);
    for (int e = e0 + t; e < e1; e += 256) {
        int bk = dst[e] >> NBSHIFT;
        atomicAdd(&hist[bk], 1u);
    }
    __syncthreads();
    if (t < nbuck) base[t] = hist[t] ? atomicAdd(&gcnt[t], hist[t]) : 0u;
    __syncthreads();
    for (int e = e0 + t; e < e1; e += 256) {
        int d = dst[e];
        int bk = d >> NBSHIFT;
        unsigned p = atomicAdd(&cur[bk], 1u);
        binbuf[(size_t)bk * cap + base[bk] + p] =
            ((unsigned)src[e] << NBSHIFT) | (unsigned)(d & (NB - 1));
    }
}

// ------- Layer1 GEMM via MFMA (64 rows/block, 4 waves) + fused al1 -------

__device__ void gemm1_body(const float* __restrict__ x, const __half* __restrict__ wt,
                           const float* __restrict__ asrc, const float* __restrict__ adst,
                           __half* __restrict__ hh, float* __restrict__ als,
                           float* __restrict__ ald, int n, int bid, char* smem) {
    __half* xs = (__half*)smem;          // [64][136] padded
    int t = threadIdx.x;
    int row0 = bid * 64;
#pragma unroll
    for (int i = 0; i < 8; i++) {
        int flat = t + 256 * i;          // 2048 float4 slots
        int r = flat >> 5, c4 = flat & 31;
        int gr = row0 + r;
        float4 v = make_float4(0.f, 0.f, 0.f, 0.f);
        if (gr < n) v = ((const float4*)(x + (size_t)gr * 128))[c4];
        __half2* p = (__half2*)&xs[r * 136 + c4 * 4];
        p[0] = __floats2half2_rn(v.x, v.y);
        p[1] = __floats2half2_rn(v.z, v.w);
    }
    __syncthreads();
    int w = t >> 6;
    int l = t & 63;
    int cc = l & 15;
    int g  = l >> 4;
    int R  = row0 + w * 16 + g * 4;

    f32x4 acc[8] = {};
#pragma unroll
    for (int kc = 0; kc < 4; kc++) {
        f16x8 af = *(const f16x8*)&xs[(w * 16 + cc) * 136 + kc * 32 + g * 8];
#pragma unroll
        for (int j = 0; j < 8; j++) {
            f16x8 bf = *(const f16x8*)&wt[(size_t)(16 * j + cc) * 128 + kc * 32 + g * 8];
            acc[j] = __builtin_amdgcn_mfma_f32_16x16x32_f16(af, bf, acc[j], 0, 0, 0);
        }
    }
    float vsx[8], vdx[8];
#pragma unroll
    for (int j = 0; j < 8; j++) { vsx[j] = asrc[16 * j + cc]; vdx[j] = adst[16 * j + cc]; }
#pragma unroll
    for (int reg = 0; reg < 4; reg++) {
        int gr = R + reg;
        if (gr < n) {
#pragma unroll
            for (int j = 0; j < 8; j++)
                hh[(size_t)gr * 128 + 16 * j + cc] = __float2half_rn(acc[j][reg]);
        }
        float ps0 = acc[0][reg] * vsx[0] + acc[1][reg] * vsx[1];
        float ps1 = acc[2][reg] * vsx[2] + acc[3][reg] * vsx[3];
        float ps2 = acc[4][reg] * vsx[4] + acc[5][reg] * vsx[5];
        float ps3 = acc[6][reg] * vsx[6] + acc[7][reg] * vsx[7];
        float pd0 = acc[0][reg] * vdx[0] + acc[1][reg] * vdx[1];
        float pd1 = acc[2][reg] * vdx[2] + acc[3][reg] * vdx[3];
        float pd2 = acc[4][reg] * vdx[4] + acc[5][reg] * vdx[5];
        float pd3 = acc[6][reg] * vdx[6] + acc[7][reg] * vdx[7];
#pragma unroll
        for (int off = 1; off <= 8; off <<= 1) {
            ps0 += __shfl_xor(ps0, off); ps1 += __shfl_xor(ps1, off);
            ps2 += __shfl_xor(ps2, off); ps3 += __shfl_xor(ps3, off);
            pd0 += __shfl_xor(pd0, off); pd1 += __shfl_xor(pd1, off);
            pd2 += __shfl_xor(pd2, off); pd3 += __shfl_xor(pd3, off);
        }
        if (cc == 0 && gr < n) {
            *(float4*)(als + (size_t)gr * 4) = make_float4(ps0, ps1, ps2, ps3);
            *(float4*)(ald + (size_t)gr * 4) = make_float4(pd0, pd1, pd2, pd3);
        }
    }
}

// fused: blocks [0,binBlocks) bin; [binBlocks, ...) gemm1. Shared smem union.
__global__ __launch_bounds__(256) void k_binGemm1(const int* src, const int* dst,
                                                  unsigned* gcnt, unsigned* binbuf,
                                                  int E, int nbuck, int cap, int epb, int binBlocks,
                                                  const float* x, const __half* wt,
                                                  const float* asrc, const float* adst,
                                                  __half* hh, float* als, float* ald, int n) {
    __shared__ __align__(16) char smem[17408];
    if ((int)blockIdx.x < binBlocks)
        bin_body(src, dst, gcnt, binbuf, E, nbuck, cap, epb, blockIdx.x, smem);
    else
        gemm1_body(x, wt, asrc, adst, hh, als, ald, n, blockIdx.x - binBlocks, smem);
}

// ------- build (fixed-stride csr regions, writes rowp+rowe) + gmax4 fused -------

__device__ void build_body(const unsigned* __restrict__ gcnt, const unsigned* __restrict__ binbuf,
                           int* __restrict__ rowp, int* __restrict__ rowe,
                           int* __restrict__ csr, int n, int cap, int b) {
    __shared__ int s_cnt[NB];
    __shared__ int s_off[NB];
    __shared__ int sums[256];
    int t = threadIdx.x;
    int nn = min(NB, n - b * NB);
    int total = (int)gcnt[b];
    int base = b * (cap + NB);           // fixed region, no bucket scan
    s_cnt[t] = 0; s_cnt[t + 256] = 0;
    __syncthreads();
    const unsigned* rec = binbuf + (size_t)b * cap;
    for (int r = t; r < total; r += 256) atomicAdd(&s_cnt[rec[r] & (NB - 1)], 1);
    __syncthreads();
    int i0 = 2 * t, i1 = 2 * t + 1;
    int v0 = (i0 < nn) ? s_cnt[i0] + 1 : 0;
    int v1 = (i1 < nn) ? s_cnt[i1] + 1 : 0;
    int ps = v0 + v1;
    sums[t] = ps;
    __syncthreads();
    for (int off = 1; off < 256; off <<= 1) {
        int x = (t >= off) ? sums[t - off] : 0;
        __syncthreads();
        sums[t] += x;
        __syncthreads();
    }
    int ex = sums[t] - ps;
    s_off[i0] = ex;
    s_off[i1] = ex + v0;
    if (i0 < nn) {
        rowp[b * NB + i0] = base + ex;
        rowe[b * NB + i0] = base + ex + v0;
        csr[base + ex] = b * NB + i0;
    }
    if (i1 < nn) {
        rowp[b * NB + i1] = base + ex + v0;
        rowe[b * NB + i1] = base + ex + v0 + v1;
        csr[base + ex + v0] = b * NB + i1;
    }
    __syncthreads();
    s_cnt[t] = 1; s_cnt[t + 256] = 1;   // cursor: slot 0 = self loop
    __syncthreads();
    for (int r = t; r < total; r += 256) {
        unsigned rc = rec[r];
        int ld = rc & (NB - 1);
        int p = atomicAdd(&s_cnt[ld], 1);
        csr[base + s_off[ld] + p] = (int)(rc >> NBSHIFT);
    }
}

__device__ void gmax4_body(const float4* __restrict__ als4, unsigned* gm, int n, int bid) {
    float m0 = -INFINITY, m1 = -INFINITY, m2 = -INFINITY, m3 = -INFINITY;
    for (int i = bid * 256 + threadIdx.x; i < n; i += 256 * 256) {
        float4 v = als4[i];
        m0 = fmaxf(m0, v.x); m1 = fmaxf(m1, v.y);
        m2 = fmaxf(m2, v.z); m3 = fmaxf(m3, v.w);
    }
#pragma unroll
    for (int off = 32; off; off >>= 1) {
        m0 = fmaxf(m0, __shfl_xor(m0, off));
        m1 = fmaxf(m1, __shfl_xor(m1, off));
        m2 = fmaxf(m2, __shfl_xor(m2, off));
        m3 = fmaxf(m3, __shfl_xor(m3, off));
    }
    __shared__ float sm[4][4];
    int wid = threadIdx.x >> 6;
    if ((threadIdx.x & 63) == 0) { sm[wid][0] = m0; sm[wid][1] = m1; sm[wid][2] = m2; sm[wid][3] = m3; }
    __syncthreads();
    if (threadIdx.x == 0) {
        float r0 = sm[0][0], r1 = sm[0][1], r2 = sm[0][2], r3 = sm[0][3];
        for (int w = 1; w < 4; w++) {
            r0 = fmaxf(r0, sm[w][0]); r1 = fmaxf(r1, sm[w][1]);
            r2 = fmaxf(r2, sm[w][2]); r3 = fmaxf(r3, sm[w][3]);
        }
        atomicMax(gm + 0, fenc(r0)); atomicMax(gm + 1, fenc(r1));
        atomicMax(gm + 2, fenc(r2)); atomicMax(gm + 3, fenc(r3));
    }
}

__global__ __launch_bounds__(256) void k_buildGmax4(const unsigned* gcnt, const unsigned* binbuf,
                                                    int* rowp, int* rowe, int* csr,
                                                    int n, int cap, int nbuck,
                                                    const float4* als4, unsigned* gm) {
    if ((int)blockIdx.x < nbuck)
        build_body(gcnt, binbuf, rowp, rowe, csr, n, cap, blockIdx.x);
    else
        gmax4_body(als4, gm, n, blockIdx.x - nbuck);
}

// single block: reduce per-block maxes (gemmBlocks floats) -> gmaxu[4]
__global__ __launch_bounds__(256) void k_gmax1(const float* __restrict__ gbmax, unsigned* gm, int nb) {
    float m = -INFINITY;
    for (int i = threadIdx.x; i < nb; i += 256) m = fmaxf(m, gbmax[i]);
#pragma unroll
    for (int off = 32; off; off >>= 1) m = fmaxf(m, __shfl_xor(m, off));
    __shared__ float sm[4];
    int wid = threadIdx.x >> 6;
    if ((threadIdx.x & 63) == 0) sm[wid] = m;
    __syncthreads();
    if (threadIdx.x == 0)
        gm[0] = fenc(fmaxf(fmaxf(sm[0], sm[1]), fmaxf(sm[2], sm[3])));
}

// wave per dst node, single edge pass, prep-then-broadcast (2-deep, R12),
// packed fp16 accumulation (R14).
__global__ __launch_bounds__(256) void k_agg1(const int* __restrict__ rowp, const int* __restrict__ rowe,
                                              const int* __restrict__ csr,
                                              const float* __restrict__ als, const float* __restrict__ ald,
                                              const __half* __restrict__ h, const float* __restrict__ b,
                                              const unsigned* __restrict__ gmaxu, __half* __restrict__ out,
                                              int n) {
    int node = blockIdx.x * 4 + (threadIdx.x >> 6);
    if (node >= n) return;
    int lane = threadIdx.x & 63;
    int start = __builtin_amdgcn_readfirstlane(rowp[node]);
    int end   = __builtin_amdgcn_readfirstlane(rowe[node]);

    int g = lane >> 4;
    int lig = lane & 15;
    int head = lig >> 2;

    float4 adv = *(const float4*)(ald + (size_t)node * 4);
    uint4 gu = *(const uint4*)gmaxu;
    float mt, mh0, mh1, mh2, mh3;
    mt = fdec(gu.x) + adv.x; mh0 = mt > 0.f ? mt : SLOPE * mt;
    mt = fdec(gu.y) + adv.y; mh1 = mt > 0.f ? mt : SLOPE * mt;
    mt = fdec(gu.z) + adv.z; mh2 = mt > 0.f ? mt : SLOPE * mt;
    mt = fdec(gu.w) + adv.w; mh3 = mt > 0.f ? mt : SLOPE * mt;

    const __half2 z2 = __floats2half2_rn(0.f, 0.f);
    float den0 = 0.f, den1 = 0.f, den2 = 0.f, den3 = 0.f;
    __half2 ah0 = z2, ah1 = z2, ah2 = z2, ah3 = z2;

    for (int k0 = start; k0 < end; k0 += 64) {
        int nb = end - k0; if (nb > 64) nb = 64;
        int s_l = (lane < nb) ? csr[k0 + lane] : 0;
        float4 av = *(const float4*)(als + (size_t)s_l * 4);
        float e, x0, x1, x2, x3;
        e = av.x + adv.x; e = e > 0.f ? e : SLOPE * e; x0 = __expf(e - mh0);
        e = av.y + adv.y; e = e > 0.f ? e : SLOPE * e; x1 = __expf(e - mh1);
        e = av.z + adv.z; e = e > 0.f ? e : SLOPE * e; x2 = __expf(e - mh2);
        e = av.w + adv.w; e = e > 0.f ? e : SLOPE * e; x3 = __expf(e - mh3);
        bool valid = lane < nb;
        x0 = valid ? x0 : 0.f; x1 = valid ? x1 : 0.f;
        x2 = valid ? x2 : 0.f; x3 = valid ? x3 : 0.f;
        den0 += x0; den1 += x1; den2 += x2; den3 += x3;
        __half2 p01 = __floats2half2_rn(x0, x1);
        __half2 p23 = __floats2half2_rn(x2, x3);
        int w01 = h22i(p01);
        int w23 = h22i(p23);

        for (int jj = 0; jj < nb; jj += 8) {
            int eA = jj + g;
            int eB = jj + 4 + g;
            int sA = __shfl(s_l, eA);
            int sB = __shfl(s_l, eB);
            int wA01 = __shfl(w01, eA);
            int wA23 = __shfl(w23, eA);
            int wB01 = __shfl(w01, eB);
            int wB23 = __shfl(w23, eB);
            int wA = (head & 2) ? wA23 : wA01;
            int wB = (head & 2) ? wB23 : wB01;
            uint4 hvA = *(const uint4*)(h + ((size_t)sA << 7) + lig * 8);
            uint4 hvB = *(const uint4*)(h + ((size_t)sB << 7) + lig * 8);
            __half exhA = (head & 1) ? __high2half(i2h2(wA)) : __low2half(i2h2(wA));
            __half exhB = (head & 1) ? __high2half(i2h2(wB)) : __low2half(i2h2(wB));
            __half2 exA2 = __half2half2(exhA);
            __half2 exB2 = __half2half2(exhB);
            exA2 = (eA < nb) ? exA2 : z2;
            exB2 = (eB < nb) ? exB2 : z2;
            ah0 = __hfma2(exA2, i2h2((int)hvA.x), ah0);
            ah1 = __hfma2(exA2, i2h2((int)hvA.y), ah1);
            ah2 = __hfma2(exA2, i2h2((int)hvA.z), ah2);
            ah3 = __hfma2(exA2, i2h2((int)hvA.w), ah3);
            ah0 = __hfma2(exB2, i2h2((int)hvB.x), ah0);
            ah1 = __hfma2(exB2, i2h2((int)hvB.y), ah1);
            ah2 = __hfma2(exB2, i2h2((int)hvB.z), ah2);
            ah3 = __hfma2(exB2, i2h2((int)hvB.w), ah3);
        }
    }
#pragma unroll
    for (int off = 32; off; off >>= 1) {
        den0 += __shfl_xor(den0, off);
        den1 += __shfl_xor(den1, off);
        den2 += __shfl_xor(den2, off);
        den3 += __shfl_xor(den3, off);
    }
    ah0 = __hadd2(ah0, h2shflxor(ah0, 16));
    ah1 = __hadd2(ah1, h2shflxor(ah1, 16));
    ah2 = __hadd2(ah2, h2shflxor(ah2, 16));
    ah3 = __hadd2(ah3, h2shflxor(ah3, 16));
    ah0 = __hadd2(ah0, h2shflxor(ah0, 32));
    ah1 = __hadd2(ah1, h2shflxor(ah1, 32));
    ah2 = __hadd2(ah2, h2shflxor(ah2, 32));
    ah3 = __hadd2(ah3, h2shflxor(ah3, 32));
    if (g == 0) {
        float den_h = (head & 2) ? ((head & 1) ? den3 : den2) : ((head & 1) ? den1 : den0);
        float inv = 1.f / den_h;
        float2 f0 = __half22float2(ah0);
        float2 f1 = __half22float2(ah1);
        float2 f2 = __half22float2(ah2);
        float2 f3 = __half22float2(ah3);
        float4 bv0 = *(const float4*)(b + lig * 8);
        float4 bv1 = *(const float4*)(b + lig * 8 + 4);
        float o0, o1, o2, o3, o4, o5, o6, o7;
        o0 = f0.x * inv + bv0.x; o0 = o0 > 0.f ? o0 : expm1f(o0);
        o1 = f0.y * inv + bv0.y; o1 = o1 > 0.f ? o1 : expm1f(o1);
        o2 = f1.x * inv + bv0.z; o2 = o2 > 0.f ? o2 : expm1f(o2);
        o3 = f1.y * inv + bv0.w; o3 = o3 > 0.f ? o3 : expm1f(o3);
        o4 = f2.x * inv + bv1.x; o4 = o4 > 0.f ? o4 : expm1f(o4);
        o5 = f2.y * inv + bv1.y; o5 = o5 > 0.f ? o5 : expm1f(o5);
        o6 = f3.x * inv + bv1.z; o6 = o6 > 0.f ? o6 : expm1f(o6);
        o7 = f3.y * inv + bv1.w; o7 = o7 > 0.f ? o7 : expm1f(o7);
        __half2 q0 = __floats2half2_rn(o0, o1);
        __half2 q1 = __floats2half2_rn(o2, o3);
        __half2 q2 = __floats2half2_rn(o4, o5);
        __half2 q3 = __floats2half2_rn(o6, o7);
        uint4 st;
        st.x = (unsigned)h22i(q0);
        st.y = (unsigned)h22i(q1);
        st.z = (unsigned)h22i(q2);
        st.w = (unsigned)h22i(q3);
        *(uint4*)(out + ((size_t)node << 7) + lig * 8) = st;
    }
}

// ------- Layer 2 GEMM via MFMA + fused al2 + per-block als2 max (R24) -------

__global__ __launch_bounds__(256) void k_gemm2(const __half* __restrict__ hm, const __half* __restrict__ wt2,
                                               const float* __restrict__ a_s, const float* __restrict__ a_d,
                                               __half* __restrict__ h2h, float* __restrict__ als,
                                               float* __restrict__ ald, float* __restrict__ gbmax, int n) {
    __shared__ __align__(16) __half xs[64 * 136];   // padded rows (17 uint4 each)
    __shared__ float smax[4];
    int t = threadIdx.x;
    int row0 = blockIdx.x * 64;
#pragma unroll
    for (int i = 0; i < 4; i++) {
        int flat = t + 256 * i;          // 1024 uint4 slots
        int r = flat >> 4, c16 = flat & 15;
        int gr = row0 + r;
        uint4 v = make_uint4(0u, 0u, 0u, 0u);
        if (gr < n) v = *(const uint4*)(hm + (size_t)gr * 128 + c16 * 8);
        *(uint4*)&xs[r * 136 + c16 * 8] = v;
    }
    __syncthreads();
    int w = t >> 6;
    int l = t & 63;
    int cc = l & 15;
    int g  = l >> 4;
    int R  = row0 + w * 16 + g * 4;

    f32x4 acc[3] = {};
#pragma unroll
    for (int kc = 0; kc < 4; kc++) {
        f16x8 af = *(const f16x8*)&xs[(w * 16 + cc) * 136 + kc * 32 + g * 8];
#pragma unroll
        for (int j = 0; j < 3; j++) {
            f16x8 bf = *(const f16x8*)&wt2[(size_t)(16 * j + cc) * 128 + kc * 32 + g * 8];
            acc[j] = __builtin_amdgcn_mfma_f32_16x16x32_f16(af, bf, acc[j], 0, 0, 0);
        }
    }
    float vsx[3], vdx[3];
#pragma unroll
    for (int j = 0; j < 3; j++) {
        int c = 16 * j + cc;
        vsx[j] = (c < 40) ? a_s[c] : 0.f;
        vdx[j] = (c < 40) ? a_d[c] : 0.f;
    }
    float pmax = -INFINITY;
#pragma unroll
    for (int reg = 0; reg < 4; reg++) {
        int gr = R + reg;
        if (gr < n) {
#pragma unroll
            for (int j = 0; j < 3; j++) {
                int c = 16 * j + cc;
                if (c < 40) h2h[(size_t)gr * 40 + c] = __float2half_rn(acc[j][reg]);
            }
        }
        // fused al2: single head; 16-lane shfl reduce (all lanes run -- R4).
        float ps = acc[0][reg] * vsx[0] + acc[1][reg] * vsx[1] + acc[2][reg] * vsx[2];
        float pd = acc[0][reg] * vdx[0] + acc[1][reg] * vdx[1] + acc[2][reg] * vdx[2];
#pragma unroll
        for (int off = 1; off <= 8; off <<= 1) {
            ps += __shfl_xor(ps, off);
            pd += __shfl_xor(pd, off);
        }
        if (gr < n) pmax = fmaxf(pmax, ps);   // als value (uniform in cc group)
        if (cc == 0 && gr < n) {
            als[gr] = ps;
            ald[gr] = pd;
        }
    }
    // per-block als max -> gbmax[bid] (shfl + LDS tree, no atomics -- R15)
#pragma unroll
    for (int off = 32; off; off >>= 1) pmax = fmaxf(pmax, __shfl_xor(pmax, off));
    if (l == 0) smax[w] = pmax;
    __syncthreads();
    if (t == 0)
        gbmax[blockIdx.x] = fmaxf(fmaxf(smax[0], smax[1]), fmaxf(smax[2], smax[3]));
}

// wave per node, single edge pass + log_softmax (2-deep, packed fp16 acc).
__global__ __launch_bounds__(256) void k_agg2(const int* __restrict__ rowp, const int* __restrict__ rowe,
                                              const int* __restrict__ csr,
                                              const float* __restrict__ als, const float* __restrict__ ald,
                                              const __half* __restrict__ h2, const float* __restrict__ b2,
                                              const unsigned* __restrict__ gmaxu, float* __restrict__ out,
                                              int n) {
    int node = blockIdx.x * 4 + (threadIdx.x >> 6);
    if (node >= n) return;
    int lane = threadIdx.x & 63;
    int start = __builtin_amdgcn_readfirstlane(rowp[node]);
    int end   = __builtin_amdgcn_readfirstlane(rowe[node]);
    float ad = ald[node];
    float mt = fdec(gmaxu[0]) + ad;
    float mh = mt > 0.f ? mt : SLOPE * mt;

    int g = lane / 5;
    int lig = lane - g * 5;
    bool act = g < 12;

    const __half2 z2 = __floats2half2_rn(0.f, 0.f);
    float den = 0.f;
    __half2 ah0 = z2, ah1 = z2, ah2 = z2, ah3 = z2;
    for (int k0 = start; k0 < end; k0 += 64) {
        int nb = end - k0; if (nb > 64) nb = 64;
        int s_l = (lane < nb) ? csr[k0 + lane] : 0;
        float e = als[s_l] + ad; e = e > 0.f ? e : SLOPE * e;
        float ex_l = __expf(e - mh);
        ex_l = (lane < nb) ? ex_l : 0.f;
        den += ex_l;
        __half exh_l = __float2half_rn(ex_l);
        int exi_l = h22i(__half2half2(exh_l));

        for (int jj = 0; jj < nb; jj += 24) {
            int eA = jj + g;
            int eB = jj + 12 + g;
            int sA = __shfl(s_l, eA & 63);
            int sB = __shfl(s_l, eB & 63);
            int exAi = __shfl(exi_l, eA & 63);
            int exBi = __shfl(exi_l, eB & 63);
            uint4 hvA = *(const uint4*)(h2 + (size_t)sA * 40 + lig * 8);
            uint4 hvB = *(const uint4*)(h2 + (size_t)sB * 40 + lig * 8);
            __half2 exA2 = i2h2(exAi);
            __half2 exB2 = i2h2(exBi);
            exA2 = (act && eA < nb) ? exA2 : z2;
            exB2 = (act && eB < nb) ? exB2 : z2;
            ah0 = __hfma2(exA2, i2h2((int)hvA.x), ah0);
            ah1 = __hfma2(exA2, i2h2((int)hvA.y), ah1);
            ah2 = __hfma2(exA2, i2h2((int)hvA.z), ah2);
            ah3 = __hfma2(exA2, i2h2((int)hvA.w), ah3);
            ah0 = __hfma2(exB2, i2h2((int)hvB.x), ah0);
            ah1 = __hfma2(exB2, i2h2((int)hvB.y), ah1);
            ah2 = __hfma2(exB2, i2h2((int)hvB.z), ah2);
            ah3 = __hfma2(exB2, i2h2((int)hvB.w), ah3);
        }
    }
#pragma unroll
    for (int off = 32; off; off >>= 1) den += __shfl_xor(den, off);
    int t1i;
    t1i = __shfl(h22i(ah0), (lane + 30) & 63); ah0 = __hadd2(ah0, i2h2(t1i));
    t1i = __shfl(h22i(ah1), (lane + 30) & 63); ah1 = __hadd2(ah1, i2h2(t1i));
    t1i = __shfl(h22i(ah2), (lane + 30) & 63); ah2 = __hadd2(ah2, i2h2(t1i));
    t1i = __shfl(h22i(ah3), (lane + 30) & 63); ah3 = __hadd2(ah3, i2h2(t1i));
    t1i = __shfl(h22i(ah0), (lane + 15) & 63); ah0 = __hadd2(ah0, i2h2(t1i));
    t1i = __shfl(h22i(ah1), (lane + 15) & 63); ah1 = __hadd2(ah1, i2h2(t1i));
    t1i = __shfl(h22i(ah2), (lane + 15) & 63); ah2 = __hadd2(ah2, i2h2(t1i));
    t1i = __shfl(h22i(ah3), (lane + 15) & 63); ah3 = __hadd2(ah3, i2h2(t1i));
    int t2i;
    t1i = __shfl(h22i(ah0), (lane + 5) & 63); t2i = __shfl(h22i(ah0), (lane + 10) & 63);
    ah0 = __hadd2(__hadd2(ah0, i2h2(t1i)), i2h2(t2i));
    t1i = __shfl(h22i(ah1), (lane + 5) & 63); t2i = __shfl(h22i(ah1), (lane + 10) & 63);
    ah1 = __hadd2(__hadd2(ah1, i2h2(t1i)), i2h2(t2i));
    t1i = __shfl(h22i(ah2), (lane + 5) & 63); t2i = __shfl(h22i(ah2), (lane + 10) & 63);
    ah2 = __hadd2(__hadd2(ah2, i2h2(t1i)), i2h2(t2i));
    t1i = __shfl(h22i(ah3), (lane + 5) & 63); t2i = __shfl(h22i(ah3), (lane + 10) & 63);
    ah3 = __hadd2(__hadd2(ah3, i2h2(t1i)), i2h2(t2i));

    float v0 = 0.f, v1 = 0.f, v2 = 0.f, v3 = 0.f, v4 = 0.f, v5 = 0.f, v6 = 0.f, v7 = 0.f;
    float mv = -INFINITY;
    if (lane < 5) {
        float inv = 1.f / den;
        float2 f0 = __half22float2(ah0);
        float2 f1 = __half22float2(ah1);
        float2 f2 = __half22float2(ah2);
        float2 f3 = __half22float2(ah3);
        float4 bv0 = *(const float4*)(b2 + lane * 8);
        float4 bv1 = *(const float4*)(b2 + lane * 8 + 4);
        v0 = f0.x * inv + bv0.x; v1 = f0.y * inv + bv0.y;
        v2 = f1.x * inv + bv0.z; v3 = f1.y * inv + bv0.w;
        v4 = f2.x * inv + bv1.x; v5 = f2.y * inv + bv1.y;
        v6 = f3.x * inv + bv1.z; v7 = f3.y * inv + bv1.w;
        mv = fmaxf(fmaxf(fmaxf(v0, v1), fmaxf(v2, v3)),
                   fmaxf(fmaxf(v4, v5), fmaxf(v6, v7)));
    }
#pragma unroll
    for (int off = 32; off; off >>= 1) mv = fmaxf(mv, __shfl_xor(mv, off));
    float se = 0.f;
    if (lane < 5)
        se = __expf(v0 - mv) + __expf(v1 - mv) + __expf(v2 - mv) + __expf(v3 - mv)
           + __expf(v4 - mv) + __expf(v5 - mv) + __expf(v6 - mv) + __expf(v7 - mv);
#pragma unroll
    for (int off = 32; off; off >>= 1) se += __shfl_xor(se, off);
    if (lane < 5) {
        float lse = mv + __logf(se);
        float4 o0, o1;
        o0.x = v0 - lse; o0.y = v1 - lse; o0.z = v2 - lse; o0.w = v3 - lse;
        o1.x = v4 - lse; o1.y = v5 - lse; o1.z = v6 - lse; o1.w = v7 - lse;
        *(float4*)(out + (size_t)node * 40 + lane * 8) = o0;
        *(float4*)(out + (size_t)node * 40 + lane * 8 + 4) = o1;
    }
}

// ---------------- launch ----------------

extern "C" void kernel_launch(void* const* d_in, const int* in_sizes, int n_in,
                              void* d_out, int out_size, void* d_ws, size_t ws_size,
                              hipStream_t stream) {
    const float* x   = (const float*)d_in[0];
    const int*   ei  = (const int*)d_in[1];
    const float* W1  = (const float*)d_in[2];
    const float* as1 = (const float*)d_in[3];
    const float* ad1 = (const float*)d_in[4];
    const float* b1  = (const float*)d_in[5];
    const float* W2  = (const float*)d_in[6];
    const float* as2 = (const float*)d_in[7];
    const float* ad2 = (const float*)d_in[8];
    const float* b2  = (const float*)d_in[9];
    float* out = (float*)d_out;

    int n = in_sizes[0] / 128;
    int E = in_sizes[1] / 2;
    const int* src = ei;
    const int* dst = ei + E;

    int nbuck = (n + NB - 1) / NB;
    int cap = (2 * (E / nbuck) + 1023) / 1024 * 1024;

    char* ws = (char*)d_ws;
    size_t off = 0;
    auto alloc = [&](size_t bytes) {
        void* p = ws + off;
        off += (bytes + 255) & ~(size_t)255;
        return p;
    };
    int*      rowp   = (int*)alloc((size_t)n * 4);
    int*      rowe   = (int*)alloc((size_t)n * 4);
    int*      csr    = (int*)alloc((size_t)nbuck * (cap + NB) * 4);
    __half*   h1h    = (__half*)alloc((size_t)n * 128 * 2);
    __half*   hmh    = (__half*)alloc((size_t)n * 128 * 2);
    float*    als1   = (float*)alloc((size_t)n * 4 * 4);
    float*    ald1   = (float*)alloc((size_t)n * 4 * 4);
    unsigned* gmaxu  = (unsigned*)alloc(256);
    unsigned* gcnt   = (unsigned*)alloc((size_t)nbuck * 4);
    __half*   wt16   = (__half*)alloc(128 * 128 * 2);
    __half*   wt2    = (__half*)alloc(48 * 128 * 2);
    float*    gbmax  = (float*)alloc(4096 * 4);
    unsigned* binbuf = (unsigned*)alloc((size_t)nbuck * cap * 4);
    __half* h2h = h1h;
    float* als2 = als1;
    float* ald2 = ald1;

    int binBlocks = 256;                    // R21: long bucket runs
    int epb = (E + binBlocks - 1) / binBlocks;
    int gemmBlocks = (n + 63) / 64;

    k_wtAll<<<89, 256, 0, stream>>>(W1, W2, wt16, wt2, gcnt, gmaxu, nbuck);

    k_binGemm1<<<binBlocks + gemmBlocks, 256, 0, stream>>>(
        src, dst, gcnt, binbuf, E, nbuck, cap, epb, binBlocks,
        x, wt16, as1, ad1, h1h, als1, ald1, n);
    k_buildGmax4<<<nbuck + 256, 256, 0, stream>>>(gcnt, binbuf, rowp, rowe, csr,
                                                  n, cap, nbuck,
                                                  (const float4*)als1, gmaxu);
    k_agg1<<<(n + 3) / 4, 256, 0, stream>>>(rowp, rowe, csr, als1, ald1, h1h, b1, gmaxu, hmh, n);

    k_gemm2<<<gemmBlocks, 256, 0, stream>>>(hmh, wt2, as2, ad2, h2h, als2, ald2, gbmax, n);
    k_gmax1<<<1, 256, 0, stream>>>(gbmax, gmaxu + 4, gemmBlocks);
    k_agg2<<<(n + 3) / 4, 256, 0, stream>>>(rowp, rowe, csr, als2, ald2, h2h, b2, gmaxu + 4, out, n);
}